// Round 8
// baseline (792.508 us; speedup 1.0000x reference)
//
#include <hip/hip_runtime.h>
#include <hip/hip_bf16.h>
#include <math.h>

#define NEG_SLOPE 0.2f
#define NPB_SHIFT 7
#define NPB 128          // nodes per bucket
#define SC_EDGES 16384   // edges per bscatter block
#define MAXD 128         // per-node edges staged in LDS

// ---------------------------------------------------------------------------
// filt[l][c][r] = softmax_r(gt_w[l][c][:])
// ---------------------------------------------------------------------------
__global__ void mkfilt(const float* __restrict__ gt_w, float* __restrict__ filt,
                       int rows) {
    int i = threadIdx.x;
    if (i < rows) {
        const float* g = gt_w + i * 3;
        float m = fmaxf(g[0], fmaxf(g[1], g[2]));
        float e0 = __expf(g[0] - m), e1 = __expf(g[1] - m), e2 = __expf(g[2] - m);
        float s = e0 + e1 + e2;
        filt[i * 3 + 0] = e0 / s;
        filt[i * 3 + 1] = e1 / s;
        filt[i * 3 + 2] = e2 / s;
    }
}

// ---------------------------------------------------------------------------
// WcF[c] = params[c] @ fc_w
// ---------------------------------------------------------------------------
__global__ __launch_bounds__(256) void combw_kernel(const float* __restrict__ params,
                                                    const float* __restrict__ fc_w,
                                                    float* __restrict__ WcF) {
    __shared__ __align__(16) float sP[64 * 64], sF[64 * 64];
    const float* P = params + (size_t)blockIdx.x * 64 * 64;
    int t = threadIdx.x;
    for (int i = t * 4; i < 4096; i += 1024) {
        *(float4*)&sP[i] = *(const float4*)&P[i];
        *(float4*)&sF[i] = *(const float4*)&fc_w[i];
    }
    __syncthreads();
    float* O = WcF + (size_t)blockIdx.x * 64 * 64;
    for (int i = t; i < 4096; i += 256) {
        int r = i >> 6, c = i & 63;
        float acc = 0.f;
#pragma unroll
        for (int k = 0; k < 64; ++k) acc += sP[r * 64 + k] * sF[k * 64 + c];
        O[i] = acc;
    }
}

// ---------------------------------------------------------------------------
// WfcW2 = fc_w @ W2 (64x50); wlr[i] = (fc_w[i]·attn_l, fc_w[i]·attn_r)
// ---------------------------------------------------------------------------
__global__ __launch_bounds__(256) void prep2_kernel(const float* __restrict__ fc_w,
                                                    const float* __restrict__ W2,
                                                    const float* __restrict__ attn_l,
                                                    const float* __restrict__ attn_r,
                                                    float* __restrict__ WfcW2,
                                                    float2* __restrict__ wlr) {
    __shared__ __align__(16) float sF[4096];
    __shared__ float sW[3200], sal[64], sar[64];
    int t = threadIdx.x;
    for (int i = t * 4; i < 4096; i += 1024)
        *(float4*)&sF[i] = *(const float4*)&fc_w[i];
    for (int i = t; i < 3200; i += 256) sW[i] = W2[i];
    if (t < 64) { sal[t] = attn_l[t]; sar[t] = attn_r[t]; }
    __syncthreads();
    if (t < 64) {
        float l = 0.f, r = 0.f;
#pragma unroll
        for (int k = 0; k < 64; ++k) {
            l += sF[t * 64 + k] * sal[k];
            r += sF[t * 64 + k] * sar[k];
        }
        wlr[t] = make_float2(l, r);
    }
    for (int i = t; i < 3200; i += 256) {
        int r = i / 50, c = i - r * 50;
        float acc = 0.f;
#pragma unroll
        for (int k = 0; k < 64; ++k) acc += sF[r * 64 + k] * sW[k * 50 + c];
        WfcW2[i] = acc;
    }
}

// ---------------------------------------------------------------------------
// Bucketed CSR build (unchanged)
// ---------------------------------------------------------------------------
__global__ __launch_bounds__(256) void bcount_kernel(const int* __restrict__ dst,
                                                     int* __restrict__ bcnt, int m, int NB) {
    __shared__ int h[1024];
    for (int i = threadIdx.x; i < NB; i += 256) h[i] = 0;
    __syncthreads();
    int base = blockIdx.x * SC_EDGES;
    int endi = base + SC_EDGES; if (endi > m) endi = m;
    for (int i = base + threadIdx.x; i < endi; i += 256)
        atomicAdd(&h[dst[i] >> NPB_SHIFT], 1);
    __syncthreads();
    for (int i = threadIdx.x; i < NB; i += 256)
        if (h[i]) atomicAdd(&bcnt[i], h[i]);
}

__global__ __launch_bounds__(1024) void bscan_kernel(const int* __restrict__ bcnt,
                                                     int* __restrict__ bbase,
                                                     int* __restrict__ bcur, int NB) {
    __shared__ int s[1024];
    int t = threadIdx.x;
    int v = (t < NB) ? bcnt[t] : 0;
    s[t] = v;
    __syncthreads();
    for (int off = 1; off < 1024; off <<= 1) {
        int u = (t >= off) ? s[t - off] : 0;
        __syncthreads();
        s[t] += u;
        __syncthreads();
    }
    if (t < NB) { bbase[t] = s[t] - v; bcur[t] = s[t] - v; }
    if (t == 1023) bbase[NB] = s[1023];
}

__global__ __launch_bounds__(256) void bscatter_kernel(const int* __restrict__ src,
                                                       const int* __restrict__ dst,
                                                       const int* __restrict__ rel,
                                                       int* __restrict__ bcur,
                                                       unsigned* __restrict__ ebuf,
                                                       int m, int NB) {
    __shared__ int cnt[1024];
    for (int i = threadIdx.x; i < NB; i += 256) cnt[i] = 0;
    __syncthreads();
    int base = blockIdx.x * SC_EDGES;
    int endi = base + SC_EDGES; if (endi > m) endi = m;
    for (int i = base + threadIdx.x; i < endi; i += 256)
        atomicAdd(&cnt[dst[i] >> NPB_SHIFT], 1);
    __syncthreads();
    for (int b = threadIdx.x; b < NB; b += 256) {
        int c = cnt[b];
        if (c) cnt[b] = atomicAdd(&bcur[b], c);
    }
    __syncthreads();
    for (int i = base + threadIdx.x; i < endi; i += 256) {
        int d = dst[i];
        int bk = d >> NPB_SHIFT;
        unsigned pk = (unsigned)src[i] | ((unsigned)rel[i] << 17) |
                      ((unsigned)(d & (NPB - 1)) << 19);
        int pos = atomicAdd(&cnt[bk], 1);
        ebuf[pos] = pk;
    }
}

__global__ __launch_bounds__(256) void bfinal_kernel(const unsigned* __restrict__ ebuf,
                                                     const int* __restrict__ bbase,
                                                     int* __restrict__ rowp,
                                                     unsigned* __restrict__ csr,
                                                     int n, int m, int NB) {
    __shared__ int cnt[NPB], cur[NPB], sc[NPB];
    int b = blockIdx.x;
    int t = threadIdx.x;
    int e0 = bbase[b], e1 = bbase[b + 1];
    if (t < NPB) cnt[t] = 0;
    __syncthreads();
    for (int j = e0 + t; j < e1; j += 256)
        atomicAdd(&cnt[(ebuf[j] >> 19) & (NPB - 1)], 1);
    __syncthreads();
    int v0 = (t < NPB) ? cnt[t] : 0;
    if (t < NPB) sc[t] = v0;
    __syncthreads();
    for (int off = 1; off < NPB; off <<= 1) {
        int u = (t >= off && t < NPB) ? sc[t - off] : 0;
        __syncthreads();
        if (t < NPB) sc[t] += u;
        __syncthreads();
    }
    if (t < NPB) {
        int ex = e0 + sc[t] - v0;
        cur[t] = ex;
        int v = b * NPB + t;
        if (v < n) rowp[v] = ex;
    }
    if (b == 0 && t == 0) rowp[n] = m;
    __syncthreads();
    for (int j = e0 + t; j < e1; j += 256) {
        unsigned pk = ebuf[j];
        int dl = (pk >> 19) & (NPB - 1);
        int pos = atomicAdd(&cur[dl], 1);
        csr[pos] = (pk & 0x1FFFF) | (((pk >> 17) & 3) << 20);
    }
}

// ---------------------------------------------------------------------------
// F0 dual GEMM: OAB = interleave(h@WcF0, h@WcF1); epilogue -> el1/er1 (float2)
// and uu (float4: ulA,ulB,urA,urB) with ul = row·wl, ur = row·wr.
// ---------------------------------------------------------------------------
__global__ __launch_bounds__(256) void gemm_f0(const float* __restrict__ A,
                                               const float* __restrict__ WcF,
                                               float2* __restrict__ OAB, int n,
                                               const float* __restrict__ attn_l,
                                               const float* __restrict__ attn_r,
                                               const float2* __restrict__ wlr,
                                               float2* __restrict__ el2,
                                               float2* __restrict__ er2,
                                               float4* __restrict__ uu) {
    __shared__ __align__(16) float sW[2][64 * 64];
    __shared__ __align__(16) float sA[64 * 68];
    __shared__ float sAl[64], sAr[64];
    __shared__ float2 sWlr[64];
    int t = threadIdx.x;
    int row0 = blockIdx.x * 64;
    for (int i = t * 4; i < 8192; i += 1024)
        *(float4*)&sW[0][i] = *(const float4*)&WcF[i];
    if (t < 64) { sAl[t] = attn_l[t]; sAr[t] = attn_r[t]; sWlr[t] = wlr[t]; }
    int rows = n - row0; if (rows > 64) rows = 64;
    for (int i = t * 4; i < 4096; i += 1024) {
        int r = i >> 6, c = i & 63;
        float4 v = {0.f, 0.f, 0.f, 0.f};
        if (r < rows) v = *(const float4*)&A[(size_t)(row0 + r) * 64 + c];
        *(float4*)&sA[r * 68 + c] = v;
    }
    __syncthreads();
    int tr = (t >> 4) * 4, tc = (t & 15) * 4;
    float accA[4][4] = {}, accB[4][4] = {};
#pragma unroll 4
    for (int k = 0; k < 64; k += 4) {
        float4 av[4];
#pragma unroll
        for (int i = 0; i < 4; ++i) av[i] = *(const float4*)&sA[(tr + i) * 68 + k];
#pragma unroll
        for (int kk = 0; kk < 4; ++kk) {
            float4 bA = *(const float4*)&sW[0][(k + kk) * 64 + tc];
            float4 bB = *(const float4*)&sW[1][(k + kk) * 64 + tc];
#pragma unroll
            for (int i = 0; i < 4; ++i) {
                float a = (&av[i].x)[kk];
                accA[i][0] += a * bA.x; accA[i][1] += a * bA.y;
                accA[i][2] += a * bA.z; accA[i][3] += a * bA.w;
                accB[i][0] += a * bB.x; accB[i][1] += a * bB.y;
                accB[i][2] += a * bB.z; accB[i][3] += a * bB.w;
            }
        }
    }
#pragma unroll
    for (int i = 0; i < 4; ++i) {
        int r = row0 + tr + i;
        if (r < n) {
            float4 v0 = {accA[i][0], accB[i][0], accA[i][1], accB[i][1]};
            float4 v1 = {accA[i][2], accB[i][2], accA[i][3], accB[i][3]};
            float* o = (float*)&OAB[(size_t)r * 64 + tc];
            *(float4*)o = v0;
            *(float4*)(o + 4) = v1;
        }
    }
    // epilogue: 8 dots per row (el,er,ul,ur × ch)
    float plA[4], prA[4], plB[4], prB[4];
    float qlA[4], qrA[4], qlB[4], qrB[4];
#pragma unroll
    for (int i = 0; i < 4; ++i) {
        float la = 0.f, ra = 0.f, lb = 0.f, rb = 0.f;
        float ua = 0.f, va = 0.f, ub = 0.f, vb = 0.f;
#pragma unroll
        for (int j = 0; j < 4; ++j) {
            float2 wv = sWlr[tc + j];
            la += accA[i][j] * sAl[tc + j]; ra += accA[i][j] * sAr[tc + j];
            lb += accB[i][j] * sAl[tc + j]; rb += accB[i][j] * sAr[tc + j];
            ua += accA[i][j] * wv.x; va += accA[i][j] * wv.y;
            ub += accB[i][j] * wv.x; vb += accB[i][j] * wv.y;
        }
        plA[i] = la; prA[i] = ra; plB[i] = lb; prB[i] = rb;
        qlA[i] = ua; qrA[i] = va; qlB[i] = ub; qrB[i] = vb;
    }
#pragma unroll
    for (int off = 1; off < 16; off <<= 1) {
#pragma unroll
        for (int i = 0; i < 4; ++i) {
            plA[i] += __shfl_xor(plA[i], off); prA[i] += __shfl_xor(prA[i], off);
            plB[i] += __shfl_xor(plB[i], off); prB[i] += __shfl_xor(prB[i], off);
            qlA[i] += __shfl_xor(qlA[i], off); qrA[i] += __shfl_xor(qrA[i], off);
            qlB[i] += __shfl_xor(qlB[i], off); qrB[i] += __shfl_xor(qrB[i], off);
        }
    }
    if ((t & 15) == 0) {
#pragma unroll
        for (int i = 0; i < 4; ++i) {
            int r = row0 + tr + i;
            if (r < n) {
                el2[r] = make_float2(plA[i], plB[i]);
                er2[r] = make_float2(prA[i], prB[i]);
                uu[r]  = make_float4(qlA[i], qlB[i], qrA[i], qrB[i]);
            }
        }
    }
}

// ---------------------------------------------------------------------------
// Sparse pass a: o = D^-1 A_w ft  (+ scalar u columns if HASU).
// One wave/node; gather: 32 lanes per row, 2 edges per instruction (float4).
// ---------------------------------------------------------------------------
template <bool HASU>
__global__ __launch_bounds__(256) void agg1_ab(
        const int* __restrict__ rowp, const unsigned* __restrict__ csr,
        const float* __restrict__ filt, int fo0, int fo1,
        const float2* __restrict__ el, const float2* __restrict__ er,
        const float4* __restrict__ uu,
        const float4* __restrict__ ft4, float4* __restrict__ o4,
        float2* __restrict__ sb, float4* __restrict__ u1, int n) {
    __shared__ unsigned sPk[4][MAXD];
    __shared__ float2 sW2[4][MAXD];
    int w = (blockIdx.x * blockDim.x + threadIdx.x) >> 6;
    int lane = threadIdx.x & 63;
    int wv = threadIdx.x >> 6;
    int sub = lane & 31, eh = lane >> 5;
    if (w >= n) return;
    int base = rowp[w], end = rowp[w + 1];
    float fA0 = filt[fo0], fA1 = filt[fo0 + 1], fA2 = filt[fo0 + 2];
    float fB0 = filt[fo1], fB1 = filt[fo1 + 1], fB2 = filt[fo1 + 2];
    float2 erv = er[w];

    float degA = 0.f, degB = 0.f, ssA = 0.f, ssB = 0.f;
    float4 uacc = {0.f, 0.f, 0.f, 0.f};
    for (int j = base + lane; j < end; j += 64) {
        unsigned pk = csr[j];
        int d = j - base;
        int s = pk & 0x1FFFF;
        int r = pk >> 20;
        float wA = (r == 0) ? fA0 : ((r == 1) ? fA1 : fA2);
        float wB = (r == 0) ? fB0 : ((r == 1) ? fB1 : fB2);
        if (d < MAXD) { sPk[wv][d] = pk; sW2[wv][d] = make_float2(wA, wB); }
        degA += wA; degB += wB;
        float2 e2 = el[s];
        float xA = e2.x + erv.x;
        ssA += __expf(xA > 0.f ? xA : NEG_SLOPE * xA);
        float xB = e2.y + erv.y;
        ssB += __expf(xB > 0.f ? xB : NEG_SLOPE * xB);
        if (HASU) {
            float4 u = uu[s];
            uacc.x += wA * u.x; uacc.y += wB * u.y;
            uacc.z += wA * u.z; uacc.w += wB * u.w;
        }
    }
    int deg = end - base;
    int dmax = deg < MAXD ? deg : MAXD;
    int dpad = (dmax + 3) & ~3;
    if (lane < dpad - dmax) {
        sPk[wv][dmax + lane] = 0;
        sW2[wv][dmax + lane] = make_float2(0.f, 0.f);
    }
    for (int off = 32; off; off >>= 1) {
        degA += __shfl_xor(degA, off); degB += __shfl_xor(degB, off);
        ssA += __shfl_xor(ssA, off);   ssB += __shfl_xor(ssB, off);
        if (HASU) {
            uacc.x += __shfl_xor(uacc.x, off); uacc.y += __shfl_xor(uacc.y, off);
            uacc.z += __shfl_xor(uacc.z, off); uacc.w += __shfl_xor(uacc.w, off);
        }
    }
    float dA = degA > 0.f ? degA : 1.f;
    float dB = degB > 0.f ? degB : 1.f;

    float4 acc = {0.f, 0.f, 0.f, 0.f};
    for (int jj = 0; jj < dpad; jj += 4) {
        unsigned pk0 = sPk[wv][jj + eh];
        unsigned pk1 = sPk[wv][jj + 2 + eh];
        float2 w0 = sW2[wv][jj + eh];
        float2 w1 = sW2[wv][jj + 2 + eh];
        int s0 = pk0 & 0x1FFFF, s1 = pk1 & 0x1FFFF;
        float4 v0 = ft4[(size_t)s0 * 32 + sub];
        float4 v1 = ft4[(size_t)s1 * 32 + sub];
        acc.x += w0.x * v0.x + w1.x * v1.x;
        acc.y += w0.y * v0.y + w1.y * v1.y;
        acc.z += w0.x * v0.z + w1.x * v1.z;
        acc.w += w0.y * v0.w + w1.y * v1.w;
    }
    for (int j = base + MAXD; j < end; j += 2) {   // deg > MAXD fallback (~never)
        int je = j + eh;
        unsigned pk = 0; float wA = 0.f, wB = 0.f;
        if (je < end) {
            pk = csr[je];
            int r = pk >> 20;
            wA = (r == 0) ? fA0 : ((r == 1) ? fA1 : fA2);
            wB = (r == 0) ? fB0 : ((r == 1) ? fB1 : fB2);
        }
        int s = pk & 0x1FFFF;
        float4 v = ft4[(size_t)s * 32 + sub];
        acc.x += wA * v.x; acc.y += wB * v.y;
        acc.z += wA * v.z; acc.w += wB * v.w;
    }
    acc.x += __shfl_xor(acc.x, 32); acc.y += __shfl_xor(acc.y, 32);
    acc.z += __shfl_xor(acc.z, 32); acc.w += __shfl_xor(acc.w, 32);
    if (eh == 0)
        o4[(size_t)w * 32 + sub] = make_float4(acc.x / dA, acc.y / dB,
                                               acc.z / dA, acc.w / dB);
    if (lane == 0) {
        sb[w] = make_float2(ssA > 0.f ? 1.f / ssA : 0.f,
                            ssB > 0.f ? 1.f / ssB : 0.f);
        if (HASU)
            u1[w] = make_float4(uacc.x / dA, uacc.y / dB, uacc.z / dA, uacc.w / dB);
    }
}

// ---------------------------------------------------------------------------
// Sparse pass b: o = S ft1 (attention softmax via el/er + sb); scalar u -> el/er
// for the next layer if HASU.
// ---------------------------------------------------------------------------
template <bool HASU>
__global__ __launch_bounds__(256) void agg2_ab(
        const int* __restrict__ rowp, const unsigned* __restrict__ csr,
        const float2* __restrict__ el, const float2* __restrict__ er,
        const float2* __restrict__ sb, const float4* __restrict__ u1,
        const float4* __restrict__ ft4, float4* __restrict__ o4,
        float2* __restrict__ elout, float2* __restrict__ erout, int n) {
    __shared__ unsigned sPk[4][MAXD];
    __shared__ float2 sE[4][MAXD];
    int w = (blockIdx.x * blockDim.x + threadIdx.x) >> 6;
    int lane = threadIdx.x & 63;
    int wv = threadIdx.x >> 6;
    int sub = lane & 31, eh = lane >> 5;
    if (w >= n) return;
    int base = rowp[w], end = rowp[w + 1];
    float2 erv = er[w];
    float2 inv = sb[w];

    float4 uacc = {0.f, 0.f, 0.f, 0.f};
    for (int j = base + lane; j < end; j += 64) {
        unsigned pk = csr[j];
        int d = j - base;
        int s = pk & 0x1FFFF;
        float2 e2 = el[s];
        float xA = e2.x + erv.x;
        float xB = e2.y + erv.y;
        float eA = __expf(xA > 0.f ? xA : NEG_SLOPE * xA);
        float eB = __expf(xB > 0.f ? xB : NEG_SLOPE * xB);
        if (d < MAXD) { sPk[wv][d] = pk; sE[wv][d] = make_float2(eA, eB); }
        if (HASU) {
            float4 u = u1[s];
            uacc.x += eA * u.x; uacc.y += eB * u.y;
            uacc.z += eA * u.z; uacc.w += eB * u.w;
        }
    }
    int deg = end - base;
    int dmax = deg < MAXD ? deg : MAXD;
    int dpad = (dmax + 3) & ~3;
    if (lane < dpad - dmax) {
        sPk[wv][dmax + lane] = 0;
        sE[wv][dmax + lane] = make_float2(0.f, 0.f);
    }
    if (HASU) {
        for (int off = 32; off; off >>= 1) {
            uacc.x += __shfl_xor(uacc.x, off); uacc.y += __shfl_xor(uacc.y, off);
            uacc.z += __shfl_xor(uacc.z, off); uacc.w += __shfl_xor(uacc.w, off);
        }
    }

    float4 acc = {0.f, 0.f, 0.f, 0.f};
    for (int jj = 0; jj < dpad; jj += 4) {
        unsigned pk0 = sPk[wv][jj + eh];
        unsigned pk1 = sPk[wv][jj + 2 + eh];
        float2 w0 = sE[wv][jj + eh];
        float2 w1 = sE[wv][jj + 2 + eh];
        int s0 = pk0 & 0x1FFFF, s1 = pk1 & 0x1FFFF;
        float4 v0 = ft4[(size_t)s0 * 32 + sub];
        float4 v1 = ft4[(size_t)s1 * 32 + sub];
        acc.x += w0.x * v0.x + w1.x * v1.x;
        acc.y += w0.y * v0.y + w1.y * v1.y;
        acc.z += w0.x * v0.z + w1.x * v1.z;
        acc.w += w0.y * v0.w + w1.y * v1.w;
    }
    for (int j = base + MAXD; j < end; j += 2) {   // fallback
        int je = j + eh;
        float eA = 0.f, eB = 0.f;
        unsigned pk = 0;
        if (je < end) {
            pk = csr[je];
            int s = pk & 0x1FFFF;
            float2 e2 = el[s];
            float xA = e2.x + erv.x;
            float xB = e2.y + erv.y;
            eA = __expf(xA > 0.f ? xA : NEG_SLOPE * xA);
            eB = __expf(xB > 0.f ? xB : NEG_SLOPE * xB);
        }
        int s = pk & 0x1FFFF;
        float4 v = ft4[(size_t)s * 32 + sub];
        acc.x += eA * v.x; acc.y += eB * v.y;
        acc.z += eA * v.z; acc.w += eB * v.w;
    }
    acc.x += __shfl_xor(acc.x, 32); acc.y += __shfl_xor(acc.y, 32);
    acc.z += __shfl_xor(acc.z, 32); acc.w += __shfl_xor(acc.w, 32);
    if (eh == 0)
        o4[(size_t)w * 32 + sub] = make_float4(acc.x * inv.x, acc.y * inv.y,
                                               acc.z * inv.x, acc.w * inv.y);
    if (HASU && lane == 0) {
        elout[w] = make_float2(uacc.x * inv.x, uacc.y * inv.y);
        erout[w] = make_float2(uacc.z * inv.x, uacc.w * inv.y);
    }
}

// ---------------------------------------------------------------------------
// Fused final: out = b2 + (lw0*A + lw1*B) @ WfcW2   (interleaved input)
// ---------------------------------------------------------------------------
__global__ __launch_bounds__(256) void gemm_out_ab(const float2* __restrict__ AAB,
                                                   const float* __restrict__ W,
                                                   const float* __restrict__ b2,
                                                   const float* __restrict__ lin_w,
                                                   float* __restrict__ out, int n) {
    __shared__ __align__(16) float sW[64 * 50];
    __shared__ __align__(16) float sA[64 * 68];
    int t = threadIdx.x;
    int row0 = blockIdx.x * 64;
    float lw0 = lin_w[0], lw1 = lin_w[1];
    for (int i = t; i < 64 * 50; i += 256) sW[i] = W[i];
    int rows = n - row0; if (rows > 64) rows = 64;
    for (int i = t * 4; i < 8192; i += 1024) {
        int r = i >> 7, c2 = i & 127;
        float4 v = {0.f, 0.f, 0.f, 0.f};
        if (r < rows) v = *(const float4*)((const float*)&AAB[(size_t)(row0 + r) * 64] + c2);
        int dim = c2 >> 1;
        sA[r * 68 + dim] = lw0 * v.x + lw1 * v.y;
        sA[r * 68 + dim + 1] = lw0 * v.z + lw1 * v.w;
    }
    __syncthreads();
    for (int i = t; i < 64 * 50; i += 256) {
        int r = i / 50, col = i - r * 50;
        if (row0 + r >= n) continue;
        float acc = 0.f;
#pragma unroll
        for (int k = 0; k < 64; ++k) acc += sA[r * 68 + k] * sW[k * 50 + col];
        out[(size_t)(row0 + r) * 50 + col] = b2[col] + acc;
    }
}

// ---------------------------------------------------------------------------
extern "C" void kernel_launch(void* const* d_in, const int* in_sizes, int n_in,
                              void* d_out, int out_size, void* d_ws, size_t ws_size,
                              hipStream_t stream) {
    const float* h      = (const float*)d_in[0];
    const float* params = (const float*)d_in[1];
    const float* gt_w   = (const float*)d_in[2];
    const float* fc_w   = (const float*)d_in[3];
    const float* attn_l = (const float*)d_in[4];
    const float* attn_r = (const float*)d_in[5];
    const float* lin_w  = (const float*)d_in[6];
    const float* W2     = (const float*)d_in[7];
    const float* b2     = (const float*)d_in[8];
    const int*   src    = (const int*)d_in[9];
    const int*   dst    = (const int*)d_in[10];
    const int*   rel    = (const int*)d_in[11];

    const int n = in_sizes[0] / 64;      // 100000 nodes
    const int m = in_sizes[9];           // 1.8M edges
    const int C = 2, L = 2;
    float* out = (float*)d_out;

    char* base = (char*)d_ws;
    size_t off = 0;
    auto alloc = [&](size_t bytes) -> char* {
        char* p = base + off;
        off = (off + bytes + 255) & ~(size_t)255;
        return p;
    };
    const int NB = (n + NPB - 1) >> NPB_SHIFT;
    const int nchunks = (m + SC_EDGES - 1) / SC_EDGES;
    float*    filt  = (float*)alloc(L * C * 3 * sizeof(float));
    float*    WcF   = (float*)alloc((size_t)C * 64 * 64 * 4);
    float*    WfcW2 = (float*)alloc((size_t)64 * 50 * 4);
    float2*   wlr   = (float2*)alloc((size_t)64 * 8);
    int*      bcnt  = (int*)alloc((size_t)NB * 4);
    int*      bbase = (int*)alloc((size_t)(NB + 1) * 4);
    int*      bcur  = (int*)alloc((size_t)NB * 4);
    int*      rowp  = (int*)alloc((size_t)(n + 1) * 4);
    unsigned* ebuf  = (unsigned*)alloc((size_t)m * 4);
    unsigned* csr   = (unsigned*)alloc((size_t)m * 4);
    float2*   el1   = (float2*)alloc((size_t)n * 8);
    float2*   er1   = (float2*)alloc((size_t)n * 8);
    float2*   elL2  = (float2*)alloc((size_t)n * 8);
    float2*   erL2  = (float2*)alloc((size_t)n * 8);
    float2*   sbAB  = (float2*)alloc((size_t)n * 8);
    float4*   uu    = (float4*)alloc((size_t)n * 16);
    float4*   u1    = (float4*)alloc((size_t)n * 16);
    float2*   FAB   = (float2*)alloc((size_t)n * 64 * 8);
    float2*   GAB   = (float2*)alloc((size_t)n * 64 * 8);
    float2*   HAB   = (float2*)alloc((size_t)n * 64 * 8);

    // ---- tiny precomputes + CSR build ----
    hipMemsetAsync(bcnt, 0, (size_t)NB * 4, stream);
    mkfilt<<<1, 64, 0, stream>>>(gt_w, filt, L * C);
    combw_kernel<<<C, 256, 0, stream>>>(params, fc_w, WcF);
    prep2_kernel<<<1, 256, 0, stream>>>(fc_w, W2, attn_l, attn_r, WfcW2, wlr);
    bcount_kernel<<<nchunks, 256, 0, stream>>>(dst, bcnt, m, NB);
    bscan_kernel<<<1, 1024, 0, stream>>>(bcnt, bbase, bcur, NB);
    bscatter_kernel<<<nchunks, 256, 0, stream>>>(src, dst, rel, bcur, ebuf, m, NB);
    bfinal_kernel<<<NB, 256, 0, stream>>>(ebuf, bbase, rowp, csr, n, m, NB);

    const int gB = (n + 63) / 64;
    const int waveBlocks = (n + 3) / 4;

    // F0 = h @ (params_c @ fc_w), fused el1/er1 + u columns
    gemm_f0<<<gB, 256, 0, stream>>>(h, WcF, FAB, n, attn_l, attn_r, wlr,
                                    el1, er1, uu);
    // layer 1 (carries u columns for layer-2 attention)
    agg1_ab<true><<<waveBlocks, 256, 0, stream>>>(rowp, csr, filt, 0, 3,
                                                  el1, er1, uu,
                                                  (const float4*)FAB, (float4*)GAB,
                                                  sbAB, u1, n);
    agg2_ab<true><<<waveBlocks, 256, 0, stream>>>(rowp, csr, el1, er1, sbAB, u1,
                                                  (const float4*)GAB, (float4*)HAB,
                                                  elL2, erL2, n);
    // layer 2 (fc_w deferred into the output GEMM)
    agg1_ab<false><<<waveBlocks, 256, 0, stream>>>(rowp, csr, filt, 6, 9,
                                                   elL2, erL2, nullptr,
                                                   (const float4*)HAB, (float4*)GAB,
                                                   sbAB, nullptr, n);
    agg2_ab<false><<<waveBlocks, 256, 0, stream>>>(rowp, csr, elL2, erL2, sbAB, nullptr,
                                                   (const float4*)GAB, (float4*)HAB,
                                                   nullptr, nullptr, n);
    // out = b2 + (lw0*HA + lw1*HB) @ (fc_w @ W2)
    gemm_out_ab<<<gB, 256, 0, stream>>>(HAB, WfcW2, b2, lin_w, out, n);
}

// Round 9
// 788.725 us; speedup vs baseline: 1.0048x; 1.0048x over previous
//
#include <hip/hip_runtime.h>
#include <hip/hip_bf16.h>
#include <math.h>

#define NEG_SLOPE 0.2f
#define NPB_SHIFT 7
#define NPB 128          // nodes per bucket
#define SC_EDGES 16384   // edges per bscatter block
#define MAXD 128         // per-node edges staged in LDS

// ---------------------------------------------------------------------------
// filt[l][c][r] = softmax_r(gt_w[l][c][:])
// ---------------------------------------------------------------------------
__global__ void mkfilt(const float* __restrict__ gt_w, float* __restrict__ filt,
                       int rows) {
    int i = threadIdx.x;
    if (i < rows) {
        const float* g = gt_w + i * 3;
        float m = fmaxf(g[0], fmaxf(g[1], g[2]));
        float e0 = __expf(g[0] - m), e1 = __expf(g[1] - m), e2 = __expf(g[2] - m);
        float s = e0 + e1 + e2;
        filt[i * 3 + 0] = e0 / s;
        filt[i * 3 + 1] = e1 / s;
        filt[i * 3 + 2] = e2 / s;
    }
}

// ---------------------------------------------------------------------------
// WcF[c] = params[c] @ fc_w
// ---------------------------------------------------------------------------
__global__ __launch_bounds__(256) void combw_kernel(const float* __restrict__ params,
                                                    const float* __restrict__ fc_w,
                                                    float* __restrict__ WcF) {
    __shared__ __align__(16) float sP[64 * 64], sF[64 * 64];
    const float* P = params + (size_t)blockIdx.x * 64 * 64;
    int t = threadIdx.x;
    for (int i = t * 4; i < 4096; i += 1024) {
        *(float4*)&sP[i] = *(const float4*)&P[i];
        *(float4*)&sF[i] = *(const float4*)&fc_w[i];
    }
    __syncthreads();
    float* O = WcF + (size_t)blockIdx.x * 64 * 64;
    for (int i = t; i < 4096; i += 256) {
        int r = i >> 6, c = i & 63;
        float acc = 0.f;
#pragma unroll
        for (int k = 0; k < 64; ++k) acc += sP[r * 64 + k] * sF[k * 64 + c];
        O[i] = acc;
    }
}

// ---------------------------------------------------------------------------
// WfcW2 = fc_w @ W2 (64x50); wlr[i] = (fc_w[i]·attn_l, fc_w[i]·attn_r)
// ---------------------------------------------------------------------------
__global__ __launch_bounds__(256) void prep2_kernel(const float* __restrict__ fc_w,
                                                    const float* __restrict__ W2,
                                                    const float* __restrict__ attn_l,
                                                    const float* __restrict__ attn_r,
                                                    float* __restrict__ WfcW2,
                                                    float2* __restrict__ wlr) {
    __shared__ __align__(16) float sF[4096];
    __shared__ float sW[3200], sal[64], sar[64];
    int t = threadIdx.x;
    for (int i = t * 4; i < 4096; i += 1024)
        *(float4*)&sF[i] = *(const float4*)&fc_w[i];
    for (int i = t; i < 3200; i += 256) sW[i] = W2[i];
    if (t < 64) { sal[t] = attn_l[t]; sar[t] = attn_r[t]; }
    __syncthreads();
    if (t < 64) {
        float l = 0.f, r = 0.f;
#pragma unroll
        for (int k = 0; k < 64; ++k) {
            l += sF[t * 64 + k] * sal[k];
            r += sF[t * 64 + k] * sar[k];
        }
        wlr[t] = make_float2(l, r);
    }
    for (int i = t; i < 3200; i += 256) {
        int r = i / 50, c = i - r * 50;
        float acc = 0.f;
#pragma unroll
        for (int k = 0; k < 64; ++k) acc += sF[r * 64 + k] * sW[k * 50 + c];
        WfcW2[i] = acc;
    }
}

// ---------------------------------------------------------------------------
// Bucketed CSR build (unchanged)
// ---------------------------------------------------------------------------
__global__ __launch_bounds__(256) void bcount_kernel(const int* __restrict__ dst,
                                                     int* __restrict__ bcnt, int m, int NB) {
    __shared__ int h[1024];
    for (int i = threadIdx.x; i < NB; i += 256) h[i] = 0;
    __syncthreads();
    int base = blockIdx.x * SC_EDGES;
    int endi = base + SC_EDGES; if (endi > m) endi = m;
    for (int i = base + threadIdx.x; i < endi; i += 256)
        atomicAdd(&h[dst[i] >> NPB_SHIFT], 1);
    __syncthreads();
    for (int i = threadIdx.x; i < NB; i += 256)
        if (h[i]) atomicAdd(&bcnt[i], h[i]);
}

__global__ __launch_bounds__(1024) void bscan_kernel(const int* __restrict__ bcnt,
                                                     int* __restrict__ bbase,
                                                     int* __restrict__ bcur, int NB) {
    __shared__ int s[1024];
    int t = threadIdx.x;
    int v = (t < NB) ? bcnt[t] : 0;
    s[t] = v;
    __syncthreads();
    for (int off = 1; off < 1024; off <<= 1) {
        int u = (t >= off) ? s[t - off] : 0;
        __syncthreads();
        s[t] += u;
        __syncthreads();
    }
    if (t < NB) { bbase[t] = s[t] - v; bcur[t] = s[t] - v; }
    if (t == 1023) bbase[NB] = s[1023];
}

__global__ __launch_bounds__(256) void bscatter_kernel(const int* __restrict__ src,
                                                       const int* __restrict__ dst,
                                                       const int* __restrict__ rel,
                                                       int* __restrict__ bcur,
                                                       unsigned* __restrict__ ebuf,
                                                       int m, int NB) {
    __shared__ int cnt[1024];
    for (int i = threadIdx.x; i < NB; i += 256) cnt[i] = 0;
    __syncthreads();
    int base = blockIdx.x * SC_EDGES;
    int endi = base + SC_EDGES; if (endi > m) endi = m;
    for (int i = base + threadIdx.x; i < endi; i += 256)
        atomicAdd(&cnt[dst[i] >> NPB_SHIFT], 1);
    __syncthreads();
    for (int b = threadIdx.x; b < NB; b += 256) {
        int c = cnt[b];
        if (c) cnt[b] = atomicAdd(&bcur[b], c);
    }
    __syncthreads();
    for (int i = base + threadIdx.x; i < endi; i += 256) {
        int d = dst[i];
        int bk = d >> NPB_SHIFT;
        unsigned pk = (unsigned)src[i] | ((unsigned)rel[i] << 17) |
                      ((unsigned)(d & (NPB - 1)) << 19);
        int pos = atomicAdd(&cnt[bk], 1);
        ebuf[pos] = pk;
    }
}

__global__ __launch_bounds__(256) void bfinal_kernel(const unsigned* __restrict__ ebuf,
                                                     const int* __restrict__ bbase,
                                                     int* __restrict__ rowp,
                                                     unsigned* __restrict__ csr,
                                                     int n, int m, int NB) {
    __shared__ int cnt[NPB], cur[NPB], sc[NPB];
    int b = blockIdx.x;
    int t = threadIdx.x;
    int e0 = bbase[b], e1 = bbase[b + 1];
    if (t < NPB) cnt[t] = 0;
    __syncthreads();
    for (int j = e0 + t; j < e1; j += 256)
        atomicAdd(&cnt[(ebuf[j] >> 19) & (NPB - 1)], 1);
    __syncthreads();
    int v0 = (t < NPB) ? cnt[t] : 0;
    if (t < NPB) sc[t] = v0;
    __syncthreads();
    for (int off = 1; off < NPB; off <<= 1) {
        int u = (t >= off && t < NPB) ? sc[t - off] : 0;
        __syncthreads();
        if (t < NPB) sc[t] += u;
        __syncthreads();
    }
    if (t < NPB) {
        int ex = e0 + sc[t] - v0;
        cur[t] = ex;
        int v = b * NPB + t;
        if (v < n) rowp[v] = ex;
    }
    if (b == 0 && t == 0) rowp[n] = m;
    __syncthreads();
    for (int j = e0 + t; j < e1; j += 256) {
        unsigned pk = ebuf[j];
        int dl = (pk >> 19) & (NPB - 1);
        int pos = atomicAdd(&cur[dl], 1);
        csr[pos] = (pk & 0x1FFFF) | (((pk >> 17) & 3) << 20);
    }
}

// ---------------------------------------------------------------------------
// F0 dual GEMM: OAB = interleave(h@WcF0, h@WcF1); epilogue -> el1/er1 (float2)
// and uu (float4: ulA,ulB,urA,urB), ul = row·wl, ur = row·wr.
// ---------------------------------------------------------------------------
__global__ __launch_bounds__(256) void gemm_f0(const float* __restrict__ A,
                                               const float* __restrict__ WcF,
                                               float2* __restrict__ OAB, int n,
                                               const float* __restrict__ attn_l,
                                               const float* __restrict__ attn_r,
                                               const float2* __restrict__ wlr,
                                               float2* __restrict__ el2,
                                               float2* __restrict__ er2,
                                               float4* __restrict__ uu) {
    __shared__ __align__(16) float sW[2][64 * 64];
    __shared__ __align__(16) float sA[64 * 68];
    __shared__ float sAl[64], sAr[64];
    __shared__ float2 sWlr[64];
    int t = threadIdx.x;
    int row0 = blockIdx.x * 64;
    for (int i = t * 4; i < 8192; i += 1024)
        *(float4*)&sW[0][i] = *(const float4*)&WcF[i];
    if (t < 64) { sAl[t] = attn_l[t]; sAr[t] = attn_r[t]; sWlr[t] = wlr[t]; }
    int rows = n - row0; if (rows > 64) rows = 64;
    for (int i = t * 4; i < 4096; i += 1024) {
        int r = i >> 6, c = i & 63;
        float4 v = {0.f, 0.f, 0.f, 0.f};
        if (r < rows) v = *(const float4*)&A[(size_t)(row0 + r) * 64 + c];
        *(float4*)&sA[r * 68 + c] = v;
    }
    __syncthreads();
    int tr = (t >> 4) * 4, tc = (t & 15) * 4;
    float accA[4][4] = {}, accB[4][4] = {};
#pragma unroll 4
    for (int k = 0; k < 64; k += 4) {
        float4 av[4];
#pragma unroll
        for (int i = 0; i < 4; ++i) av[i] = *(const float4*)&sA[(tr + i) * 68 + k];
#pragma unroll
        for (int kk = 0; kk < 4; ++kk) {
            float4 bA = *(const float4*)&sW[0][(k + kk) * 64 + tc];
            float4 bB = *(const float4*)&sW[1][(k + kk) * 64 + tc];
#pragma unroll
            for (int i = 0; i < 4; ++i) {
                float a = (&av[i].x)[kk];
                accA[i][0] += a * bA.x; accA[i][1] += a * bA.y;
                accA[i][2] += a * bA.z; accA[i][3] += a * bA.w;
                accB[i][0] += a * bB.x; accB[i][1] += a * bB.y;
                accB[i][2] += a * bB.z; accB[i][3] += a * bB.w;
            }
        }
    }
#pragma unroll
    for (int i = 0; i < 4; ++i) {
        int r = row0 + tr + i;
        if (r < n) {
            float4 v0 = {accA[i][0], accB[i][0], accA[i][1], accB[i][1]};
            float4 v1 = {accA[i][2], accB[i][2], accA[i][3], accB[i][3]};
            float* o = (float*)&OAB[(size_t)r * 64 + tc];
            *(float4*)o = v0;
            *(float4*)(o + 4) = v1;
        }
    }
    float plA[4], prA[4], plB[4], prB[4];
    float qlA[4], qrA[4], qlB[4], qrB[4];
#pragma unroll
    for (int i = 0; i < 4; ++i) {
        float la = 0.f, ra = 0.f, lb = 0.f, rb = 0.f;
        float ua = 0.f, va = 0.f, ub = 0.f, vb = 0.f;
#pragma unroll
        for (int j = 0; j < 4; ++j) {
            float2 wv = sWlr[tc + j];
            la += accA[i][j] * sAl[tc + j]; ra += accA[i][j] * sAr[tc + j];
            lb += accB[i][j] * sAl[tc + j]; rb += accB[i][j] * sAr[tc + j];
            ua += accA[i][j] * wv.x; va += accA[i][j] * wv.y;
            ub += accB[i][j] * wv.x; vb += accB[i][j] * wv.y;
        }
        plA[i] = la; prA[i] = ra; plB[i] = lb; prB[i] = rb;
        qlA[i] = ua; qrA[i] = va; qlB[i] = ub; qrB[i] = vb;
    }
#pragma unroll
    for (int off = 1; off < 16; off <<= 1) {
#pragma unroll
        for (int i = 0; i < 4; ++i) {
            plA[i] += __shfl_xor(plA[i], off); prA[i] += __shfl_xor(prA[i], off);
            plB[i] += __shfl_xor(plB[i], off); prB[i] += __shfl_xor(prB[i], off);
            qlA[i] += __shfl_xor(qlA[i], off); qrA[i] += __shfl_xor(qrA[i], off);
            qlB[i] += __shfl_xor(qlB[i], off); qrB[i] += __shfl_xor(qrB[i], off);
        }
    }
    if ((t & 15) == 0) {
#pragma unroll
        for (int i = 0; i < 4; ++i) {
            int r = row0 + tr + i;
            if (r < n) {
                el2[r] = make_float2(plA[i], plB[i]);
                er2[r] = make_float2(prA[i], prB[i]);
                uu[r]  = make_float4(qlA[i], qlB[i], qrA[i], qrB[i]);
            }
        }
    }
}

// ---------------------------------------------------------------------------
// Sparse pass a: o = D^-1 A_w ft (+ scalar u columns if HASU).
// One wave/node; R7-proven gather: lane = dim (float2 both channels), unroll 4.
// ---------------------------------------------------------------------------
template <bool HASU>
__global__ __launch_bounds__(256) void agg1_ab(
        const int* __restrict__ rowp, const unsigned* __restrict__ csr,
        const float* __restrict__ filt, int fo0, int fo1,
        const float2* __restrict__ el, const float2* __restrict__ er,
        const float4* __restrict__ uu,
        const float2* __restrict__ ftAB, float2* __restrict__ oAB,
        float2* __restrict__ sb, float4* __restrict__ u1, int n) {
    __shared__ unsigned sPk[4][MAXD];
    __shared__ float2 sW2[4][MAXD];
    int w = (blockIdx.x * blockDim.x + threadIdx.x) >> 6;
    int lane = threadIdx.x & 63;
    int wv = threadIdx.x >> 6;
    if (w >= n) return;
    int base = rowp[w], end = rowp[w + 1];
    float fA0 = filt[fo0], fA1 = filt[fo0 + 1], fA2 = filt[fo0 + 2];
    float fB0 = filt[fo1], fB1 = filt[fo1 + 1], fB2 = filt[fo1 + 2];
    float2 erv = er[w];

    // lane-parallel: stage edges + weights, degw, softmax denom, u columns
    float degA = 0.f, degB = 0.f, ssA = 0.f, ssB = 0.f;
    float4 uacc = {0.f, 0.f, 0.f, 0.f};
    for (int j = base + lane; j < end; j += 64) {
        unsigned pk = csr[j];
        int d = j - base;
        int s = pk & 0x1FFFF;
        int r = pk >> 20;
        float wA = (r == 0) ? fA0 : ((r == 1) ? fA1 : fA2);
        float wB = (r == 0) ? fB0 : ((r == 1) ? fB1 : fB2);
        if (d < MAXD) { sPk[wv][d] = pk; sW2[wv][d] = make_float2(wA, wB); }
        degA += wA; degB += wB;
        float2 e2 = el[s];
        float xA = e2.x + erv.x;
        ssA += __expf(xA > 0.f ? xA : NEG_SLOPE * xA);
        float xB = e2.y + erv.y;
        ssB += __expf(xB > 0.f ? xB : NEG_SLOPE * xB);
        if (HASU) {
            float4 u = uu[s];
            uacc.x += wA * u.x; uacc.y += wB * u.y;
            uacc.z += wA * u.z; uacc.w += wB * u.w;
        }
    }
    for (int off = 32; off; off >>= 1) {
        degA += __shfl_xor(degA, off); degB += __shfl_xor(degB, off);
        ssA += __shfl_xor(ssA, off);   ssB += __shfl_xor(ssB, off);
        if (HASU) {
            uacc.x += __shfl_xor(uacc.x, off); uacc.y += __shfl_xor(uacc.y, off);
            uacc.z += __shfl_xor(uacc.z, off); uacc.w += __shfl_xor(uacc.w, off);
        }
    }
    float dA = degA > 0.f ? degA : 1.f;
    float dB = degB > 0.f ? degB : 1.f;

    // serial gather, lane = dim, unroll 4 (4 independent loads in flight)
    int deg = end - base;
    int dmax = deg < MAXD ? deg : MAXD;
    float accA = 0.f, accB = 0.f;
    int jj = 0;
    for (; jj + 4 <= dmax; jj += 4) {
        int s0 = sPk[wv][jj] & 0x1FFFF, s1 = sPk[wv][jj + 1] & 0x1FFFF;
        int s2 = sPk[wv][jj + 2] & 0x1FFFF, s3 = sPk[wv][jj + 3] & 0x1FFFF;
        float2 w0 = sW2[wv][jj], w1 = sW2[wv][jj + 1];
        float2 w2 = sW2[wv][jj + 2], w3 = sW2[wv][jj + 3];
        float2 v0 = ftAB[(size_t)s0 * 64 + lane];
        float2 v1 = ftAB[(size_t)s1 * 64 + lane];
        float2 v2 = ftAB[(size_t)s2 * 64 + lane];
        float2 v3 = ftAB[(size_t)s3 * 64 + lane];
        accA += w0.x * v0.x + w1.x * v1.x + w2.x * v2.x + w3.x * v3.x;
        accB += w0.y * v0.y + w1.y * v1.y + w2.y * v2.y + w3.y * v3.y;
    }
    for (; jj < dmax; ++jj) {
        int s = sPk[wv][jj] & 0x1FFFF;
        float2 wv2 = sW2[wv][jj];
        float2 v = ftAB[(size_t)s * 64 + lane];
        accA += wv2.x * v.x;
        accB += wv2.y * v.y;
    }
    for (int j = base + MAXD; j < end; ++j) {   // deg > MAXD fallback (~never)
        unsigned pk = csr[j];
        int s = pk & 0x1FFFF;
        int r = pk >> 20;
        float2 v = ftAB[(size_t)s * 64 + lane];
        accA += ((r == 0) ? fA0 : ((r == 1) ? fA1 : fA2)) * v.x;
        accB += ((r == 0) ? fB0 : ((r == 1) ? fB1 : fB2)) * v.y;
    }
    oAB[(size_t)w * 64 + lane] = make_float2(accA / dA, accB / dB);
    if (lane == 0) {
        sb[w] = make_float2(ssA > 0.f ? 1.f / ssA : 0.f,
                            ssB > 0.f ? 1.f / ssB : 0.f);
        if (HASU)
            u1[w] = make_float4(uacc.x / dA, uacc.y / dB, uacc.z / dA, uacc.w / dB);
    }
}

// ---------------------------------------------------------------------------
// Sparse pass b: o = S ft1 (softmax weights recomputed from el/er, sb);
// scalar u columns -> el/er of next layer if HASU.
// ---------------------------------------------------------------------------
template <bool HASU>
__global__ __launch_bounds__(256) void agg2_ab(
        const int* __restrict__ rowp, const unsigned* __restrict__ csr,
        const float2* __restrict__ el, const float2* __restrict__ er,
        const float2* __restrict__ sb, const float4* __restrict__ u1,
        const float2* __restrict__ ftAB, float2* __restrict__ oAB,
        float2* __restrict__ elout, float2* __restrict__ erout, int n) {
    __shared__ unsigned sPk[4][MAXD];
    __shared__ float2 sE[4][MAXD];
    int w = (blockIdx.x * blockDim.x + threadIdx.x) >> 6;
    int lane = threadIdx.x & 63;
    int wv = threadIdx.x >> 6;
    if (w >= n) return;
    int base = rowp[w], end = rowp[w + 1];
    float2 erv = er[w];
    float2 inv = sb[w];

    float4 uacc = {0.f, 0.f, 0.f, 0.f};
    for (int j = base + lane; j < end; j += 64) {
        unsigned pk = csr[j];
        int d = j - base;
        int s = pk & 0x1FFFF;
        float2 e2 = el[s];
        float xA = e2.x + erv.x;
        float xB = e2.y + erv.y;
        float eA = __expf(xA > 0.f ? xA : NEG_SLOPE * xA);
        float eB = __expf(xB > 0.f ? xB : NEG_SLOPE * xB);
        if (d < MAXD) { sPk[wv][d] = pk; sE[wv][d] = make_float2(eA, eB); }
        if (HASU) {
            float4 u = u1[s];
            uacc.x += eA * u.x; uacc.y += eB * u.y;
            uacc.z += eA * u.z; uacc.w += eB * u.w;
        }
    }
    if (HASU) {
        for (int off = 32; off; off >>= 1) {
            uacc.x += __shfl_xor(uacc.x, off); uacc.y += __shfl_xor(uacc.y, off);
            uacc.z += __shfl_xor(uacc.z, off); uacc.w += __shfl_xor(uacc.w, off);
        }
    }

    int deg = end - base;
    int dmax = deg < MAXD ? deg : MAXD;
    float accA = 0.f, accB = 0.f;
    int jj = 0;
    for (; jj + 4 <= dmax; jj += 4) {
        int s0 = sPk[wv][jj] & 0x1FFFF, s1 = sPk[wv][jj + 1] & 0x1FFFF;
        int s2 = sPk[wv][jj + 2] & 0x1FFFF, s3 = sPk[wv][jj + 3] & 0x1FFFF;
        float2 e0 = sE[wv][jj], e1 = sE[wv][jj + 1];
        float2 e2 = sE[wv][jj + 2], e3 = sE[wv][jj + 3];
        float2 v0 = ftAB[(size_t)s0 * 64 + lane];
        float2 v1 = ftAB[(size_t)s1 * 64 + lane];
        float2 v2 = ftAB[(size_t)s2 * 64 + lane];
        float2 v3 = ftAB[(size_t)s3 * 64 + lane];
        accA += e0.x * v0.x + e1.x * v1.x + e2.x * v2.x + e3.x * v3.x;
        accB += e0.y * v0.y + e1.y * v1.y + e2.y * v2.y + e3.y * v3.y;
    }
    for (; jj < dmax; ++jj) {
        int s = sPk[wv][jj] & 0x1FFFF;
        float2 ev = sE[wv][jj];
        float2 v = ftAB[(size_t)s * 64 + lane];
        accA += ev.x * v.x;
        accB += ev.y * v.y;
    }
    for (int j = base + MAXD; j < end; ++j) {   // fallback
        unsigned pk = csr[j];
        int s = pk & 0x1FFFF;
        float2 e2 = el[s];
        float xA = e2.x + erv.x;
        float xB = e2.y + erv.y;
        float2 v = ftAB[(size_t)s * 64 + lane];
        accA += __expf(xA > 0.f ? xA : NEG_SLOPE * xA) * v.x;
        accB += __expf(xB > 0.f ? xB : NEG_SLOPE * xB) * v.y;
    }
    oAB[(size_t)w * 64 + lane] = make_float2(accA * inv.x, accB * inv.y);
    if (HASU && lane == 0) {
        elout[w] = make_float2(uacc.x * inv.x, uacc.y * inv.y);
        erout[w] = make_float2(uacc.z * inv.x, uacc.w * inv.y);
    }
}

// ---------------------------------------------------------------------------
// Fused final: out = b2 + (lw0*A + lw1*B) @ WfcW2   (interleaved input)
// ---------------------------------------------------------------------------
__global__ __launch_bounds__(256) void gemm_out_ab(const float2* __restrict__ AAB,
                                                   const float* __restrict__ W,
                                                   const float* __restrict__ b2,
                                                   const float* __restrict__ lin_w,
                                                   float* __restrict__ out, int n) {
    __shared__ __align__(16) float sW[64 * 50];
    __shared__ __align__(16) float sA[64 * 68];
    int t = threadIdx.x;
    int row0 = blockIdx.x * 64;
    float lw0 = lin_w[0], lw1 = lin_w[1];
    for (int i = t; i < 64 * 50; i += 256) sW[i] = W[i];
    int rows = n - row0; if (rows > 64) rows = 64;
    for (int i = t * 4; i < 8192; i += 1024) {
        int r = i >> 7, c2 = i & 127;
        float4 v = {0.f, 0.f, 0.f, 0.f};
        if (r < rows) v = *(const float4*)((const float*)&AAB[(size_t)(row0 + r) * 64] + c2);
        int dim = c2 >> 1;
        sA[r * 68 + dim] = lw0 * v.x + lw1 * v.y;
        sA[r * 68 + dim + 1] = lw0 * v.z + lw1 * v.w;
    }
    __syncthreads();
    for (int i = t; i < 64 * 50; i += 256) {
        int r = i / 50, col = i - r * 50;
        if (row0 + r >= n) continue;
        float acc = 0.f;
#pragma unroll
        for (int k = 0; k < 64; ++k) acc += sA[r * 68 + k] * sW[k * 50 + col];
        out[(size_t)(row0 + r) * 50 + col] = b2[col] + acc;
    }
}

// ---------------------------------------------------------------------------
extern "C" void kernel_launch(void* const* d_in, const int* in_sizes, int n_in,
                              void* d_out, int out_size, void* d_ws, size_t ws_size,
                              hipStream_t stream) {
    const float* h      = (const float*)d_in[0];
    const float* params = (const float*)d_in[1];
    const float* gt_w   = (const float*)d_in[2];
    const float* fc_w   = (const float*)d_in[3];
    const float* attn_l = (const float*)d_in[4];
    const float* attn_r = (const float*)d_in[5];
    const float* lin_w  = (const float*)d_in[6];
    const float* W2     = (const float*)d_in[7];
    const float* b2     = (const float*)d_in[8];
    const int*   src    = (const int*)d_in[9];
    const int*   dst    = (const int*)d_in[10];
    const int*   rel    = (const int*)d_in[11];

    const int n = in_sizes[0] / 64;      // 100000 nodes
    const int m = in_sizes[9];           // 1.8M edges
    const int C = 2, L = 2;
    float* out = (float*)d_out;

    char* base = (char*)d_ws;
    size_t off = 0;
    auto alloc = [&](size_t bytes) -> char* {
        char* p = base + off;
        off = (off + bytes + 255) & ~(size_t)255;
        return p;
    };
    const int NB = (n + NPB - 1) >> NPB_SHIFT;
    const int nchunks = (m + SC_EDGES - 1) / SC_EDGES;
    float*    filt  = (float*)alloc(L * C * 3 * sizeof(float));
    float*    WcF   = (float*)alloc((size_t)C * 64 * 64 * 4);
    float*    WfcW2 = (float*)alloc((size_t)64 * 50 * 4);
    float2*   wlr   = (float2*)alloc((size_t)64 * 8);
    int*      bcnt  = (int*)alloc((size_t)NB * 4);
    int*      bbase = (int*)alloc((size_t)(NB + 1) * 4);
    int*      bcur  = (int*)alloc((size_t)NB * 4);
    int*      rowp  = (int*)alloc((size_t)(n + 1) * 4);
    unsigned* ebuf  = (unsigned*)alloc((size_t)m * 4);
    unsigned* csr   = (unsigned*)alloc((size_t)m * 4);
    float2*   el1   = (float2*)alloc((size_t)n * 8);
    float2*   er1   = (float2*)alloc((size_t)n * 8);
    float2*   elL2  = (float2*)alloc((size_t)n * 8);
    float2*   erL2  = (float2*)alloc((size_t)n * 8);
    float2*   sbAB  = (float2*)alloc((size_t)n * 8);
    float4*   uu    = (float4*)alloc((size_t)n * 16);
    float4*   u1    = (float4*)alloc((size_t)n * 16);
    float2*   FAB   = (float2*)alloc((size_t)n * 64 * 8);
    float2*   GAB   = (float2*)alloc((size_t)n * 64 * 8);
    float2*   HAB   = (float2*)alloc((size_t)n * 64 * 8);

    // ---- tiny precomputes + CSR build ----
    hipMemsetAsync(bcnt, 0, (size_t)NB * 4, stream);
    mkfilt<<<1, 64, 0, stream>>>(gt_w, filt, L * C);
    combw_kernel<<<C, 256, 0, stream>>>(params, fc_w, WcF);
    prep2_kernel<<<1, 256, 0, stream>>>(fc_w, W2, attn_l, attn_r, WfcW2, wlr);
    bcount_kernel<<<nchunks, 256, 0, stream>>>(dst, bcnt, m, NB);
    bscan_kernel<<<1, 1024, 0, stream>>>(bcnt, bbase, bcur, NB);
    bscatter_kernel<<<nchunks, 256, 0, stream>>>(src, dst, rel, bcur, ebuf, m, NB);
    bfinal_kernel<<<NB, 256, 0, stream>>>(ebuf, bbase, rowp, csr, n, m, NB);

    const int gB = (n + 63) / 64;
    const int waveBlocks = (n + 3) / 4;

    // F0 = h @ (params_c @ fc_w), fused el1/er1 + u columns
    gemm_f0<<<gB, 256, 0, stream>>>(h, WcF, FAB, n, attn_l, attn_r, wlr,
                                    el1, er1, uu);
    // layer 1 (carries u columns so layer-2 attention needs no dense GEMM)
    agg1_ab<true><<<waveBlocks, 256, 0, stream>>>(rowp, csr, filt, 0, 3,
                                                  el1, er1, uu,
                                                  FAB, GAB, sbAB, u1, n);
    agg2_ab<true><<<waveBlocks, 256, 0, stream>>>(rowp, csr, el1, er1, sbAB, u1,
                                                  GAB, HAB, elL2, erL2, n);
    // layer 2 (fc_w deferred into the output GEMM)
    agg1_ab<false><<<waveBlocks, 256, 0, stream>>>(rowp, csr, filt, 6, 9,
                                                   elL2, erL2, nullptr,
                                                   HAB, GAB, sbAB, nullptr, n);
    agg2_ab<false><<<waveBlocks, 256, 0, stream>>>(rowp, csr, elL2, erL2, sbAB, nullptr,
                                                   GAB, HAB, nullptr, nullptr, n);
    // out = b2 + (lw0*HA + lw1*HB) @ (fc_w @ W2)
    gemm_out_ab<<<gB, 256, 0, stream>>>(HAB, WfcW2, b2, lin_w, out, n);
}

// Round 10
// 732.673 us; speedup vs baseline: 1.0817x; 1.0765x over previous
//
#include <hip/hip_runtime.h>
#include <hip/hip_bf16.h>
#include <math.h>

#define NEG_SLOPE 0.2f
#define NPB_SHIFT 7
#define NPB 128          // nodes per bucket
#define SC_EDGES 16384   // edges per bscatter block
#define MAXD 128         // per-node edges staged in LDS

// ---------------------------------------------------------------------------
// filt[l][c][r] = softmax_r(gt_w[l][c][:])
// ---------------------------------------------------------------------------
__global__ void mkfilt(const float* __restrict__ gt_w, float* __restrict__ filt,
                       int rows) {
    int i = threadIdx.x;
    if (i < rows) {
        const float* g = gt_w + i * 3;
        float m = fmaxf(g[0], fmaxf(g[1], g[2]));
        float e0 = __expf(g[0] - m), e1 = __expf(g[1] - m), e2 = __expf(g[2] - m);
        float s = e0 + e1 + e2;
        filt[i * 3 + 0] = e0 / s;
        filt[i * 3 + 1] = e1 / s;
        filt[i * 3 + 2] = e2 / s;
    }
}

// ---------------------------------------------------------------------------
// WcF[c] = params[c] @ fc_w
// ---------------------------------------------------------------------------
__global__ __launch_bounds__(256) void combw_kernel(const float* __restrict__ params,
                                                    const float* __restrict__ fc_w,
                                                    float* __restrict__ WcF) {
    __shared__ __align__(16) float sP[64 * 64], sF[64 * 64];
    const float* P = params + (size_t)blockIdx.x * 64 * 64;
    int t = threadIdx.x;
    for (int i = t * 4; i < 4096; i += 1024) {
        *(float4*)&sP[i] = *(const float4*)&P[i];
        *(float4*)&sF[i] = *(const float4*)&fc_w[i];
    }
    __syncthreads();
    float* O = WcF + (size_t)blockIdx.x * 64 * 64;
    for (int i = t; i < 4096; i += 256) {
        int r = i >> 6, c = i & 63;
        float acc = 0.f;
#pragma unroll
        for (int k = 0; k < 64; ++k) acc += sP[r * 64 + k] * sF[k * 64 + c];
        O[i] = acc;
    }
}

// ---------------------------------------------------------------------------
// WfcW2 = fc_w @ W2 (64x50); wlr[i] = (fc_w[i]·attn_l, fc_w[i]·attn_r)
// ---------------------------------------------------------------------------
__global__ __launch_bounds__(256) void prep2_kernel(const float* __restrict__ fc_w,
                                                    const float* __restrict__ W2,
                                                    const float* __restrict__ attn_l,
                                                    const float* __restrict__ attn_r,
                                                    float* __restrict__ WfcW2,
                                                    float2* __restrict__ wlr) {
    __shared__ __align__(16) float sF[4096];
    __shared__ float sW[3200], sal[64], sar[64];
    int t = threadIdx.x;
    for (int i = t * 4; i < 4096; i += 1024)
        *(float4*)&sF[i] = *(const float4*)&fc_w[i];
    for (int i = t; i < 3200; i += 256) sW[i] = W2[i];
    if (t < 64) { sal[t] = attn_l[t]; sar[t] = attn_r[t]; }
    __syncthreads();
    if (t < 64) {
        float l = 0.f, r = 0.f;
#pragma unroll
        for (int k = 0; k < 64; ++k) {
            l += sF[t * 64 + k] * sal[k];
            r += sF[t * 64 + k] * sar[k];
        }
        wlr[t] = make_float2(l, r);
    }
    for (int i = t; i < 3200; i += 256) {
        int r = i / 50, c = i - r * 50;
        float acc = 0.f;
#pragma unroll
        for (int k = 0; k < 64; ++k) acc += sF[r * 64 + k] * sW[k * 50 + c];
        WfcW2[i] = acc;
    }
}

// ---------------------------------------------------------------------------
// Bucketed CSR build (unchanged)
// ---------------------------------------------------------------------------
__global__ __launch_bounds__(256) void bcount_kernel(const int* __restrict__ dst,
                                                     int* __restrict__ bcnt, int m, int NB) {
    __shared__ int h[1024];
    for (int i = threadIdx.x; i < NB; i += 256) h[i] = 0;
    __syncthreads();
    int base = blockIdx.x * SC_EDGES;
    int endi = base + SC_EDGES; if (endi > m) endi = m;
    for (int i = base + threadIdx.x; i < endi; i += 256)
        atomicAdd(&h[dst[i] >> NPB_SHIFT], 1);
    __syncthreads();
    for (int i = threadIdx.x; i < NB; i += 256)
        if (h[i]) atomicAdd(&bcnt[i], h[i]);
}

__global__ __launch_bounds__(1024) void bscan_kernel(const int* __restrict__ bcnt,
                                                     int* __restrict__ bbase,
                                                     int* __restrict__ bcur, int NB) {
    __shared__ int s[1024];
    int t = threadIdx.x;
    int v = (t < NB) ? bcnt[t] : 0;
    s[t] = v;
    __syncthreads();
    for (int off = 1; off < 1024; off <<= 1) {
        int u = (t >= off) ? s[t - off] : 0;
        __syncthreads();
        s[t] += u;
        __syncthreads();
    }
    if (t < NB) { bbase[t] = s[t] - v; bcur[t] = s[t] - v; }
    if (t == 1023) bbase[NB] = s[1023];
}

__global__ __launch_bounds__(256) void bscatter_kernel(const int* __restrict__ src,
                                                       const int* __restrict__ dst,
                                                       const int* __restrict__ rel,
                                                       int* __restrict__ bcur,
                                                       unsigned* __restrict__ ebuf,
                                                       int m, int NB) {
    __shared__ int cnt[1024];
    for (int i = threadIdx.x; i < NB; i += 256) cnt[i] = 0;
    __syncthreads();
    int base = blockIdx.x * SC_EDGES;
    int endi = base + SC_EDGES; if (endi > m) endi = m;
    for (int i = base + threadIdx.x; i < endi; i += 256)
        atomicAdd(&cnt[dst[i] >> NPB_SHIFT], 1);
    __syncthreads();
    for (int b = threadIdx.x; b < NB; b += 256) {
        int c = cnt[b];
        if (c) cnt[b] = atomicAdd(&bcur[b], c);
    }
    __syncthreads();
    for (int i = base + threadIdx.x; i < endi; i += 256) {
        int d = dst[i];
        int bk = d >> NPB_SHIFT;
        unsigned pk = (unsigned)src[i] | ((unsigned)rel[i] << 17) |
                      ((unsigned)(d & (NPB - 1)) << 19);
        int pos = atomicAdd(&cnt[bk], 1);
        ebuf[pos] = pk;
    }
}

__global__ __launch_bounds__(256) void bfinal_kernel(const unsigned* __restrict__ ebuf,
                                                     const int* __restrict__ bbase,
                                                     int* __restrict__ rowp,
                                                     unsigned* __restrict__ csr,
                                                     int n, int m, int NB) {
    __shared__ int cnt[NPB], cur[NPB], sc[NPB];
    int b = blockIdx.x;
    int t = threadIdx.x;
    int e0 = bbase[b], e1 = bbase[b + 1];
    if (t < NPB) cnt[t] = 0;
    __syncthreads();
    for (int j = e0 + t; j < e1; j += 256)
        atomicAdd(&cnt[(ebuf[j] >> 19) & (NPB - 1)], 1);
    __syncthreads();
    int v0 = (t < NPB) ? cnt[t] : 0;
    if (t < NPB) sc[t] = v0;
    __syncthreads();
    for (int off = 1; off < NPB; off <<= 1) {
        int u = (t >= off && t < NPB) ? sc[t - off] : 0;
        __syncthreads();
        if (t < NPB) sc[t] += u;
        __syncthreads();
    }
    if (t < NPB) {
        int ex = e0 + sc[t] - v0;
        cur[t] = ex;
        int v = b * NPB + t;
        if (v < n) rowp[v] = ex;
    }
    if (b == 0 && t == 0) rowp[n] = m;
    __syncthreads();
    for (int j = e0 + t; j < e1; j += 256) {
        unsigned pk = ebuf[j];
        int dl = (pk >> 19) & (NPB - 1);
        int pos = atomicAdd(&cur[dl], 1);
        csr[pos] = (pk & 0x1FFFF) | (((pk >> 17) & 3) << 20);
    }
}

// ---------------------------------------------------------------------------
// F0 dual GEMM: OAB = interleave(h@WcF0, h@WcF1); epilogue -> el1/er1 (float2).
// ---------------------------------------------------------------------------
__global__ __launch_bounds__(256) void gemm_f0(const float* __restrict__ A,
                                               const float* __restrict__ WcF,
                                               float2* __restrict__ OAB, int n,
                                               const float* __restrict__ attn_l,
                                               const float* __restrict__ attn_r,
                                               float2* __restrict__ el2,
                                               float2* __restrict__ er2) {
    __shared__ __align__(16) float sW[2][64 * 64];
    __shared__ __align__(16) float sA[64 * 68];
    __shared__ float sAl[64], sAr[64];
    int t = threadIdx.x;
    int row0 = blockIdx.x * 64;
    for (int i = t * 4; i < 8192; i += 1024)
        *(float4*)&sW[0][i] = *(const float4*)&WcF[i];
    if (t < 64) { sAl[t] = attn_l[t]; sAr[t] = attn_r[t]; }
    int rows = n - row0; if (rows > 64) rows = 64;
    for (int i = t * 4; i < 4096; i += 1024) {
        int r = i >> 6, c = i & 63;
        float4 v = {0.f, 0.f, 0.f, 0.f};
        if (r < rows) v = *(const float4*)&A[(size_t)(row0 + r) * 64 + c];
        *(float4*)&sA[r * 68 + c] = v;
    }
    __syncthreads();
    int tr = (t >> 4) * 4, tc = (t & 15) * 4;
    float accA[4][4] = {}, accB[4][4] = {};
#pragma unroll 4
    for (int k = 0; k < 64; k += 4) {
        float4 av[4];
#pragma unroll
        for (int i = 0; i < 4; ++i) av[i] = *(const float4*)&sA[(tr + i) * 68 + k];
#pragma unroll
        for (int kk = 0; kk < 4; ++kk) {
            float4 bA = *(const float4*)&sW[0][(k + kk) * 64 + tc];
            float4 bB = *(const float4*)&sW[1][(k + kk) * 64 + tc];
#pragma unroll
            for (int i = 0; i < 4; ++i) {
                float a = (&av[i].x)[kk];
                accA[i][0] += a * bA.x; accA[i][1] += a * bA.y;
                accA[i][2] += a * bA.z; accA[i][3] += a * bA.w;
                accB[i][0] += a * bB.x; accB[i][1] += a * bB.y;
                accB[i][2] += a * bB.z; accB[i][3] += a * bB.w;
            }
        }
    }
#pragma unroll
    for (int i = 0; i < 4; ++i) {
        int r = row0 + tr + i;
        if (r < n) {
            float4 v0 = {accA[i][0], accB[i][0], accA[i][1], accB[i][1]};
            float4 v1 = {accA[i][2], accB[i][2], accA[i][3], accB[i][3]};
            float* o = (float*)&OAB[(size_t)r * 64 + tc];
            *(float4*)o = v0;
            *(float4*)(o + 4) = v1;
        }
    }
    float plA[4], prA[4], plB[4], prB[4];
#pragma unroll
    for (int i = 0; i < 4; ++i) {
        float la = 0.f, ra = 0.f, lb = 0.f, rb = 0.f;
#pragma unroll
        for (int j = 0; j < 4; ++j) {
            la += accA[i][j] * sAl[tc + j]; ra += accA[i][j] * sAr[tc + j];
            lb += accB[i][j] * sAl[tc + j]; rb += accB[i][j] * sAr[tc + j];
        }
        plA[i] = la; prA[i] = ra; plB[i] = lb; prB[i] = rb;
    }
#pragma unroll
    for (int off = 1; off < 16; off <<= 1) {
#pragma unroll
        for (int i = 0; i < 4; ++i) {
            plA[i] += __shfl_xor(plA[i], off); prA[i] += __shfl_xor(prA[i], off);
            plB[i] += __shfl_xor(plB[i], off); prB[i] += __shfl_xor(prB[i], off);
        }
    }
    if ((t & 15) == 0) {
#pragma unroll
        for (int i = 0; i < 4; ++i) {
            int r = row0 + tr + i;
            if (r < n) {
                el2[r] = make_float2(plA[i], plB[i]);
                er2[r] = make_float2(prA[i], prB[i]);
            }
        }
    }
}

// ---------------------------------------------------------------------------
// Sparse pass a: o = D^-1 A_w ft. One wave per dst node; lane = dim (float2),
// unroll 4. Per-edge weights staged in LDS.
// ---------------------------------------------------------------------------
__global__ __launch_bounds__(256) void agg1_ab(
        const int* __restrict__ rowp, const unsigned* __restrict__ csr,
        const float* __restrict__ filt, int fo0, int fo1,
        const float2* __restrict__ el, const float2* __restrict__ er,
        const float2* __restrict__ ftAB, float2* __restrict__ oAB,
        float2* __restrict__ sb, int n) {
    __shared__ unsigned sPk[4][MAXD];
    __shared__ float2 sW2[4][MAXD];
    int w = (blockIdx.x * blockDim.x + threadIdx.x) >> 6;
    int lane = threadIdx.x & 63;
    int wv = threadIdx.x >> 6;
    if (w >= n) return;
    int base = rowp[w], end = rowp[w + 1];
    float fA0 = filt[fo0], fA1 = filt[fo0 + 1], fA2 = filt[fo0 + 2];
    float fB0 = filt[fo1], fB1 = filt[fo1 + 1], fB2 = filt[fo1 + 2];
    float2 erv = er[w];

    // lane-parallel: stage edges + weights, degw, softmax denom
    float degA = 0.f, degB = 0.f, ssA = 0.f, ssB = 0.f;
    for (int j = base + lane; j < end; j += 64) {
        unsigned pk = csr[j];
        int d = j - base;
        int s = pk & 0x1FFFF;
        int r = pk >> 20;
        float wA = (r == 0) ? fA0 : ((r == 1) ? fA1 : fA2);
        float wB = (r == 0) ? fB0 : ((r == 1) ? fB1 : fB2);
        if (d < MAXD) { sPk[wv][d] = pk; sW2[wv][d] = make_float2(wA, wB); }
        degA += wA; degB += wB;
        float2 e2 = el[s];
        float xA = e2.x + erv.x;
        ssA += __expf(xA > 0.f ? xA : NEG_SLOPE * xA);
        float xB = e2.y + erv.y;
        ssB += __expf(xB > 0.f ? xB : NEG_SLOPE * xB);
    }
    for (int off = 32; off; off >>= 1) {
        degA += __shfl_xor(degA, off); degB += __shfl_xor(degB, off);
        ssA += __shfl_xor(ssA, off);   ssB += __shfl_xor(ssB, off);
    }
    float dA = degA > 0.f ? degA : 1.f;
    float dB = degB > 0.f ? degB : 1.f;

    // serial gather, lane = dim, unroll 4 (4 independent loads in flight)
    int deg = end - base;
    int dmax = deg < MAXD ? deg : MAXD;
    float accA = 0.f, accB = 0.f;
    int jj = 0;
    for (; jj + 4 <= dmax; jj += 4) {
        int s0 = sPk[wv][jj] & 0x1FFFF, s1 = sPk[wv][jj + 1] & 0x1FFFF;
        int s2 = sPk[wv][jj + 2] & 0x1FFFF, s3 = sPk[wv][jj + 3] & 0x1FFFF;
        float2 w0 = sW2[wv][jj], w1 = sW2[wv][jj + 1];
        float2 w2 = sW2[wv][jj + 2], w3 = sW2[wv][jj + 3];
        float2 v0 = ftAB[(size_t)s0 * 64 + lane];
        float2 v1 = ftAB[(size_t)s1 * 64 + lane];
        float2 v2 = ftAB[(size_t)s2 * 64 + lane];
        float2 v3 = ftAB[(size_t)s3 * 64 + lane];
        accA += w0.x * v0.x + w1.x * v1.x + w2.x * v2.x + w3.x * v3.x;
        accB += w0.y * v0.y + w1.y * v1.y + w2.y * v2.y + w3.y * v3.y;
    }
    for (; jj < dmax; ++jj) {
        int s = sPk[wv][jj] & 0x1FFFF;
        float2 wv2 = sW2[wv][jj];
        float2 v = ftAB[(size_t)s * 64 + lane];
        accA += wv2.x * v.x;
        accB += wv2.y * v.y;
    }
    for (int j = base + MAXD; j < end; ++j) {   // deg > MAXD fallback (~never)
        unsigned pk = csr[j];
        int s = pk & 0x1FFFF;
        int r = pk >> 20;
        float2 v = ftAB[(size_t)s * 64 + lane];
        accA += ((r == 0) ? fA0 : ((r == 1) ? fA1 : fA2)) * v.x;
        accB += ((r == 0) ? fB0 : ((r == 1) ? fB1 : fB2)) * v.y;
    }
    oAB[(size_t)w * 64 + lane] = make_float2(accA / dA, accB / dB);
    if (lane == 0)
        sb[w] = make_float2(ssA > 0.f ? 1.f / ssA : 0.f,
                            ssB > 0.f ? 1.f / ssB : 0.f);
}

// ---------------------------------------------------------------------------
// Sparse pass b: o = S ft1 (softmax weights recomputed from el/er, sb).
// If EPI: epilogue computes next layer's el/er = wave-reduce(o-row · wl/wr)
// against the LDS-staged wlr table — zero extra memory traffic.
// ---------------------------------------------------------------------------
template <bool EPI>
__global__ __launch_bounds__(256) void agg2_ab(
        const int* __restrict__ rowp, const unsigned* __restrict__ csr,
        const float2* __restrict__ el, const float2* __restrict__ er,
        const float2* __restrict__ sb,
        const float2* __restrict__ ftAB, float2* __restrict__ oAB,
        const float2* __restrict__ wlr,
        float2* __restrict__ elout, float2* __restrict__ erout, int n) {
    __shared__ unsigned sPk[4][MAXD];
    __shared__ float2 sE[4][MAXD];
    __shared__ float2 sWlr[64];
    int t = threadIdx.x;
    if (EPI) {
        if (t < 64) sWlr[t] = wlr[t];
        __syncthreads();
    }
    int w = (blockIdx.x * blockDim.x + t) >> 6;
    int lane = t & 63;
    int wv = t >> 6;
    if (w >= n) return;
    int base = rowp[w], end = rowp[w + 1];
    float2 erv = er[w];
    float2 inv = sb[w];

    for (int j = base + lane; j < end; j += 64) {
        unsigned pk = csr[j];
        int d = j - base;
        int s = pk & 0x1FFFF;
        float2 e2 = el[s];
        float xA = e2.x + erv.x;
        float xB = e2.y + erv.y;
        float eA = __expf(xA > 0.f ? xA : NEG_SLOPE * xA);
        float eB = __expf(xB > 0.f ? xB : NEG_SLOPE * xB);
        if (d < MAXD) { sPk[wv][d] = pk; sE[wv][d] = make_float2(eA, eB); }
    }

    int deg = end - base;
    int dmax = deg < MAXD ? deg : MAXD;
    float accA = 0.f, accB = 0.f;
    int jj = 0;
    for (; jj + 4 <= dmax; jj += 4) {
        int s0 = sPk[wv][jj] & 0x1FFFF, s1 = sPk[wv][jj + 1] & 0x1FFFF;
        int s2 = sPk[wv][jj + 2] & 0x1FFFF, s3 = sPk[wv][jj + 3] & 0x1FFFF;
        float2 e0 = sE[wv][jj], e1 = sE[wv][jj + 1];
        float2 e2 = sE[wv][jj + 2], e3 = sE[wv][jj + 3];
        float2 v0 = ftAB[(size_t)s0 * 64 + lane];
        float2 v1 = ftAB[(size_t)s1 * 64 + lane];
        float2 v2 = ftAB[(size_t)s2 * 64 + lane];
        float2 v3 = ftAB[(size_t)s3 * 64 + lane];
        accA += e0.x * v0.x + e1.x * v1.x + e2.x * v2.x + e3.x * v3.x;
        accB += e0.y * v0.y + e1.y * v1.y + e2.y * v2.y + e3.y * v3.y;
    }
    for (; jj < dmax; ++jj) {
        int s = sPk[wv][jj] & 0x1FFFF;
        float2 ev = sE[wv][jj];
        float2 v = ftAB[(size_t)s * 64 + lane];
        accA += ev.x * v.x;
        accB += ev.y * v.y;
    }
    for (int j = base + MAXD; j < end; ++j) {   // fallback
        unsigned pk = csr[j];
        int s = pk & 0x1FFFF;
        float2 e2 = el[s];
        float xA = e2.x + erv.x;
        float xB = e2.y + erv.y;
        float2 v = ftAB[(size_t)s * 64 + lane];
        accA += __expf(xA > 0.f ? xA : NEG_SLOPE * xA) * v.x;
        accB += __expf(xB > 0.f ? xB : NEG_SLOPE * xB) * v.y;
    }
    float oA = accA * inv.x, oB = accB * inv.y;
    oAB[(size_t)w * 64 + lane] = make_float2(oA, oB);
    if (EPI) {
        // next-layer attention scalars: el' = o·wl, er' = o·wr (per channel)
        float2 wv2 = sWlr[lane];
        float elA = oA * wv2.x, elB = oB * wv2.x;
        float erA = oA * wv2.y, erB = oB * wv2.y;
        for (int off = 32; off; off >>= 1) {
            elA += __shfl_xor(elA, off); elB += __shfl_xor(elB, off);
            erA += __shfl_xor(erA, off); erB += __shfl_xor(erB, off);
        }
        if (lane == 0) {
            elout[w] = make_float2(elA, elB);
            erout[w] = make_float2(erA, erB);
        }
    }
}

// ---------------------------------------------------------------------------
// Fused final: out = b2 + (lw0*A + lw1*B) @ WfcW2   (interleaved input)
// ---------------------------------------------------------------------------
__global__ __launch_bounds__(256) void gemm_out_ab(const float2* __restrict__ AAB,
                                                   const float* __restrict__ W,
                                                   const float* __restrict__ b2,
                                                   const float* __restrict__ lin_w,
                                                   float* __restrict__ out, int n) {
    __shared__ __align__(16) float sW[64 * 50];
    __shared__ __align__(16) float sA[64 * 68];
    int t = threadIdx.x;
    int row0 = blockIdx.x * 64;
    float lw0 = lin_w[0], lw1 = lin_w[1];
    for (int i = t; i < 64 * 50; i += 256) sW[i] = W[i];
    int rows = n - row0; if (rows > 64) rows = 64;
    for (int i = t * 4; i < 8192; i += 1024) {
        int r = i >> 7, c2 = i & 127;
        float4 v = {0.f, 0.f, 0.f, 0.f};
        if (r < rows) v = *(const float4*)((const float*)&AAB[(size_t)(row0 + r) * 64] + c2);
        int dim = c2 >> 1;
        sA[r * 68 + dim] = lw0 * v.x + lw1 * v.y;
        sA[r * 68 + dim + 1] = lw0 * v.z + lw1 * v.w;
    }
    __syncthreads();
    for (int i = t; i < 64 * 50; i += 256) {
        int r = i / 50, col = i - r * 50;
        if (row0 + r >= n) continue;
        float acc = 0.f;
#pragma unroll
        for (int k = 0; k < 64; ++k) acc += sA[r * 68 + k] * sW[k * 50 + col];
        out[(size_t)(row0 + r) * 50 + col] = b2[col] + acc;
    }
}

// ---------------------------------------------------------------------------
extern "C" void kernel_launch(void* const* d_in, const int* in_sizes, int n_in,
                              void* d_out, int out_size, void* d_ws, size_t ws_size,
                              hipStream_t stream) {
    const float* h      = (const float*)d_in[0];
    const float* params = (const float*)d_in[1];
    const float* gt_w   = (const float*)d_in[2];
    const float* fc_w   = (const float*)d_in[3];
    const float* attn_l = (const float*)d_in[4];
    const float* attn_r = (const float*)d_in[5];
    const float* lin_w  = (const float*)d_in[6];
    const float* W2     = (const float*)d_in[7];
    const float* b2     = (const float*)d_in[8];
    const int*   src    = (const int*)d_in[9];
    const int*   dst    = (const int*)d_in[10];
    const int*   rel    = (const int*)d_in[11];

    const int n = in_sizes[0] / 64;      // 100000 nodes
    const int m = in_sizes[9];           // 1.8M edges
    const int C = 2, L = 2;
    float* out = (float*)d_out;

    char* base = (char*)d_ws;
    size_t off = 0;
    auto alloc = [&](size_t bytes) -> char* {
        char* p = base + off;
        off = (off + bytes + 255) & ~(size_t)255;
        return p;
    };
    const int NB = (n + NPB - 1) >> NPB_SHIFT;
    const int nchunks = (m + SC_EDGES - 1) / SC_EDGES;
    float*    filt  = (float*)alloc(L * C * 3 * sizeof(float));
    float*    WcF   = (float*)alloc((size_t)C * 64 * 64 * 4);
    float*    WfcW2 = (float*)alloc((size_t)64 * 50 * 4);
    float2*   wlr   = (float2*)alloc((size_t)64 * 8);
    int*      bcnt  = (int*)alloc((size_t)NB * 4);
    int*      bbase = (int*)alloc((size_t)(NB + 1) * 4);
    int*      bcur  = (int*)alloc((size_t)NB * 4);
    int*      rowp  = (int*)alloc((size_t)(n + 1) * 4);
    unsigned* ebuf  = (unsigned*)alloc((size_t)m * 4);
    unsigned* csr   = (unsigned*)alloc((size_t)m * 4);
    float2*   el1   = (float2*)alloc((size_t)n * 8);
    float2*   er1   = (float2*)alloc((size_t)n * 8);
    float2*   elL2  = (float2*)alloc((size_t)n * 8);
    float2*   erL2  = (float2*)alloc((size_t)n * 8);
    float2*   sbAB  = (float2*)alloc((size_t)n * 8);
    float2*   FAB   = (float2*)alloc((size_t)n * 64 * 8);
    float2*   GAB   = (float2*)alloc((size_t)n * 64 * 8);
    float2*   HAB   = (float2*)alloc((size_t)n * 64 * 8);

    // ---- tiny precomputes + CSR build ----
    hipMemsetAsync(bcnt, 0, (size_t)NB * 4, stream);
    mkfilt<<<1, 64, 0, stream>>>(gt_w, filt, L * C);
    combw_kernel<<<C, 256, 0, stream>>>(params, fc_w, WcF);
    prep2_kernel<<<1, 256, 0, stream>>>(fc_w, W2, attn_l, attn_r, WfcW2, wlr);
    bcount_kernel<<<nchunks, 256, 0, stream>>>(dst, bcnt, m, NB);
    bscan_kernel<<<1, 1024, 0, stream>>>(bcnt, bbase, bcur, NB);
    bscatter_kernel<<<nchunks, 256, 0, stream>>>(src, dst, rel, bcur, ebuf, m, NB);
    bfinal_kernel<<<NB, 256, 0, stream>>>(ebuf, bbase, rowp, csr, n, m, NB);

    const int gB = (n + 63) / 64;
    const int waveBlocks = (n + 3) / 4;

    // F0 = h @ (params_c @ fc_w), fused el1/er1
    gemm_f0<<<gB, 256, 0, stream>>>(h, WcF, FAB, n, attn_l, attn_r, el1, er1);
    // layer 1
    agg1_ab<<<waveBlocks, 256, 0, stream>>>(rowp, csr, filt, 0, 3,
                                            el1, er1, FAB, GAB, sbAB, n);
    agg2_ab<true><<<waveBlocks, 256, 0, stream>>>(rowp, csr, el1, er1, sbAB,
                                                  GAB, HAB, wlr, elL2, erL2, n);
    // layer 2 (fc_w deferred into the output GEMM)
    agg1_ab<<<waveBlocks, 256, 0, stream>>>(rowp, csr, filt, 6, 9,
                                            elL2, erL2, HAB, GAB, sbAB, n);
    agg2_ab<false><<<waveBlocks, 256, 0, stream>>>(rowp, csr, elL2, erL2, sbAB,
                                                   GAB, HAB, nullptr, nullptr, nullptr, n);
    // out = b2 + (lw0*HA + lw1*HB) @ (fc_w @ W2)
    gemm_out_ab<<<gB, 256, 0, stream>>>(HAB, WfcW2, b2, lin_w, out, n);
}

// Round 11
// 487.338 us; speedup vs baseline: 1.6262x; 1.5034x over previous
//
#include <hip/hip_runtime.h>
#include <hip/hip_bf16.h>
#include <math.h>

#define NEG_SLOPE 0.2f
#define NPB_SHIFT 7
#define NPB 128          // nodes per bucket
#define SC_EDGES 16384   // edges per bscatter block
#define MAXD 128         // per-node edges staged in LDS

// packed bf16 pair: lo = chA, hi = chB (RNE rounding)
__device__ __forceinline__ unsigned bpack(float a, float b) {
    unsigned ua = __float_as_uint(a);
    unsigned ub = __float_as_uint(b);
    ua += 0x7FFFu + ((ua >> 16) & 1u);
    ub += 0x7FFFu + ((ub >> 16) & 1u);
    return (ua >> 16) | (ub & 0xFFFF0000u);
}
__device__ __forceinline__ float2 bunpack(unsigned v) {
    return make_float2(__uint_as_float(v << 16),
                       __uint_as_float(v & 0xFFFF0000u));
}

// ---------------------------------------------------------------------------
// filt[l][c][r] = softmax_r(gt_w[l][c][:])
// ---------------------------------------------------------------------------
__global__ void mkfilt(const float* __restrict__ gt_w, float* __restrict__ filt,
                       int rows) {
    int i = threadIdx.x;
    if (i < rows) {
        const float* g = gt_w + i * 3;
        float m = fmaxf(g[0], fmaxf(g[1], g[2]));
        float e0 = __expf(g[0] - m), e1 = __expf(g[1] - m), e2 = __expf(g[2] - m);
        float s = e0 + e1 + e2;
        filt[i * 3 + 0] = e0 / s;
        filt[i * 3 + 1] = e1 / s;
        filt[i * 3 + 2] = e2 / s;
    }
}

// ---------------------------------------------------------------------------
// WcF[c] = params[c] @ fc_w
// ---------------------------------------------------------------------------
__global__ __launch_bounds__(256) void combw_kernel(const float* __restrict__ params,
                                                    const float* __restrict__ fc_w,
                                                    float* __restrict__ WcF) {
    __shared__ __align__(16) float sP[64 * 64], sF[64 * 64];
    const float* P = params + (size_t)blockIdx.x * 64 * 64;
    int t = threadIdx.x;
    for (int i = t * 4; i < 4096; i += 1024) {
        *(float4*)&sP[i] = *(const float4*)&P[i];
        *(float4*)&sF[i] = *(const float4*)&fc_w[i];
    }
    __syncthreads();
    float* O = WcF + (size_t)blockIdx.x * 64 * 64;
    for (int i = t; i < 4096; i += 256) {
        int r = i >> 6, c = i & 63;
        float acc = 0.f;
#pragma unroll
        for (int k = 0; k < 64; ++k) acc += sP[r * 64 + k] * sF[k * 64 + c];
        O[i] = acc;
    }
}

// ---------------------------------------------------------------------------
// WfcW2 = fc_w @ W2 (64x50); wlr[i] = (fc_w[i]·attn_l, fc_w[i]·attn_r)
// ---------------------------------------------------------------------------
__global__ __launch_bounds__(256) void prep2_kernel(const float* __restrict__ fc_w,
                                                    const float* __restrict__ W2,
                                                    const float* __restrict__ attn_l,
                                                    const float* __restrict__ attn_r,
                                                    float* __restrict__ WfcW2,
                                                    float2* __restrict__ wlr) {
    __shared__ __align__(16) float sF[4096];
    __shared__ float sW[3200], sal[64], sar[64];
    int t = threadIdx.x;
    for (int i = t * 4; i < 4096; i += 1024)
        *(float4*)&sF[i] = *(const float4*)&fc_w[i];
    for (int i = t; i < 3200; i += 256) sW[i] = W2[i];
    if (t < 64) { sal[t] = attn_l[t]; sar[t] = attn_r[t]; }
    __syncthreads();
    if (t < 64) {
        float l = 0.f, r = 0.f;
#pragma unroll
        for (int k = 0; k < 64; ++k) {
            l += sF[t * 64 + k] * sal[k];
            r += sF[t * 64 + k] * sar[k];
        }
        wlr[t] = make_float2(l, r);
    }
    for (int i = t; i < 3200; i += 256) {
        int r = i / 50, c = i - r * 50;
        float acc = 0.f;
#pragma unroll
        for (int k = 0; k < 64; ++k) acc += sF[r * 64 + k] * sW[k * 50 + c];
        WfcW2[i] = acc;
    }
}

// ---------------------------------------------------------------------------
// Bucketed CSR build (unchanged)
// ---------------------------------------------------------------------------
__global__ __launch_bounds__(256) void bcount_kernel(const int* __restrict__ dst,
                                                     int* __restrict__ bcnt, int m, int NB) {
    __shared__ int h[1024];
    for (int i = threadIdx.x; i < NB; i += 256) h[i] = 0;
    __syncthreads();
    int base = blockIdx.x * SC_EDGES;
    int endi = base + SC_EDGES; if (endi > m) endi = m;
    for (int i = base + threadIdx.x; i < endi; i += 256)
        atomicAdd(&h[dst[i] >> NPB_SHIFT], 1);
    __syncthreads();
    for (int i = threadIdx.x; i < NB; i += 256)
        if (h[i]) atomicAdd(&bcnt[i], h[i]);
}

__global__ __launch_bounds__(1024) void bscan_kernel(const int* __restrict__ bcnt,
                                                     int* __restrict__ bbase,
                                                     int* __restrict__ bcur, int NB) {
    __shared__ int s[1024];
    int t = threadIdx.x;
    int v = (t < NB) ? bcnt[t] : 0;
    s[t] = v;
    __syncthreads();
    for (int off = 1; off < 1024; off <<= 1) {
        int u = (t >= off) ? s[t - off] : 0;
        __syncthreads();
        s[t] += u;
        __syncthreads();
    }
    if (t < NB) { bbase[t] = s[t] - v; bcur[t] = s[t] - v; }
    if (t == 1023) bbase[NB] = s[1023];
}

__global__ __launch_bounds__(256) void bscatter_kernel(const int* __restrict__ src,
                                                       const int* __restrict__ dst,
                                                       const int* __restrict__ rel,
                                                       int* __restrict__ bcur,
                                                       unsigned* __restrict__ ebuf,
                                                       int m, int NB) {
    __shared__ int cnt[1024];
    for (int i = threadIdx.x; i < NB; i += 256) cnt[i] = 0;
    __syncthreads();
    int base = blockIdx.x * SC_EDGES;
    int endi = base + SC_EDGES; if (endi > m) endi = m;
    for (int i = base + threadIdx.x; i < endi; i += 256)
        atomicAdd(&cnt[dst[i] >> NPB_SHIFT], 1);
    __syncthreads();
    for (int b = threadIdx.x; b < NB; b += 256) {
        int c = cnt[b];
        if (c) cnt[b] = atomicAdd(&bcur[b], c);
    }
    __syncthreads();
    for (int i = base + threadIdx.x; i < endi; i += 256) {
        int d = dst[i];
        int bk = d >> NPB_SHIFT;
        unsigned pk = (unsigned)src[i] | ((unsigned)rel[i] << 17) |
                      ((unsigned)(d & (NPB - 1)) << 19);
        int pos = atomicAdd(&cnt[bk], 1);
        ebuf[pos] = pk;
    }
}

__global__ __launch_bounds__(256) void bfinal_kernel(const unsigned* __restrict__ ebuf,
                                                     const int* __restrict__ bbase,
                                                     int* __restrict__ rowp,
                                                     unsigned* __restrict__ csr,
                                                     int n, int m, int NB) {
    __shared__ int cnt[NPB], cur[NPB], sc[NPB];
    int b = blockIdx.x;
    int t = threadIdx.x;
    int e0 = bbase[b], e1 = bbase[b + 1];
    if (t < NPB) cnt[t] = 0;
    __syncthreads();
    for (int j = e0 + t; j < e1; j += 256)
        atomicAdd(&cnt[(ebuf[j] >> 19) & (NPB - 1)], 1);
    __syncthreads();
    int v0 = (t < NPB) ? cnt[t] : 0;
    if (t < NPB) sc[t] = v0;
    __syncthreads();
    for (int off = 1; off < NPB; off <<= 1) {
        int u = (t >= off && t < NPB) ? sc[t - off] : 0;
        __syncthreads();
        if (t < NPB) sc[t] += u;
        __syncthreads();
    }
    if (t < NPB) {
        int ex = e0 + sc[t] - v0;
        cur[t] = ex;
        int v = b * NPB + t;
        if (v < n) rowp[v] = ex;
    }
    if (b == 0 && t == 0) rowp[n] = m;
    __syncthreads();
    for (int j = e0 + t; j < e1; j += 256) {
        unsigned pk = ebuf[j];
        int dl = (pk >> 19) & (NPB - 1);
        int pos = atomicAdd(&cur[dl], 1);
        csr[pos] = (pk & 0x1FFFF) | (((pk >> 17) & 3) << 20);
    }
}

// ---------------------------------------------------------------------------
// F0 dual GEMM: OAB[r][d] = bpack((h@WcF0)[r][d], (h@WcF1)[r][d]);
// epilogue -> el1/er1 (float2, from f32 accumulators).
// ---------------------------------------------------------------------------
__global__ __launch_bounds__(256) void gemm_f0(const float* __restrict__ A,
                                               const float* __restrict__ WcF,
                                               unsigned* __restrict__ OAB, int n,
                                               const float* __restrict__ attn_l,
                                               const float* __restrict__ attn_r,
                                               float2* __restrict__ el2,
                                               float2* __restrict__ er2) {
    __shared__ __align__(16) float sW[2][64 * 64];
    __shared__ __align__(16) float sA[64 * 68];
    __shared__ float sAl[64], sAr[64];
    int t = threadIdx.x;
    int row0 = blockIdx.x * 64;
    for (int i = t * 4; i < 8192; i += 1024)
        *(float4*)&sW[0][i] = *(const float4*)&WcF[i];
    if (t < 64) { sAl[t] = attn_l[t]; sAr[t] = attn_r[t]; }
    int rows = n - row0; if (rows > 64) rows = 64;
    for (int i = t * 4; i < 4096; i += 1024) {
        int r = i >> 6, c = i & 63;
        float4 v = {0.f, 0.f, 0.f, 0.f};
        if (r < rows) v = *(const float4*)&A[(size_t)(row0 + r) * 64 + c];
        *(float4*)&sA[r * 68 + c] = v;
    }
    __syncthreads();
    int tr = (t >> 4) * 4, tc = (t & 15) * 4;
    float accA[4][4] = {}, accB[4][4] = {};
#pragma unroll 4
    for (int k = 0; k < 64; k += 4) {
        float4 av[4];
#pragma unroll
        for (int i = 0; i < 4; ++i) av[i] = *(const float4*)&sA[(tr + i) * 68 + k];
#pragma unroll
        for (int kk = 0; kk < 4; ++kk) {
            float4 bA = *(const float4*)&sW[0][(k + kk) * 64 + tc];
            float4 bB = *(const float4*)&sW[1][(k + kk) * 64 + tc];
#pragma unroll
            for (int i = 0; i < 4; ++i) {
                float a = (&av[i].x)[kk];
                accA[i][0] += a * bA.x; accA[i][1] += a * bA.y;
                accA[i][2] += a * bA.z; accA[i][3] += a * bA.w;
                accB[i][0] += a * bB.x; accB[i][1] += a * bB.y;
                accB[i][2] += a * bB.z; accB[i][3] += a * bB.w;
            }
        }
    }
#pragma unroll
    for (int i = 0; i < 4; ++i) {
        int r = row0 + tr + i;
        if (r < n) {
            uint4 v = {bpack(accA[i][0], accB[i][0]), bpack(accA[i][1], accB[i][1]),
                       bpack(accA[i][2], accB[i][2]), bpack(accA[i][3], accB[i][3])};
            *(uint4*)&OAB[(size_t)r * 64 + tc] = v;
        }
    }
    float plA[4], prA[4], plB[4], prB[4];
#pragma unroll
    for (int i = 0; i < 4; ++i) {
        float la = 0.f, ra = 0.f, lb = 0.f, rb = 0.f;
#pragma unroll
        for (int j = 0; j < 4; ++j) {
            la += accA[i][j] * sAl[tc + j]; ra += accA[i][j] * sAr[tc + j];
            lb += accB[i][j] * sAl[tc + j]; rb += accB[i][j] * sAr[tc + j];
        }
        plA[i] = la; prA[i] = ra; plB[i] = lb; prB[i] = rb;
    }
#pragma unroll
    for (int off = 1; off < 16; off <<= 1) {
#pragma unroll
        for (int i = 0; i < 4; ++i) {
            plA[i] += __shfl_xor(plA[i], off); prA[i] += __shfl_xor(prA[i], off);
            plB[i] += __shfl_xor(plB[i], off); prB[i] += __shfl_xor(prB[i], off);
        }
    }
    if ((t & 15) == 0) {
#pragma unroll
        for (int i = 0; i < 4; ++i) {
            int r = row0 + tr + i;
            if (r < n) {
                el2[r] = make_float2(plA[i], plB[i]);
                er2[r] = make_float2(prA[i], prB[i]);
            }
        }
    }
}

// ---------------------------------------------------------------------------
// Sparse pass a: o = D^-1 A_w ft. One wave per dst node; lane = dim,
// packed bf16x2 gather (4 B/lane), f32 accumulate, unroll 4.
// ---------------------------------------------------------------------------
__global__ __launch_bounds__(256) void agg1_ab(
        const int* __restrict__ rowp, const unsigned* __restrict__ csr,
        const float* __restrict__ filt, int fo0, int fo1,
        const float2* __restrict__ el, const float2* __restrict__ er,
        const unsigned* __restrict__ ftAB, unsigned* __restrict__ oAB,
        float2* __restrict__ sb, int n) {
    __shared__ unsigned sPk[4][MAXD];
    __shared__ float2 sW2[4][MAXD];
    int w = (blockIdx.x * blockDim.x + threadIdx.x) >> 6;
    int lane = threadIdx.x & 63;
    int wv = threadIdx.x >> 6;
    if (w >= n) return;
    int base = rowp[w], end = rowp[w + 1];
    float fA0 = filt[fo0], fA1 = filt[fo0 + 1], fA2 = filt[fo0 + 2];
    float fB0 = filt[fo1], fB1 = filt[fo1 + 1], fB2 = filt[fo1 + 2];
    float2 erv = er[w];

    // lane-parallel: stage edges + weights, degw, softmax denom
    float degA = 0.f, degB = 0.f, ssA = 0.f, ssB = 0.f;
    for (int j = base + lane; j < end; j += 64) {
        unsigned pk = csr[j];
        int d = j - base;
        int s = pk & 0x1FFFF;
        int r = pk >> 20;
        float wA = (r == 0) ? fA0 : ((r == 1) ? fA1 : fA2);
        float wB = (r == 0) ? fB0 : ((r == 1) ? fB1 : fB2);
        if (d < MAXD) { sPk[wv][d] = pk; sW2[wv][d] = make_float2(wA, wB); }
        degA += wA; degB += wB;
        float2 e2 = el[s];
        float xA = e2.x + erv.x;
        ssA += __expf(xA > 0.f ? xA : NEG_SLOPE * xA);
        float xB = e2.y + erv.y;
        ssB += __expf(xB > 0.f ? xB : NEG_SLOPE * xB);
    }
    for (int off = 32; off; off >>= 1) {
        degA += __shfl_xor(degA, off); degB += __shfl_xor(degB, off);
        ssA += __shfl_xor(ssA, off);   ssB += __shfl_xor(ssB, off);
    }
    float dA = degA > 0.f ? degA : 1.f;
    float dB = degB > 0.f ? degB : 1.f;

    // serial gather, lane = dim, unroll 4
    int deg = end - base;
    int dmax = deg < MAXD ? deg : MAXD;
    float accA = 0.f, accB = 0.f;
    int jj = 0;
    for (; jj + 4 <= dmax; jj += 4) {
        int s0 = sPk[wv][jj] & 0x1FFFF, s1 = sPk[wv][jj + 1] & 0x1FFFF;
        int s2 = sPk[wv][jj + 2] & 0x1FFFF, s3 = sPk[wv][jj + 3] & 0x1FFFF;
        float2 w0 = sW2[wv][jj], w1 = sW2[wv][jj + 1];
        float2 w2 = sW2[wv][jj + 2], w3 = sW2[wv][jj + 3];
        float2 v0 = bunpack(ftAB[(size_t)s0 * 64 + lane]);
        float2 v1 = bunpack(ftAB[(size_t)s1 * 64 + lane]);
        float2 v2 = bunpack(ftAB[(size_t)s2 * 64 + lane]);
        float2 v3 = bunpack(ftAB[(size_t)s3 * 64 + lane]);
        accA += w0.x * v0.x + w1.x * v1.x + w2.x * v2.x + w3.x * v3.x;
        accB += w0.y * v0.y + w1.y * v1.y + w2.y * v2.y + w3.y * v3.y;
    }
    for (; jj < dmax; ++jj) {
        int s = sPk[wv][jj] & 0x1FFFF;
        float2 wv2 = sW2[wv][jj];
        float2 v = bunpack(ftAB[(size_t)s * 64 + lane]);
        accA += wv2.x * v.x;
        accB += wv2.y * v.y;
    }
    for (int j = base + MAXD; j < end; ++j) {   // deg > MAXD fallback (~never)
        unsigned pk = csr[j];
        int s = pk & 0x1FFFF;
        int r = pk >> 20;
        float2 v = bunpack(ftAB[(size_t)s * 64 + lane]);
        accA += ((r == 0) ? fA0 : ((r == 1) ? fA1 : fA2)) * v.x;
        accB += ((r == 0) ? fB0 : ((r == 1) ? fB1 : fB2)) * v.y;
    }
    oAB[(size_t)w * 64 + lane] = bpack(accA / dA, accB / dB);
    if (lane == 0)
        sb[w] = make_float2(ssA > 0.f ? 1.f / ssA : 0.f,
                            ssB > 0.f ? 1.f / ssB : 0.f);
}

// ---------------------------------------------------------------------------
// Sparse pass b: o = S ft1. If EPI: next layer's el/er from f32 output row
// (wave reduce vs LDS wlr table) — zero extra memory traffic.
// ---------------------------------------------------------------------------
template <bool EPI>
__global__ __launch_bounds__(256) void agg2_ab(
        const int* __restrict__ rowp, const unsigned* __restrict__ csr,
        const float2* __restrict__ el, const float2* __restrict__ er,
        const float2* __restrict__ sb,
        const unsigned* __restrict__ ftAB, unsigned* __restrict__ oAB,
        const float2* __restrict__ wlr,
        float2* __restrict__ elout, float2* __restrict__ erout, int n) {
    __shared__ unsigned sPk[4][MAXD];
    __shared__ float2 sE[4][MAXD];
    __shared__ float2 sWlr[64];
    int t = threadIdx.x;
    if (EPI) {
        if (t < 64) sWlr[t] = wlr[t];
        __syncthreads();
    }
    int w = (blockIdx.x * blockDim.x + t) >> 6;
    int lane = t & 63;
    int wv = t >> 6;
    if (w >= n) return;
    int base = rowp[w], end = rowp[w + 1];
    float2 erv = er[w];
    float2 inv = sb[w];

    for (int j = base + lane; j < end; j += 64) {
        unsigned pk = csr[j];
        int d = j - base;
        int s = pk & 0x1FFFF;
        float2 e2 = el[s];
        float xA = e2.x + erv.x;
        float xB = e2.y + erv.y;
        float eA = __expf(xA > 0.f ? xA : NEG_SLOPE * xA);
        float eB = __expf(xB > 0.f ? xB : NEG_SLOPE * xB);
        if (d < MAXD) { sPk[wv][d] = pk; sE[wv][d] = make_float2(eA, eB); }
    }

    int deg = end - base;
    int dmax = deg < MAXD ? deg : MAXD;
    float accA = 0.f, accB = 0.f;
    int jj = 0;
    for (; jj + 4 <= dmax; jj += 4) {
        int s0 = sPk[wv][jj] & 0x1FFFF, s1 = sPk[wv][jj + 1] & 0x1FFFF;
        int s2 = sPk[wv][jj + 2] & 0x1FFFF, s3 = sPk[wv][jj + 3] & 0x1FFFF;
        float2 e0 = sE[wv][jj], e1 = sE[wv][jj + 1];
        float2 e2 = sE[wv][jj + 2], e3 = sE[wv][jj + 3];
        float2 v0 = bunpack(ftAB[(size_t)s0 * 64 + lane]);
        float2 v1 = bunpack(ftAB[(size_t)s1 * 64 + lane]);
        float2 v2 = bunpack(ftAB[(size_t)s2 * 64 + lane]);
        float2 v3 = bunpack(ftAB[(size_t)s3 * 64 + lane]);
        accA += e0.x * v0.x + e1.x * v1.x + e2.x * v2.x + e3.x * v3.x;
        accB += e0.y * v0.y + e1.y * v1.y + e2.y * v2.y + e3.y * v3.y;
    }
    for (; jj < dmax; ++jj) {
        int s = sPk[wv][jj] & 0x1FFFF;
        float2 ev = sE[wv][jj];
        float2 v = bunpack(ftAB[(size_t)s * 64 + lane]);
        accA += ev.x * v.x;
        accB += ev.y * v.y;
    }
    for (int j = base + MAXD; j < end; ++j) {   // fallback
        unsigned pk = csr[j];
        int s = pk & 0x1FFFF;
        float2 e2 = el[s];
        float xA = e2.x + erv.x;
        float xB = e2.y + erv.y;
        float2 v = bunpack(ftAB[(size_t)s * 64 + lane]);
        accA += __expf(xA > 0.f ? xA : NEG_SLOPE * xA) * v.x;
        accB += __expf(xB > 0.f ? xB : NEG_SLOPE * xB) * v.y;
    }
    float oA = accA * inv.x, oB = accB * inv.y;
    oAB[(size_t)w * 64 + lane] = bpack(oA, oB);
    if (EPI) {
        float2 wv2 = sWlr[lane];
        float elA = oA * wv2.x, elB = oB * wv2.x;
        float erA = oA * wv2.y, erB = oB * wv2.y;
        for (int off = 32; off; off >>= 1) {
            elA += __shfl_xor(elA, off); elB += __shfl_xor(elB, off);
            erA += __shfl_xor(erA, off); erB += __shfl_xor(erB, off);
        }
        if (lane == 0) {
            elout[w] = make_float2(elA, elB);
            erout[w] = make_float2(erA, erB);
        }
    }
}

// ---------------------------------------------------------------------------
// Fused final: out = b2 + (lw0*A + lw1*B) @ WfcW2   (packed bf16x2 input)
// ---------------------------------------------------------------------------
__global__ __launch_bounds__(256) void gemm_out_ab(const unsigned* __restrict__ AAB,
                                                   const float* __restrict__ W,
                                                   const float* __restrict__ b2,
                                                   const float* __restrict__ lin_w,
                                                   float* __restrict__ out, int n) {
    __shared__ __align__(16) float sW[64 * 50];
    __shared__ __align__(16) float sA[64 * 68];
    int t = threadIdx.x;
    int row0 = blockIdx.x * 64;
    float lw0 = lin_w[0], lw1 = lin_w[1];
    for (int i = t; i < 64 * 50; i += 256) sW[i] = W[i];
    int rows = n - row0; if (rows > 64) rows = 64;
    for (int i = t * 4; i < 4096; i += 1024) {
        int r = i >> 6, c = i & 63;
        uint4 v = {0u, 0u, 0u, 0u};
        if (r < rows) v = *(const uint4*)&AAB[(size_t)(row0 + r) * 64 + c];
        float2 f0 = bunpack(v.x), f1 = bunpack(v.y);
        float2 f2 = bunpack(v.z), f3 = bunpack(v.w);
        sA[r * 68 + c]     = lw0 * f0.x + lw1 * f0.y;
        sA[r * 68 + c + 1] = lw0 * f1.x + lw1 * f1.y;
        sA[r * 68 + c + 2] = lw0 * f2.x + lw1 * f2.y;
        sA[r * 68 + c + 3] = lw0 * f3.x + lw1 * f3.y;
    }
    __syncthreads();
    for (int i = t; i < 64 * 50; i += 256) {
        int r = i / 50, col = i - r * 50;
        if (row0 + r >= n) continue;
        float acc = 0.f;
#pragma unroll
        for (int k = 0; k < 64; ++k) acc += sA[r * 68 + k] * sW[k * 50 + col];
        out[(size_t)(row0 + r) * 50 + col] = b2[col] + acc;
    }
}

// ---------------------------------------------------------------------------
extern "C" void kernel_launch(void* const* d_in, const int* in_sizes, int n_in,
                              void* d_out, int out_size, void* d_ws, size_t ws_size,
                              hipStream_t stream) {
    const float* h      = (const float*)d_in[0];
    const float* params = (const float*)d_in[1];
    const float* gt_w   = (const float*)d_in[2];
    const float* fc_w   = (const float*)d_in[3];
    const float* attn_l = (const float*)d_in[4];
    const float* attn_r = (const float*)d_in[5];
    const float* lin_w  = (const float*)d_in[6];
    const float* W2     = (const float*)d_in[7];
    const float* b2     = (const float*)d_in[8];
    const int*   src    = (const int*)d_in[9];
    const int*   dst    = (const int*)d_in[10];
    const int*   rel    = (const int*)d_in[11];

    const int n = in_sizes[0] / 64;      // 100000 nodes
    const int m = in_sizes[9];           // 1.8M edges
    const int C = 2, L = 2;
    float* out = (float*)d_out;

    char* base = (char*)d_ws;
    size_t off = 0;
    auto alloc = [&](size_t bytes) -> char* {
        char* p = base + off;
        off = (off + bytes + 255) & ~(size_t)255;
        return p;
    };
    const int NB = (n + NPB - 1) >> NPB_SHIFT;
    const int nchunks = (m + SC_EDGES - 1) / SC_EDGES;
    float*    filt  = (float*)alloc(L * C * 3 * sizeof(float));
    float*    WcF   = (float*)alloc((size_t)C * 64 * 64 * 4);
    float*    WfcW2 = (float*)alloc((size_t)64 * 50 * 4);
    float2*   wlr   = (float2*)alloc((size_t)64 * 8);
    int*      bcnt  = (int*)alloc((size_t)NB * 4);
    int*      bbase = (int*)alloc((size_t)(NB + 1) * 4);
    int*      bcur  = (int*)alloc((size_t)NB * 4);
    int*      rowp  = (int*)alloc((size_t)(n + 1) * 4);
    unsigned* ebuf  = (unsigned*)alloc((size_t)m * 4);
    unsigned* csr   = (unsigned*)alloc((size_t)m * 4);
    float2*   el1   = (float2*)alloc((size_t)n * 8);
    float2*   er1   = (float2*)alloc((size_t)n * 8);
    float2*   elL2  = (float2*)alloc((size_t)n * 8);
    float2*   erL2  = (float2*)alloc((size_t)n * 8);
    float2*   sbAB  = (float2*)alloc((size_t)n * 8);
    unsigned* FAB   = (unsigned*)alloc((size_t)n * 64 * 4);   // packed bf16x2
    unsigned* GAB   = (unsigned*)alloc((size_t)n * 64 * 4);
    unsigned* HAB   = (unsigned*)alloc((size_t)n * 64 * 4);

    // ---- tiny precomputes + CSR build ----
    hipMemsetAsync(bcnt, 0, (size_t)NB * 4, stream);
    mkfilt<<<1, 64, 0, stream>>>(gt_w, filt, L * C);
    combw_kernel<<<C, 256, 0, stream>>>(params, fc_w, WcF);
    prep2_kernel<<<1, 256, 0, stream>>>(fc_w, W2, attn_l, attn_r, WfcW2, wlr);
    bcount_kernel<<<nchunks, 256, 0, stream>>>(dst, bcnt, m, NB);
    bscan_kernel<<<1, 1024, 0, stream>>>(bcnt, bbase, bcur, NB);
    bscatter_kernel<<<nchunks, 256, 0, stream>>>(src, dst, rel, bcur, ebuf, m, NB);
    bfinal_kernel<<<NB, 256, 0, stream>>>(ebuf, bbase, rowp, csr, n, m, NB);

    const int gB = (n + 63) / 64;
    const int waveBlocks = (n + 3) / 4;

    // F0 = h @ (params_c @ fc_w), fused el1/er1
    gemm_f0<<<gB, 256, 0, stream>>>(h, WcF, FAB, n, attn_l, attn_r, el1, er1);
    // layer 1
    agg1_ab<<<waveBlocks, 256, 0, stream>>>(rowp, csr, filt, 0, 3,
                                            el1, er1, FAB, GAB, sbAB, n);
    agg2_ab<true><<<waveBlocks, 256, 0, stream>>>(rowp, csr, el1, er1, sbAB,
                                                  GAB, HAB, wlr, elL2, erL2, n);
    // layer 2 (fc_w deferred into the output GEMM)
    agg1_ab<<<waveBlocks, 256, 0, stream>>>(rowp, csr, filt, 6, 9,
                                            elL2, erL2, HAB, GAB, sbAB, n);
    agg2_ab<false><<<waveBlocks, 256, 0, stream>>>(rowp, csr, elL2, erL2, sbAB,
                                                   GAB, HAB, nullptr, nullptr, nullptr, n);
    // out = b2 + (lw0*HA + lw1*HB) @ (fc_w @ W2)
    gemm_out_ab<<<gB, 256, 0, stream>>>(HAB, WfcW2, b2, lin_w, out, n);
}

// Round 12
// 478.006 us; speedup vs baseline: 1.6579x; 1.0195x over previous
//
#include <hip/hip_runtime.h>
#include <hip/hip_bf16.h>
#include <hip/hip_fp16.h>
#include <math.h>

#define NEG_SLOPE 0.2f
#define NPB_SHIFT 7
#define NPB 128          // nodes per bucket
#define SC_EDGES 16384   // edges per bscatter block
#define MAXD 128         // per-node edges staged in LDS

// packed f16 pair: lo = chA, hi = chB (RN rounding)
__device__ __forceinline__ unsigned hpack(float a, float b) {
    __half2 h = __floats2half2_rn(a, b);
    return *(unsigned*)&h;
}
__device__ __forceinline__ float2 hunpack(unsigned v) {
    __half2 h = *(__half2*)&v;
    return make_float2(__low2float(h), __high2float(h));
}

// ---------------------------------------------------------------------------
// filt[l][c][r] = softmax_r(gt_w[l][c][:])
// ---------------------------------------------------------------------------
__global__ void mkfilt(const float* __restrict__ gt_w, float* __restrict__ filt,
                       int rows) {
    int i = threadIdx.x;
    if (i < rows) {
        const float* g = gt_w + i * 3;
        float m = fmaxf(g[0], fmaxf(g[1], g[2]));
        float e0 = __expf(g[0] - m), e1 = __expf(g[1] - m), e2 = __expf(g[2] - m);
        float s = e0 + e1 + e2;
        filt[i * 3 + 0] = e0 / s;
        filt[i * 3 + 1] = e1 / s;
        filt[i * 3 + 2] = e2 / s;
    }
}

// ---------------------------------------------------------------------------
// WcF[c] = params[c] @ fc_w
// ---------------------------------------------------------------------------
__global__ __launch_bounds__(256) void combw_kernel(const float* __restrict__ params,
                                                    const float* __restrict__ fc_w,
                                                    float* __restrict__ WcF) {
    __shared__ __align__(16) float sP[64 * 64], sF[64 * 64];
    const float* P = params + (size_t)blockIdx.x * 64 * 64;
    int t = threadIdx.x;
    for (int i = t * 4; i < 4096; i += 1024) {
        *(float4*)&sP[i] = *(const float4*)&P[i];
        *(float4*)&sF[i] = *(const float4*)&fc_w[i];
    }
    __syncthreads();
    float* O = WcF + (size_t)blockIdx.x * 64 * 64;
    for (int i = t; i < 4096; i += 256) {
        int r = i >> 6, c = i & 63;
        float acc = 0.f;
#pragma unroll
        for (int k = 0; k < 64; ++k) acc += sP[r * 64 + k] * sF[k * 64 + c];
        O[i] = acc;
    }
}

// ---------------------------------------------------------------------------
// WfcW2 = fc_w @ W2 (64x50); wlr[i] = (fc_w[i]·attn_l, fc_w[i]·attn_r)
// ---------------------------------------------------------------------------
__global__ __launch_bounds__(256) void prep2_kernel(const float* __restrict__ fc_w,
                                                    const float* __restrict__ W2,
                                                    const float* __restrict__ attn_l,
                                                    const float* __restrict__ attn_r,
                                                    float* __restrict__ WfcW2,
                                                    float2* __restrict__ wlr) {
    __shared__ __align__(16) float sF[4096];
    __shared__ float sW[3200], sal[64], sar[64];
    int t = threadIdx.x;
    for (int i = t * 4; i < 4096; i += 1024)
        *(float4*)&sF[i] = *(const float4*)&fc_w[i];
    for (int i = t; i < 3200; i += 256) sW[i] = W2[i];
    if (t < 64) { sal[t] = attn_l[t]; sar[t] = attn_r[t]; }
    __syncthreads();
    if (t < 64) {
        float l = 0.f, r = 0.f;
#pragma unroll
        for (int k = 0; k < 64; ++k) {
            l += sF[t * 64 + k] * sal[k];
            r += sF[t * 64 + k] * sar[k];
        }
        wlr[t] = make_float2(l, r);
    }
    for (int i = t; i < 3200; i += 256) {
        int r = i / 50, c = i - r * 50;
        float acc = 0.f;
#pragma unroll
        for (int k = 0; k < 64; ++k) acc += sF[r * 64 + k] * sW[k * 50 + c];
        WfcW2[i] = acc;
    }
}

// ---------------------------------------------------------------------------
// Bucketed CSR build (unchanged)
// ---------------------------------------------------------------------------
__global__ __launch_bounds__(256) void bcount_kernel(const int* __restrict__ dst,
                                                     int* __restrict__ bcnt, int m, int NB) {
    __shared__ int h[1024];
    for (int i = threadIdx.x; i < NB; i += 256) h[i] = 0;
    __syncthreads();
    int base = blockIdx.x * SC_EDGES;
    int endi = base + SC_EDGES; if (endi > m) endi = m;
    for (int i = base + threadIdx.x; i < endi; i += 256)
        atomicAdd(&h[dst[i] >> NPB_SHIFT], 1);
    __syncthreads();
    for (int i = threadIdx.x; i < NB; i += 256)
        if (h[i]) atomicAdd(&bcnt[i], h[i]);
}

__global__ __launch_bounds__(1024) void bscan_kernel(const int* __restrict__ bcnt,
                                                     int* __restrict__ bbase,
                                                     int* __restrict__ bcur, int NB) {
    __shared__ int s[1024];
    int t = threadIdx.x;
    int v = (t < NB) ? bcnt[t] : 0;
    s[t] = v;
    __syncthreads();
    for (int off = 1; off < 1024; off <<= 1) {
        int u = (t >= off) ? s[t - off] : 0;
        __syncthreads();
        s[t] += u;
        __syncthreads();
    }
    if (t < NB) { bbase[t] = s[t] - v; bcur[t] = s[t] - v; }
    if (t == 1023) bbase[NB] = s[1023];
}

__global__ __launch_bounds__(256) void bscatter_kernel(const int* __restrict__ src,
                                                       const int* __restrict__ dst,
                                                       const int* __restrict__ rel,
                                                       int* __restrict__ bcur,
                                                       unsigned* __restrict__ ebuf,
                                                       int m, int NB) {
    __shared__ int cnt[1024];
    for (int i = threadIdx.x; i < NB; i += 256) cnt[i] = 0;
    __syncthreads();
    int base = blockIdx.x * SC_EDGES;
    int endi = base + SC_EDGES; if (endi > m) endi = m;
    for (int i = base + threadIdx.x; i < endi; i += 256)
        atomicAdd(&cnt[dst[i] >> NPB_SHIFT], 1);
    __syncthreads();
    for (int b = threadIdx.x; b < NB; b += 256) {
        int c = cnt[b];
        if (c) cnt[b] = atomicAdd(&bcur[b], c);
    }
    __syncthreads();
    for (int i = base + threadIdx.x; i < endi; i += 256) {
        int d = dst[i];
        int bk = d >> NPB_SHIFT;
        unsigned pk = (unsigned)src[i] | ((unsigned)rel[i] << 17) |
                      ((unsigned)(d & (NPB - 1)) << 19);
        int pos = atomicAdd(&cnt[bk], 1);
        ebuf[pos] = pk;
    }
}

__global__ __launch_bounds__(256) void bfinal_kernel(const unsigned* __restrict__ ebuf,
                                                     const int* __restrict__ bbase,
                                                     int* __restrict__ rowp,
                                                     unsigned* __restrict__ csr,
                                                     int n, int m, int NB) {
    __shared__ int cnt[NPB], cur[NPB], sc[NPB];
    int b = blockIdx.x;
    int t = threadIdx.x;
    int e0 = bbase[b], e1 = bbase[b + 1];
    if (t < NPB) cnt[t] = 0;
    __syncthreads();
    for (int j = e0 + t; j < e1; j += 256)
        atomicAdd(&cnt[(ebuf[j] >> 19) & (NPB - 1)], 1);
    __syncthreads();
    int v0 = (t < NPB) ? cnt[t] : 0;
    if (t < NPB) sc[t] = v0;
    __syncthreads();
    for (int off = 1; off < NPB; off <<= 1) {
        int u = (t >= off && t < NPB) ? sc[t - off] : 0;
        __syncthreads();
        if (t < NPB) sc[t] += u;
        __syncthreads();
    }
    if (t < NPB) {
        int ex = e0 + sc[t] - v0;
        cur[t] = ex;
        int v = b * NPB + t;
        if (v < n) rowp[v] = ex;
    }
    if (b == 0 && t == 0) rowp[n] = m;
    __syncthreads();
    for (int j = e0 + t; j < e1; j += 256) {
        unsigned pk = ebuf[j];
        int dl = (pk >> 19) & (NPB - 1);
        int pos = atomicAdd(&cur[dl], 1);
        csr[pos] = (pk & 0x1FFFF) | (((pk >> 17) & 3) << 20);
    }
}

// ---------------------------------------------------------------------------
// F0 dual GEMM: OAB[r][d] = hpack((h@WcF0)[r][d], (h@WcF1)[r][d]);
// epilogue -> el1/er1 (float2, from f32 accumulators).
// ---------------------------------------------------------------------------
__global__ __launch_bounds__(256) void gemm_f0(const float* __restrict__ A,
                                               const float* __restrict__ WcF,
                                               unsigned* __restrict__ OAB, int n,
                                               const float* __restrict__ attn_l,
                                               const float* __restrict__ attn_r,
                                               float2* __restrict__ el2,
                                               float2* __restrict__ er2) {
    __shared__ __align__(16) float sW[2][64 * 64];
    __shared__ __align__(16) float sA[64 * 68];
    __shared__ float sAl[64], sAr[64];
    int t = threadIdx.x;
    int row0 = blockIdx.x * 64;
    for (int i = t * 4; i < 8192; i += 1024)
        *(float4*)&sW[0][i] = *(const float4*)&WcF[i];
    if (t < 64) { sAl[t] = attn_l[t]; sAr[t] = attn_r[t]; }
    int rows = n - row0; if (rows > 64) rows = 64;
    for (int i = t * 4; i < 4096; i += 1024) {
        int r = i >> 6, c = i & 63;
        float4 v = {0.f, 0.f, 0.f, 0.f};
        if (r < rows) v = *(const float4*)&A[(size_t)(row0 + r) * 64 + c];
        *(float4*)&sA[r * 68 + c] = v;
    }
    __syncthreads();
    int tr = (t >> 4) * 4, tc = (t & 15) * 4;
    float accA[4][4] = {}, accB[4][4] = {};
#pragma unroll 4
    for (int k = 0; k < 64; k += 4) {
        float4 av[4];
#pragma unroll
        for (int i = 0; i < 4; ++i) av[i] = *(const float4*)&sA[(tr + i) * 68 + k];
#pragma unroll
        for (int kk = 0; kk < 4; ++kk) {
            float4 bA = *(const float4*)&sW[0][(k + kk) * 64 + tc];
            float4 bB = *(const float4*)&sW[1][(k + kk) * 64 + tc];
#pragma unroll
            for (int i = 0; i < 4; ++i) {
                float a = (&av[i].x)[kk];
                accA[i][0] += a * bA.x; accA[i][1] += a * bA.y;
                accA[i][2] += a * bA.z; accA[i][3] += a * bA.w;
                accB[i][0] += a * bB.x; accB[i][1] += a * bB.y;
                accB[i][2] += a * bB.z; accB[i][3] += a * bB.w;
            }
        }
    }
#pragma unroll
    for (int i = 0; i < 4; ++i) {
        int r = row0 + tr + i;
        if (r < n) {
            uint4 v = {hpack(accA[i][0], accB[i][0]), hpack(accA[i][1], accB[i][1]),
                       hpack(accA[i][2], accB[i][2]), hpack(accA[i][3], accB[i][3])};
            *(uint4*)&OAB[(size_t)r * 64 + tc] = v;
        }
    }
    float plA[4], prA[4], plB[4], prB[4];
#pragma unroll
    for (int i = 0; i < 4; ++i) {
        float la = 0.f, ra = 0.f, lb = 0.f, rb = 0.f;
#pragma unroll
        for (int j = 0; j < 4; ++j) {
            la += accA[i][j] * sAl[tc + j]; ra += accA[i][j] * sAr[tc + j];
            lb += accB[i][j] * sAl[tc + j]; rb += accB[i][j] * sAr[tc + j];
        }
        plA[i] = la; prA[i] = ra; plB[i] = lb; prB[i] = rb;
    }
#pragma unroll
    for (int off = 1; off < 16; off <<= 1) {
#pragma unroll
        for (int i = 0; i < 4; ++i) {
            plA[i] += __shfl_xor(plA[i], off); prA[i] += __shfl_xor(prA[i], off);
            plB[i] += __shfl_xor(plB[i], off); prB[i] += __shfl_xor(prB[i], off);
        }
    }
    if ((t & 15) == 0) {
#pragma unroll
        for (int i = 0; i < 4; ++i) {
            int r = row0 + tr + i;
            if (r < n) {
                el2[r] = make_float2(plA[i], plB[i]);
                er2[r] = make_float2(prA[i], prB[i]);
            }
        }
    }
}

// ---------------------------------------------------------------------------
// Sparse pass a: o = D^-1 A_w ft; also writes attention e (packed f16x2) to ab.
// One wave per dst node; lane = dim, packed f16x2 gather, f32 accumulate.
// ---------------------------------------------------------------------------
__global__ __launch_bounds__(256) void agg1_ab(
        const int* __restrict__ rowp, const unsigned* __restrict__ csr,
        const float* __restrict__ filt, int fo0, int fo1,
        const float2* __restrict__ el, const float2* __restrict__ er,
        const unsigned* __restrict__ ftAB, unsigned* __restrict__ oAB,
        unsigned* __restrict__ ab, float2* __restrict__ sb, int n) {
    __shared__ unsigned sPk[4][MAXD];
    __shared__ float2 sW2[4][MAXD];
    int w = (blockIdx.x * blockDim.x + threadIdx.x) >> 6;
    int lane = threadIdx.x & 63;
    int wv = threadIdx.x >> 6;
    if (w >= n) return;
    int base = rowp[w], end = rowp[w + 1];
    float fA0 = filt[fo0], fA1 = filt[fo0 + 1], fA2 = filt[fo0 + 2];
    float fB0 = filt[fo1], fB1 = filt[fo1 + 1], fB2 = filt[fo1 + 2];
    float2 erv = er[w];

    // lane-parallel: stage edges + weights, degw, attention e -> ab, denom
    float degA = 0.f, degB = 0.f, ssA = 0.f, ssB = 0.f;
    for (int j = base + lane; j < end; j += 64) {
        unsigned pk = csr[j];
        int d = j - base;
        int s = pk & 0x1FFFF;
        int r = pk >> 20;
        float wA = (r == 0) ? fA0 : ((r == 1) ? fA1 : fA2);
        float wB = (r == 0) ? fB0 : ((r == 1) ? fB1 : fB2);
        if (d < MAXD) { sPk[wv][d] = pk; sW2[wv][d] = make_float2(wA, wB); }
        degA += wA; degB += wB;
        float2 e2 = el[s];
        float xA = e2.x + erv.x;
        float eA = __expf(xA > 0.f ? xA : NEG_SLOPE * xA);
        float xB = e2.y + erv.y;
        float eB = __expf(xB > 0.f ? xB : NEG_SLOPE * xB);
        ab[j] = hpack(eA, eB);
        ssA += eA; ssB += eB;
    }
    for (int off = 32; off; off >>= 1) {
        degA += __shfl_xor(degA, off); degB += __shfl_xor(degB, off);
        ssA += __shfl_xor(ssA, off);   ssB += __shfl_xor(ssB, off);
    }
    float dA = degA > 0.f ? degA : 1.f;
    float dB = degB > 0.f ? degB : 1.f;

    // serial gather, lane = dim, unroll 4
    int deg = end - base;
    int dmax = deg < MAXD ? deg : MAXD;
    float accA = 0.f, accB = 0.f;
    int jj = 0;
    for (; jj + 4 <= dmax; jj += 4) {
        int s0 = sPk[wv][jj] & 0x1FFFF, s1 = sPk[wv][jj + 1] & 0x1FFFF;
        int s2 = sPk[wv][jj + 2] & 0x1FFFF, s3 = sPk[wv][jj + 3] & 0x1FFFF;
        float2 w0 = sW2[wv][jj], w1 = sW2[wv][jj + 1];
        float2 w2 = sW2[wv][jj + 2], w3 = sW2[wv][jj + 3];
        float2 v0 = hunpack(ftAB[(size_t)s0 * 64 + lane]);
        float2 v1 = hunpack(ftAB[(size_t)s1 * 64 + lane]);
        float2 v2 = hunpack(ftAB[(size_t)s2 * 64 + lane]);
        float2 v3 = hunpack(ftAB[(size_t)s3 * 64 + lane]);
        accA += w0.x * v0.x + w1.x * v1.x + w2.x * v2.x + w3.x * v3.x;
        accB += w0.y * v0.y + w1.y * v1.y + w2.y * v2.y + w3.y * v3.y;
    }
    for (; jj < dmax; ++jj) {
        int s = sPk[wv][jj] & 0x1FFFF;
        float2 wv2 = sW2[wv][jj];
        float2 v = hunpack(ftAB[(size_t)s * 64 + lane]);
        accA += wv2.x * v.x;
        accB += wv2.y * v.y;
    }
    for (int j = base + MAXD; j < end; ++j) {   // deg > MAXD fallback (~never)
        unsigned pk = csr[j];
        int s = pk & 0x1FFFF;
        int r = pk >> 20;
        float2 v = hunpack(ftAB[(size_t)s * 64 + lane]);
        accA += ((r == 0) ? fA0 : ((r == 1) ? fA1 : fA2)) * v.x;
        accB += ((r == 0) ? fB0 : ((r == 1) ? fB1 : fB2)) * v.y;
    }
    oAB[(size_t)w * 64 + lane] = hpack(accA / dA, accB / dB);
    if (lane == 0)
        sb[w] = make_float2(ssA > 0.f ? 1.f / ssA : 0.f,
                            ssB > 0.f ? 1.f / ssB : 0.f);
}

// ---------------------------------------------------------------------------
// Sparse pass b: o = S ft1. Attention e read from ab (coalesced, f16x2) —
// no random el gather, no exp. If EPI: next layer's el/er from f32 output row.
// ---------------------------------------------------------------------------
template <bool EPI>
__global__ __launch_bounds__(256) void agg2_ab(
        const int* __restrict__ rowp, const unsigned* __restrict__ csr,
        const unsigned* __restrict__ ab, const float2* __restrict__ sb,
        const unsigned* __restrict__ ftAB, unsigned* __restrict__ oAB,
        const float2* __restrict__ wlr,
        float2* __restrict__ elout, float2* __restrict__ erout, int n) {
    __shared__ unsigned sPk[4][MAXD];
    __shared__ float2 sE[4][MAXD];
    __shared__ float2 sWlr[64];
    int t = threadIdx.x;
    if (EPI) {
        if (t < 64) sWlr[t] = wlr[t];
        __syncthreads();
    }
    int w = (blockIdx.x * blockDim.x + t) >> 6;
    int lane = t & 63;
    int wv = t >> 6;
    if (w >= n) return;
    int base = rowp[w], end = rowp[w + 1];
    float2 inv = sb[w];

    // lane-parallel staging: pk + attention e (both coalesced)
    for (int j = base + lane; j < end; j += 64) {
        int d = j - base;
        if (d < MAXD) {
            sPk[wv][d] = csr[j];
            sE[wv][d] = hunpack(ab[j]);
        }
    }

    int deg = end - base;
    int dmax = deg < MAXD ? deg : MAXD;
    float accA = 0.f, accB = 0.f;
    int jj = 0;
    for (; jj + 4 <= dmax; jj += 4) {
        int s0 = sPk[wv][jj] & 0x1FFFF, s1 = sPk[wv][jj + 1] & 0x1FFFF;
        int s2 = sPk[wv][jj + 2] & 0x1FFFF, s3 = sPk[wv][jj + 3] & 0x1FFFF;
        float2 e0 = sE[wv][jj], e1 = sE[wv][jj + 1];
        float2 e2 = sE[wv][jj + 2], e3 = sE[wv][jj + 3];
        float2 v0 = hunpack(ftAB[(size_t)s0 * 64 + lane]);
        float2 v1 = hunpack(ftAB[(size_t)s1 * 64 + lane]);
        float2 v2 = hunpack(ftAB[(size_t)s2 * 64 + lane]);
        float2 v3 = hunpack(ftAB[(size_t)s3 * 64 + lane]);
        accA += e0.x * v0.x + e1.x * v1.x + e2.x * v2.x + e3.x * v3.x;
        accB += e0.y * v0.y + e1.y * v1.y + e2.y * v2.y + e3.y * v3.y;
    }
    for (; jj < dmax; ++jj) {
        int s = sPk[wv][jj] & 0x1FFFF;
        float2 ev = sE[wv][jj];
        float2 v = hunpack(ftAB[(size_t)s * 64 + lane]);
        accA += ev.x * v.x;
        accB += ev.y * v.y;
    }
    for (int j = base + MAXD; j < end; ++j) {   // fallback (~never)
        unsigned pk = csr[j];
        int s = pk & 0x1FFFF;
        float2 ev = hunpack(ab[j]);
        float2 v = hunpack(ftAB[(size_t)s * 64 + lane]);
        accA += ev.x * v.x;
        accB += ev.y * v.y;
    }
    float oA = accA * inv.x, oB = accB * inv.y;
    oAB[(size_t)w * 64 + lane] = hpack(oA, oB);
    if (EPI) {
        float2 wv2 = sWlr[lane];
        float elA = oA * wv2.x, elB = oB * wv2.x;
        float erA = oA * wv2.y, erB = oB * wv2.y;
        for (int off = 32; off; off >>= 1) {
            elA += __shfl_xor(elA, off); elB += __shfl_xor(elB, off);
            erA += __shfl_xor(erA, off); erB += __shfl_xor(erB, off);
        }
        if (lane == 0) {
            elout[w] = make_float2(elA, elB);
            erout[w] = make_float2(erA, erB);
        }
    }
}

// ---------------------------------------------------------------------------
// Fused final: out = b2 + (lw0*A + lw1*B) @ WfcW2   (packed f16x2 input)
// ---------------------------------------------------------------------------
__global__ __launch_bounds__(256) void gemm_out_ab(const unsigned* __restrict__ AAB,
                                                   const float* __restrict__ W,
                                                   const float* __restrict__ b2,
                                                   const float* __restrict__ lin_w,
                                                   float* __restrict__ out, int n) {
    __shared__ __align__(16) float sW[64 * 50];
    __shared__ __align__(16) float sA[64 * 68];
    int t = threadIdx.x;
    int row0 = blockIdx.x * 64;
    float lw0 = lin_w[0], lw1 = lin_w[1];
    for (int i = t; i < 64 * 50; i += 256) sW[i] = W[i];
    int rows = n - row0; if (rows > 64) rows = 64;
    for (int i = t * 4; i < 4096; i += 1024) {
        int r = i >> 6, c = i & 63;
        uint4 v = {0u, 0u, 0u, 0u};
        if (r < rows) v = *(const uint4*)&AAB[(size_t)(row0 + r) * 64 + c];
        float2 f0 = hunpack(v.x), f1 = hunpack(v.y);
        float2 f2 = hunpack(v.z), f3 = hunpack(v.w);
        sA[r * 68 + c]     = lw0 * f0.x + lw1 * f0.y;
        sA[r * 68 + c + 1] = lw0 * f1.x + lw1 * f1.y;
        sA[r * 68 + c + 2] = lw0 * f2.x + lw1 * f2.y;
        sA[r * 68 + c + 3] = lw0 * f3.x + lw1 * f3.y;
    }
    __syncthreads();
    for (int i = t; i < 64 * 50; i += 256) {
        int r = i / 50, col = i - r * 50;
        if (row0 + r >= n) continue;
        float acc = 0.f;
#pragma unroll
        for (int k = 0; k < 64; ++k) acc += sA[r * 68 + k] * sW[k * 50 + col];
        out[(size_t)(row0 + r) * 50 + col] = b2[col] + acc;
    }
}

// ---------------------------------------------------------------------------
extern "C" void kernel_launch(void* const* d_in, const int* in_sizes, int n_in,
                              void* d_out, int out_size, void* d_ws, size_t ws_size,
                              hipStream_t stream) {
    const float* h      = (const float*)d_in[0];
    const float* params = (const float*)d_in[1];
    const float* gt_w   = (const float*)d_in[2];
    const float* fc_w   = (const float*)d_in[3];
    const float* attn_l = (const float*)d_in[4];
    const float* attn_r = (const float*)d_in[5];
    const float* lin_w  = (const float*)d_in[6];
    const float* W2     = (const float*)d_in[7];
    const float* b2     = (const float*)d_in[8];
    const int*   src    = (const int*)d_in[9];
    const int*   dst    = (const int*)d_in[10];
    const int*   rel    = (const int*)d_in[11];

    const int n = in_sizes[0] / 64;      // 100000 nodes
    const int m = in_sizes[9];           // 1.8M edges
    const int C = 2, L = 2;
    float* out = (float*)d_out;

    char* base = (char*)d_ws;
    size_t off = 0;
    auto alloc = [&](size_t bytes) -> char* {
        char* p = base + off;
        off = (off + bytes + 255) & ~(size_t)255;
        return p;
    };
    const int NB = (n + NPB - 1) >> NPB_SHIFT;
    const int nchunks = (m + SC_EDGES - 1) / SC_EDGES;
    float*    filt  = (float*)alloc(L * C * 3 * sizeof(float));
    float*    WcF   = (float*)alloc((size_t)C * 64 * 64 * 4);
    float*    WfcW2 = (float*)alloc((size_t)64 * 50 * 4);
    float2*   wlr   = (float2*)alloc((size_t)64 * 8);
    int*      bcnt  = (int*)alloc((size_t)NB * 4);
    int*      bbase = (int*)alloc((size_t)(NB + 1) * 4);
    int*      bcur  = (int*)alloc((size_t)NB * 4);
    int*      rowp  = (int*)alloc((size_t)(n + 1) * 4);
    unsigned* ebuf  = (unsigned*)alloc((size_t)m * 4);
    unsigned* csr   = (unsigned*)alloc((size_t)m * 4);
    unsigned* abuf  = (unsigned*)alloc((size_t)m * 4);   // packed f16x2 attention e
    float2*   el1   = (float2*)alloc((size_t)n * 8);
    float2*   er1   = (float2*)alloc((size_t)n * 8);
    float2*   elL2  = (float2*)alloc((size_t)n * 8);
    float2*   erL2  = (float2*)alloc((size_t)n * 8);
    float2*   sbAB  = (float2*)alloc((size_t)n * 8);
    unsigned* FAB   = (unsigned*)alloc((size_t)n * 64 * 4);   // packed f16x2
    unsigned* GAB   = (unsigned*)alloc((size_t)n * 64 * 4);
    unsigned* HAB   = (unsigned*)alloc((size_t)n * 64 * 4);

    // ---- tiny precomputes + CSR build ----
    hipMemsetAsync(bcnt, 0, (size_t)NB * 4, stream);
    mkfilt<<<1, 64, 0, stream>>>(gt_w, filt, L * C);
    combw_kernel<<<C, 256, 0, stream>>>(params, fc_w, WcF);
    prep2_kernel<<<1, 256, 0, stream>>>(fc_w, W2, attn_l, attn_r, WfcW2, wlr);
    bcount_kernel<<<nchunks, 256, 0, stream>>>(dst, bcnt, m, NB);
    bscan_kernel<<<1, 1024, 0, stream>>>(bcnt, bbase, bcur, NB);
    bscatter_kernel<<<nchunks, 256, 0, stream>>>(src, dst, rel, bcur, ebuf, m, NB);
    bfinal_kernel<<<NB, 256, 0, stream>>>(ebuf, bbase, rowp, csr, n, m, NB);

    const int gB = (n + 63) / 64;
    const int waveBlocks = (n + 3) / 4;

    // F0 = h @ (params_c @ fc_w), fused el1/er1
    gemm_f0<<<gB, 256, 0, stream>>>(h, WcF, FAB, n, attn_l, attn_r, el1, er1);
    // layer 1
    agg1_ab<<<waveBlocks, 256, 0, stream>>>(rowp, csr, filt, 0, 3,
                                            el1, er1, FAB, GAB, abuf, sbAB, n);
    agg2_ab<true><<<waveBlocks, 256, 0, stream>>>(rowp, csr, abuf, sbAB,
                                                  GAB, HAB, wlr, elL2, erL2, n);
    // layer 2 (fc_w deferred into the output GEMM)
    agg1_ab<<<waveBlocks, 256, 0, stream>>>(rowp, csr, filt, 6, 9,
                                            elL2, erL2, HAB, GAB, abuf, sbAB, n);
    agg2_ab<false><<<waveBlocks, 256, 0, stream>>>(rowp, csr, abuf, sbAB,
                                                   GAB, HAB, nullptr, nullptr, nullptr, n);
    // out = b2 + (lw0*HA + lw1*HB) @ (fc_w @ W2)
    gemm_out_ab<<<gB, 256, 0, stream>>>(HAB, WfcW2, b2, lin_w, out, n);
}

// Round 13
// 473.713 us; speedup vs baseline: 1.6730x; 1.0091x over previous
//
#include <hip/hip_runtime.h>
#include <hip/hip_bf16.h>
#include <hip/hip_fp16.h>
#include <math.h>

#define NEG_SLOPE 0.2f
#define NPB_SHIFT 7
#define NPB 128          // nodes per bucket
#define SC_EDGES 16384   // edges per bscatter block
#define MAXD 128         // per-node edges staged in LDS

// packed f16 pair: lo = chA, hi = chB (RN rounding)
__device__ __forceinline__ unsigned hpack(float a, float b) {
    __half2 h = __floats2half2_rn(a, b);
    return *(unsigned*)&h;
}
__device__ __forceinline__ float2 hunpack(unsigned v) {
    __half2 h = *(__half2*)&v;
    return make_float2(__low2float(h), __high2float(h));
}
// accA += f16lo(v)*f16lo(w); accB += f16hi(v)*f16hi(w)  — one VOP3P each
__device__ __forceinline__ void fmix_lo(float& acc, unsigned v, unsigned w) {
    asm("v_fma_mix_f32 %0, %1, %2, %0 op_sel:[0,0,0] op_sel_hi:[1,1,0]"
        : "+v"(acc) : "v"(v), "v"(w));
}
__device__ __forceinline__ void fmix_hi(float& acc, unsigned v, unsigned w) {
    asm("v_fma_mix_f32 %0, %1, %2, %0 op_sel:[1,1,0] op_sel_hi:[1,1,0]"
        : "+v"(acc) : "v"(v), "v"(w));
}

// ---------------------------------------------------------------------------
// filt[l][c][r] = softmax_r(gt_w[l][c][:])
// ---------------------------------------------------------------------------
__global__ void mkfilt(const float* __restrict__ gt_w, float* __restrict__ filt,
                       int rows) {
    int i = threadIdx.x;
    if (i < rows) {
        const float* g = gt_w + i * 3;
        float m = fmaxf(g[0], fmaxf(g[1], g[2]));
        float e0 = __expf(g[0] - m), e1 = __expf(g[1] - m), e2 = __expf(g[2] - m);
        float s = e0 + e1 + e2;
        filt[i * 3 + 0] = e0 / s;
        filt[i * 3 + 1] = e1 / s;
        filt[i * 3 + 2] = e2 / s;
    }
}

// ---------------------------------------------------------------------------
// WcF[c] = params[c] @ fc_w
// ---------------------------------------------------------------------------
__global__ __launch_bounds__(256) void combw_kernel(const float* __restrict__ params,
                                                    const float* __restrict__ fc_w,
                                                    float* __restrict__ WcF) {
    __shared__ __align__(16) float sP[64 * 64], sF[64 * 64];
    const float* P = params + (size_t)blockIdx.x * 64 * 64;
    int t = threadIdx.x;
    for (int i = t * 4; i < 4096; i += 1024) {
        *(float4*)&sP[i] = *(const float4*)&P[i];
        *(float4*)&sF[i] = *(const float4*)&fc_w[i];
    }
    __syncthreads();
    float* O = WcF + (size_t)blockIdx.x * 64 * 64;
    for (int i = t; i < 4096; i += 256) {
        int r = i >> 6, c = i & 63;
        float acc = 0.f;
#pragma unroll
        for (int k = 0; k < 64; ++k) acc += sP[r * 64 + k] * sF[k * 64 + c];
        O[i] = acc;
    }
}

// ---------------------------------------------------------------------------
// WfcW2 = fc_w @ W2 (64x50); wlr[i] = (fc_w[i]·attn_l, fc_w[i]·attn_r)
// ---------------------------------------------------------------------------
__global__ __launch_bounds__(256) void prep2_kernel(const float* __restrict__ fc_w,
                                                    const float* __restrict__ W2,
                                                    const float* __restrict__ attn_l,
                                                    const float* __restrict__ attn_r,
                                                    float* __restrict__ WfcW2,
                                                    float2* __restrict__ wlr) {
    __shared__ __align__(16) float sF[4096];
    __shared__ float sW[3200], sal[64], sar[64];
    int t = threadIdx.x;
    for (int i = t * 4; i < 4096; i += 1024)
        *(float4*)&sF[i] = *(const float4*)&fc_w[i];
    for (int i = t; i < 3200; i += 256) sW[i] = W2[i];
    if (t < 64) { sal[t] = attn_l[t]; sar[t] = attn_r[t]; }
    __syncthreads();
    if (t < 64) {
        float l = 0.f, r = 0.f;
#pragma unroll
        for (int k = 0; k < 64; ++k) {
            l += sF[t * 64 + k] * sal[k];
            r += sF[t * 64 + k] * sar[k];
        }
        wlr[t] = make_float2(l, r);
    }
    for (int i = t; i < 3200; i += 256) {
        int r = i / 50, c = i - r * 50;
        float acc = 0.f;
#pragma unroll
        for (int k = 0; k < 64; ++k) acc += sF[r * 64 + k] * sW[k * 50 + c];
        WfcW2[i] = acc;
    }
}

// ---------------------------------------------------------------------------
// Bucketed CSR build (unchanged)
// ---------------------------------------------------------------------------
__global__ __launch_bounds__(256) void bcount_kernel(const int* __restrict__ dst,
                                                     int* __restrict__ bcnt, int m, int NB) {
    __shared__ int h[1024];
    for (int i = threadIdx.x; i < NB; i += 256) h[i] = 0;
    __syncthreads();
    int base = blockIdx.x * SC_EDGES;
    int endi = base + SC_EDGES; if (endi > m) endi = m;
    for (int i = base + threadIdx.x; i < endi; i += 256)
        atomicAdd(&h[dst[i] >> NPB_SHIFT], 1);
    __syncthreads();
    for (int i = threadIdx.x; i < NB; i += 256)
        if (h[i]) atomicAdd(&bcnt[i], h[i]);
}

__global__ __launch_bounds__(1024) void bscan_kernel(const int* __restrict__ bcnt,
                                                     int* __restrict__ bbase,
                                                     int* __restrict__ bcur, int NB) {
    __shared__ int s[1024];
    int t = threadIdx.x;
    int v = (t < NB) ? bcnt[t] : 0;
    s[t] = v;
    __syncthreads();
    for (int off = 1; off < 1024; off <<= 1) {
        int u = (t >= off) ? s[t - off] : 0;
        __syncthreads();
        s[t] += u;
        __syncthreads();
    }
    if (t < NB) { bbase[t] = s[t] - v; bcur[t] = s[t] - v; }
    if (t == 1023) bbase[NB] = s[1023];
}

__global__ __launch_bounds__(256) void bscatter_kernel(const int* __restrict__ src,
                                                       const int* __restrict__ dst,
                                                       const int* __restrict__ rel,
                                                       int* __restrict__ bcur,
                                                       unsigned* __restrict__ ebuf,
                                                       int m, int NB) {
    __shared__ int cnt[1024];
    for (int i = threadIdx.x; i < NB; i += 256) cnt[i] = 0;
    __syncthreads();
    int base = blockIdx.x * SC_EDGES;
    int endi = base + SC_EDGES; if (endi > m) endi = m;
    for (int i = base + threadIdx.x; i < endi; i += 256)
        atomicAdd(&cnt[dst[i] >> NPB_SHIFT], 1);
    __syncthreads();
    for (int b = threadIdx.x; b < NB; b += 256) {
        int c = cnt[b];
        if (c) cnt[b] = atomicAdd(&bcur[b], c);
    }
    __syncthreads();
    for (int i = base + threadIdx.x; i < endi; i += 256) {
        int d = dst[i];
        int bk = d >> NPB_SHIFT;
        unsigned pk = (unsigned)src[i] | ((unsigned)rel[i] << 17) |
                      ((unsigned)(d & (NPB - 1)) << 19);
        int pos = atomicAdd(&cnt[bk], 1);
        ebuf[pos] = pk;
    }
}

__global__ __launch_bounds__(256) void bfinal_kernel(const unsigned* __restrict__ ebuf,
                                                     const int* __restrict__ bbase,
                                                     int* __restrict__ rowp,
                                                     unsigned* __restrict__ csr,
                                                     int n, int m, int NB) {
    __shared__ int cnt[NPB], cur[NPB], sc[NPB];
    int b = blockIdx.x;
    int t = threadIdx.x;
    int e0 = bbase[b], e1 = bbase[b + 1];
    if (t < NPB) cnt[t] = 0;
    __syncthreads();
    for (int j = e0 + t; j < e1; j += 256)
        atomicAdd(&cnt[(ebuf[j] >> 19) & (NPB - 1)], 1);
    __syncthreads();
    int v0 = (t < NPB) ? cnt[t] : 0;
    if (t < NPB) sc[t] = v0;
    __syncthreads();
    for (int off = 1; off < NPB; off <<= 1) {
        int u = (t >= off && t < NPB) ? sc[t - off] : 0;
        __syncthreads();
        if (t < NPB) sc[t] += u;
        __syncthreads();
    }
    if (t < NPB) {
        int ex = e0 + sc[t] - v0;
        cur[t] = ex;
        int v = b * NPB + t;
        if (v < n) rowp[v] = ex;
    }
    if (b == 0 && t == 0) rowp[n] = m;
    __syncthreads();
    for (int j = e0 + t; j < e1; j += 256) {
        unsigned pk = ebuf[j];
        int dl = (pk >> 19) & (NPB - 1);
        int pos = atomicAdd(&cur[dl], 1);
        csr[pos] = (pk & 0x1FFFF) | (((pk >> 17) & 3) << 20);
    }
}

// ---------------------------------------------------------------------------
// F0 dual GEMM: OAB[r][d] = hpack((h@WcF0)[r][d], (h@WcF1)[r][d]);
// epilogue -> el1/er1 (float2, from f32 accumulators).
// ---------------------------------------------------------------------------
__global__ __launch_bounds__(256) void gemm_f0(const float* __restrict__ A,
                                               const float* __restrict__ WcF,
                                               unsigned* __restrict__ OAB, int n,
                                               const float* __restrict__ attn_l,
                                               const float* __restrict__ attn_r,
                                               float2* __restrict__ el2,
                                               float2* __restrict__ er2) {
    __shared__ __align__(16) float sW[2][64 * 64];
    __shared__ __align__(16) float sA[64 * 68];
    __shared__ float sAl[64], sAr[64];
    int t = threadIdx.x;
    int row0 = blockIdx.x * 64;
    for (int i = t * 4; i < 8192; i += 1024)
        *(float4*)&sW[0][i] = *(const float4*)&WcF[i];
    if (t < 64) { sAl[t] = attn_l[t]; sAr[t] = attn_r[t]; }
    int rows = n - row0; if (rows > 64) rows = 64;
    for (int i = t * 4; i < 4096; i += 1024) {
        int r = i >> 6, c = i & 63;
        float4 v = {0.f, 0.f, 0.f, 0.f};
        if (r < rows) v = *(const float4*)&A[(size_t)(row0 + r) * 64 + c];
        *(float4*)&sA[r * 68 + c] = v;
    }
    __syncthreads();
    int tr = (t >> 4) * 4, tc = (t & 15) * 4;
    float accA[4][4] = {}, accB[4][4] = {};
#pragma unroll 4
    for (int k = 0; k < 64; k += 4) {
        float4 av[4];
#pragma unroll
        for (int i = 0; i < 4; ++i) av[i] = *(const float4*)&sA[(tr + i) * 68 + k];
#pragma unroll
        for (int kk = 0; kk < 4; ++kk) {
            float4 bA = *(const float4*)&sW[0][(k + kk) * 64 + tc];
            float4 bB = *(const float4*)&sW[1][(k + kk) * 64 + tc];
#pragma unroll
            for (int i = 0; i < 4; ++i) {
                float a = (&av[i].x)[kk];
                accA[i][0] += a * bA.x; accA[i][1] += a * bA.y;
                accA[i][2] += a * bA.z; accA[i][3] += a * bA.w;
                accB[i][0] += a * bB.x; accB[i][1] += a * bB.y;
                accB[i][2] += a * bB.z; accB[i][3] += a * bB.w;
            }
        }
    }
#pragma unroll
    for (int i = 0; i < 4; ++i) {
        int r = row0 + tr + i;
        if (r < n) {
            uint4 v = {hpack(accA[i][0], accB[i][0]), hpack(accA[i][1], accB[i][1]),
                       hpack(accA[i][2], accB[i][2]), hpack(accA[i][3], accB[i][3])};
            *(uint4*)&OAB[(size_t)r * 64 + tc] = v;
        }
    }
    float plA[4], prA[4], plB[4], prB[4];
#pragma unroll
    for (int i = 0; i < 4; ++i) {
        float la = 0.f, ra = 0.f, lb = 0.f, rb = 0.f;
#pragma unroll
        for (int j = 0; j < 4; ++j) {
            la += accA[i][j] * sAl[tc + j]; ra += accA[i][j] * sAr[tc + j];
            lb += accB[i][j] * sAl[tc + j]; rb += accB[i][j] * sAr[tc + j];
        }
        plA[i] = la; prA[i] = ra; plB[i] = lb; prB[i] = rb;
    }
#pragma unroll
    for (int off = 1; off < 16; off <<= 1) {
#pragma unroll
        for (int i = 0; i < 4; ++i) {
            plA[i] += __shfl_xor(plA[i], off); prA[i] += __shfl_xor(prA[i], off);
            plB[i] += __shfl_xor(plB[i], off); prB[i] += __shfl_xor(prB[i], off);
        }
    }
    if ((t & 15) == 0) {
#pragma unroll
        for (int i = 0; i < 4; ++i) {
            int r = row0 + tr + i;
            if (r < n) {
                el2[r] = make_float2(plA[i], plB[i]);
                er2[r] = make_float2(prA[i], prB[i]);
            }
        }
    }
}

// ---------------------------------------------------------------------------
// Sparse pass a: o = D^-1 A_w ft; writes attention e (f16x2) to ab.
// Serial gather: 1 ds_read_b64 (pk,wpk) + saddr load + 2 v_fma_mix per edge.
// ---------------------------------------------------------------------------
__global__ __launch_bounds__(256) void agg1_ab(
        const int* __restrict__ rowp, const unsigned* __restrict__ csr,
        const float* __restrict__ filt, int fo0, int fo1,
        const float2* __restrict__ el, const float2* __restrict__ er,
        const unsigned* __restrict__ ftAB, unsigned* __restrict__ oAB,
        unsigned* __restrict__ ab, float2* __restrict__ sb, int n) {
    __shared__ uint2 sPW[4][MAXD];
    int w = (blockIdx.x * blockDim.x + threadIdx.x) >> 6;
    int lane = threadIdx.x & 63;
    int wv = threadIdx.x >> 6;
    if (w >= n) return;
    int base = rowp[w], end = rowp[w + 1];
    float fA0 = filt[fo0], fA1 = filt[fo0 + 1], fA2 = filt[fo0 + 2];
    float fB0 = filt[fo1], fB1 = filt[fo1 + 1], fB2 = filt[fo1 + 2];
    float2 erv = er[w];
    const char* ftb = (const char*)ftAB;
    unsigned laneoff = (unsigned)lane << 2;

    // lane-parallel: stage (pk, wpk), degw, attention e -> ab, denom
    float degA = 0.f, degB = 0.f, ssA = 0.f, ssB = 0.f;
    for (int j = base + lane; j < end; j += 64) {
        unsigned pk = csr[j];
        int d = j - base;
        int s = pk & 0x1FFFF;
        int r = pk >> 20;
        float wA = (r == 0) ? fA0 : ((r == 1) ? fA1 : fA2);
        float wB = (r == 0) ? fB0 : ((r == 1) ? fB1 : fB2);
        if (d < MAXD) sPW[wv][d] = make_uint2(pk, hpack(wA, wB));
        degA += wA; degB += wB;
        float2 e2 = el[s];
        float xA = e2.x + erv.x;
        float eA = __expf(xA > 0.f ? xA : NEG_SLOPE * xA);
        float xB = e2.y + erv.y;
        float eB = __expf(xB > 0.f ? xB : NEG_SLOPE * xB);
        ab[j] = hpack(eA, eB);
        ssA += eA; ssB += eB;
    }
    for (int off = 32; off; off >>= 1) {
        degA += __shfl_xor(degA, off); degB += __shfl_xor(degB, off);
        ssA += __shfl_xor(ssA, off);   ssB += __shfl_xor(ssB, off);
    }
    float dA = degA > 0.f ? degA : 1.f;
    float dB = degB > 0.f ? degB : 1.f;

    // serial gather, lane = dim, unroll 4
    int deg = end - base;
    int dmax = deg < MAXD ? deg : MAXD;
    float accA = 0.f, accB = 0.f;
    int jj = 0;
    for (; jj + 4 <= dmax; jj += 4) {
        uint2 p0 = sPW[wv][jj],     p1 = sPW[wv][jj + 1];
        uint2 p2 = sPW[wv][jj + 2], p3 = sPW[wv][jj + 3];
        unsigned v0 = *(const unsigned*)(ftb + (((p0.x & 0x1FFFF) << 8) + laneoff));
        unsigned v1 = *(const unsigned*)(ftb + (((p1.x & 0x1FFFF) << 8) + laneoff));
        unsigned v2 = *(const unsigned*)(ftb + (((p2.x & 0x1FFFF) << 8) + laneoff));
        unsigned v3 = *(const unsigned*)(ftb + (((p3.x & 0x1FFFF) << 8) + laneoff));
        fmix_lo(accA, v0, p0.y); fmix_hi(accB, v0, p0.y);
        fmix_lo(accA, v1, p1.y); fmix_hi(accB, v1, p1.y);
        fmix_lo(accA, v2, p2.y); fmix_hi(accB, v2, p2.y);
        fmix_lo(accA, v3, p3.y); fmix_hi(accB, v3, p3.y);
    }
    for (; jj < dmax; ++jj) {
        uint2 p = sPW[wv][jj];
        unsigned v = *(const unsigned*)(ftb + (((p.x & 0x1FFFF) << 8) + laneoff));
        fmix_lo(accA, v, p.y); fmix_hi(accB, v, p.y);
    }
    for (int j = base + MAXD; j < end; ++j) {   // deg > MAXD fallback (~never)
        unsigned pk = csr[j];
        int s = pk & 0x1FFFF;
        int r = pk >> 20;
        float2 v = hunpack(*(const unsigned*)(ftb + ((unsigned)(s << 8) + laneoff)));
        accA += ((r == 0) ? fA0 : ((r == 1) ? fA1 : fA2)) * v.x;
        accB += ((r == 0) ? fB0 : ((r == 1) ? fB1 : fB2)) * v.y;
    }
    oAB[(size_t)w * 64 + lane] = hpack(accA / dA, accB / dB);
    if (lane == 0)
        sb[w] = make_float2(ssA > 0.f ? 1.f / ssA : 0.f,
                            ssB > 0.f ? 1.f / ssB : 0.f);
}

// ---------------------------------------------------------------------------
// Sparse pass b: o = S ft1. Attention e from ab (coalesced f16x2).
// Serial gather identical structure to pass a. If EPI: next-layer el/er.
// ---------------------------------------------------------------------------
template <bool EPI>
__global__ __launch_bounds__(256) void agg2_ab(
        const int* __restrict__ rowp, const unsigned* __restrict__ csr,
        const unsigned* __restrict__ ab, const float2* __restrict__ sb,
        const unsigned* __restrict__ ftAB, unsigned* __restrict__ oAB,
        const float2* __restrict__ wlr,
        float2* __restrict__ elout, float2* __restrict__ erout, int n) {
    __shared__ uint2 sPW[4][MAXD];
    __shared__ float2 sWlr[64];
    int t = threadIdx.x;
    if (EPI) {
        if (t < 64) sWlr[t] = wlr[t];
        __syncthreads();
    }
    int w = (blockIdx.x * blockDim.x + t) >> 6;
    int lane = t & 63;
    int wv = t >> 6;
    if (w >= n) return;
    int base = rowp[w], end = rowp[w + 1];
    float2 inv = sb[w];
    const char* ftb = (const char*)ftAB;
    unsigned laneoff = (unsigned)lane << 2;

    // lane-parallel staging: (pk, e-pair) — both coalesced
    for (int j = base + lane; j < end; j += 64) {
        int d = j - base;
        if (d < MAXD) sPW[wv][d] = make_uint2(csr[j], ab[j]);
    }

    int deg = end - base;
    int dmax = deg < MAXD ? deg : MAXD;
    float accA = 0.f, accB = 0.f;
    int jj = 0;
    for (; jj + 4 <= dmax; jj += 4) {
        uint2 p0 = sPW[wv][jj],     p1 = sPW[wv][jj + 1];
        uint2 p2 = sPW[wv][jj + 2], p3 = sPW[wv][jj + 3];
        unsigned v0 = *(const unsigned*)(ftb + (((p0.x & 0x1FFFF) << 8) + laneoff));
        unsigned v1 = *(const unsigned*)(ftb + (((p1.x & 0x1FFFF) << 8) + laneoff));
        unsigned v2 = *(const unsigned*)(ftb + (((p2.x & 0x1FFFF) << 8) + laneoff));
        unsigned v3 = *(const unsigned*)(ftb + (((p3.x & 0x1FFFF) << 8) + laneoff));
        fmix_lo(accA, v0, p0.y); fmix_hi(accB, v0, p0.y);
        fmix_lo(accA, v1, p1.y); fmix_hi(accB, v1, p1.y);
        fmix_lo(accA, v2, p2.y); fmix_hi(accB, v2, p2.y);
        fmix_lo(accA, v3, p3.y); fmix_hi(accB, v3, p3.y);
    }
    for (; jj < dmax; ++jj) {
        uint2 p = sPW[wv][jj];
        unsigned v = *(const unsigned*)(ftb + (((p.x & 0x1FFFF) << 8) + laneoff));
        fmix_lo(accA, v, p.y); fmix_hi(accB, v, p.y);
    }
    for (int j = base + MAXD; j < end; ++j) {   // fallback (~never)
        unsigned pk = csr[j];
        int s = pk & 0x1FFFF;
        float2 ev = hunpack(ab[j]);
        float2 v = hunpack(*(const unsigned*)(ftb + ((unsigned)(s << 8) + laneoff)));
        accA += ev.x * v.x;
        accB += ev.y * v.y;
    }
    float oA = accA * inv.x, oB = accB * inv.y;
    oAB[(size_t)w * 64 + lane] = hpack(oA, oB);
    if (EPI) {
        float2 wv2 = sWlr[lane];
        float elA = oA * wv2.x, elB = oB * wv2.x;
        float erA = oA * wv2.y, erB = oB * wv2.y;
        for (int off = 32; off; off >>= 1) {
            elA += __shfl_xor(elA, off); elB += __shfl_xor(elB, off);
            erA += __shfl_xor(erA, off); erB += __shfl_xor(erB, off);
        }
        if (lane == 0) {
            elout[w] = make_float2(elA, elB);
            erout[w] = make_float2(erA, erB);
        }
    }
}

// ---------------------------------------------------------------------------
// Fused final: out = b2 + (lw0*A + lw1*B) @ WfcW2   (packed f16x2 input)
// ---------------------------------------------------------------------------
__global__ __launch_bounds__(256) void gemm_out_ab(const unsigned* __restrict__ AAB,
                                                   const float* __restrict__ W,
                                                   const float* __restrict__ b2,
                                                   const float* __restrict__ lin_w,
                                                   float* __restrict__ out, int n) {
    __shared__ __align__(16) float sW[64 * 50];
    __shared__ __align__(16) float sA[64 * 68];
    int t = threadIdx.x;
    int row0 = blockIdx.x * 64;
    float lw0 = lin_w[0], lw1 = lin_w[1];
    for (int i = t; i < 64 * 50; i += 256) sW[i] = W[i];
    int rows = n - row0; if (rows > 64) rows = 64;
    for (int i = t * 4; i < 4096; i += 1024) {
        int r = i >> 6, c = i & 63;
        uint4 v = {0u, 0u, 0u, 0u};
        if (r < rows) v = *(const uint4*)&AAB[(size_t)(row0 + r) * 64 + c];
        float2 f0 = hunpack(v.x), f1 = hunpack(v.y);
        float2 f2 = hunpack(v.z), f3 = hunpack(v.w);
        sA[r * 68 + c]     = lw0 * f0.x + lw1 * f0.y;
        sA[r * 68 + c + 1] = lw0 * f1.x + lw1 * f1.y;
        sA[r * 68 + c + 2] = lw0 * f2.x + lw1 * f2.y;
        sA[r * 68 + c + 3] = lw0 * f3.x + lw1 * f3.y;
    }
    __syncthreads();
    for (int i = t; i < 64 * 50; i += 256) {
        int r = i / 50, col = i - r * 50;
        if (row0 + r >= n) continue;
        float acc = 0.f;
#pragma unroll
        for (int k = 0; k < 64; ++k) acc += sA[r * 68 + k] * sW[k * 50 + col];
        out[(size_t)(row0 + r) * 50 + col] = b2[col] + acc;
    }
}

// ---------------------------------------------------------------------------
extern "C" void kernel_launch(void* const* d_in, const int* in_sizes, int n_in,
                              void* d_out, int out_size, void* d_ws, size_t ws_size,
                              hipStream_t stream) {
    const float* h      = (const float*)d_in[0];
    const float* params = (const float*)d_in[1];
    const float* gt_w   = (const float*)d_in[2];
    const float* fc_w   = (const float*)d_in[3];
    const float* attn_l = (const float*)d_in[4];
    const float* attn_r = (const float*)d_in[5];
    const float* lin_w  = (const float*)d_in[6];
    const float* W2     = (const float*)d_in[7];
    const float* b2     = (const float*)d_in[8];
    const int*   src    = (const int*)d_in[9];
    const int*   dst    = (const int*)d_in[10];
    const int*   rel    = (const int*)d_in[11];

    const int n = in_sizes[0] / 64;      // 100000 nodes
    const int m = in_sizes[9];           // 1.8M edges
    const int C = 2, L = 2;
    float* out = (float*)d_out;

    char* base = (char*)d_ws;
    size_t off = 0;
    auto alloc = [&](size_t bytes) -> char* {
        char* p = base + off;
        off = (off + bytes + 255) & ~(size_t)255;
        return p;
    };
    const int NB = (n + NPB - 1) >> NPB_SHIFT;
    const int nchunks = (m + SC_EDGES - 1) / SC_EDGES;
    float*    filt  = (float*)alloc(L * C * 3 * sizeof(float));
    float*    WcF   = (float*)alloc((size_t)C * 64 * 64 * 4);
    float*    WfcW2 = (float*)alloc((size_t)64 * 50 * 4);
    float2*   wlr   = (float2*)alloc((size_t)64 * 8);
    int*      bcnt  = (int*)alloc((size_t)NB * 4);
    int*      bbase = (int*)alloc((size_t)(NB + 1) * 4);
    int*      bcur  = (int*)alloc((size_t)NB * 4);
    int*      rowp  = (int*)alloc((size_t)(n + 1) * 4);
    unsigned* ebuf  = (unsigned*)alloc((size_t)m * 4);
    unsigned* csr   = (unsigned*)alloc((size_t)m * 4);
    unsigned* abuf  = (unsigned*)alloc((size_t)m * 4);   // packed f16x2 attention e
    float2*   el1   = (float2*)alloc((size_t)n * 8);
    float2*   er1   = (float2*)alloc((size_t)n * 8);
    float2*   elL2  = (float2*)alloc((size_t)n * 8);
    float2*   erL2  = (float2*)alloc((size_t)n * 8);
    float2*   sbAB  = (float2*)alloc((size_t)n * 8);
    unsigned* FAB   = (unsigned*)alloc((size_t)n * 64 * 4);   // packed f16x2
    unsigned* GAB   = (unsigned*)alloc((size_t)n * 64 * 4);
    unsigned* HAB   = (unsigned*)alloc((size_t)n * 64 * 4);

    // ---- tiny precomputes + CSR build ----
    hipMemsetAsync(bcnt, 0, (size_t)NB * 4, stream);
    mkfilt<<<1, 64, 0, stream>>>(gt_w, filt, L * C);
    combw_kernel<<<C, 256, 0, stream>>>(params, fc_w, WcF);
    prep2_kernel<<<1, 256, 0, stream>>>(fc_w, W2, attn_l, attn_r, WfcW2, wlr);
    bcount_kernel<<<nchunks, 256, 0, stream>>>(dst, bcnt, m, NB);
    bscan_kernel<<<1, 1024, 0, stream>>>(bcnt, bbase, bcur, NB);
    bscatter_kernel<<<nchunks, 256, 0, stream>>>(src, dst, rel, bcur, ebuf, m, NB);
    bfinal_kernel<<<NB, 256, 0, stream>>>(ebuf, bbase, rowp, csr, n, m, NB);

    const int gB = (n + 63) / 64;
    const int waveBlocks = (n + 3) / 4;

    // F0 = h @ (params_c @ fc_w), fused el1/er1
    gemm_f0<<<gB, 256, 0, stream>>>(h, WcF, FAB, n, attn_l, attn_r, el1, er1);
    // layer 1
    agg1_ab<<<waveBlocks, 256, 0, stream>>>(rowp, csr, filt, 0, 3,
                                            el1, er1, FAB, GAB, abuf, sbAB, n);
    agg2_ab<true><<<waveBlocks, 256, 0, stream>>>(rowp, csr, abuf, sbAB,
                                                  GAB, HAB, wlr, elL2, erL2, n);
    // layer 2 (fc_w deferred into the output GEMM)
    agg1_ab<<<waveBlocks, 256, 0, stream>>>(rowp, csr, filt, 6, 9,
                                            elL2, erL2, HAB, GAB, abuf, sbAB, n);
    agg2_ab<false><<<waveBlocks, 256, 0, stream>>>(rowp, csr, abuf, sbAB,
                                                   GAB, HAB, nullptr, nullptr, nullptr, n);
    // out = b2 + (lw0*HA + lw1*HB) @ (fc_w @ W2)
    gemm_out_ab<<<gB, 256, 0, stream>>>(HAB, WfcW2, b2, lin_w, out, n);
}

// Round 14
// 471.570 us; speedup vs baseline: 1.6806x; 1.0045x over previous
//
#include <hip/hip_runtime.h>
#include <hip/hip_bf16.h>
#include <hip/hip_fp16.h>
#include <math.h>

#define NEG_SLOPE 0.2f
#define NPB_SHIFT 7
#define NPB 128          // nodes per bucket
#define SC_EDGES 16384   // edges per bscatter block
#define MAXD 128         // per-node edges staged in LDS

// packed f16 pair: lo = chA, hi = chB (RN rounding)
__device__ __forceinline__ unsigned hpack(float a, float b) {
    __half2 h = __floats2half2_rn(a, b);
    return *(unsigned*)&h;
}
__device__ __forceinline__ float2 hunpack(unsigned v) {
    __half2 h = *(__half2*)&v;
    return make_float2(__low2float(h), __high2float(h));
}
// accA += f16lo(v)*f16lo(w); accB += f16hi(v)*f16hi(w)  — one VOP3P each
__device__ __forceinline__ void fmix_lo(float& acc, unsigned v, unsigned w) {
    asm("v_fma_mix_f32 %0, %1, %2, %0 op_sel:[0,0,0] op_sel_hi:[1,1,0]"
        : "+v"(acc) : "v"(v), "v"(w));
}
__device__ __forceinline__ void fmix_hi(float& acc, unsigned v, unsigned w) {
    asm("v_fma_mix_f32 %0, %1, %2, %0 op_sel:[1,1,0] op_sel_hi:[1,1,0]"
        : "+v"(acc) : "v"(v), "v"(w));
}

// ---------------------------------------------------------------------------
// filt[l][c][r] = softmax_r(gt_w[l][c][:])
// ---------------------------------------------------------------------------
__global__ void mkfilt(const float* __restrict__ gt_w, float* __restrict__ filt,
                       int rows) {
    int i = threadIdx.x;
    if (i < rows) {
        const float* g = gt_w + i * 3;
        float m = fmaxf(g[0], fmaxf(g[1], g[2]));
        float e0 = __expf(g[0] - m), e1 = __expf(g[1] - m), e2 = __expf(g[2] - m);
        float s = e0 + e1 + e2;
        filt[i * 3 + 0] = e0 / s;
        filt[i * 3 + 1] = e1 / s;
        filt[i * 3 + 2] = e2 / s;
    }
}

// ---------------------------------------------------------------------------
// WcF[c] = params[c] @ fc_w
// ---------------------------------------------------------------------------
__global__ __launch_bounds__(256) void combw_kernel(const float* __restrict__ params,
                                                    const float* __restrict__ fc_w,
                                                    float* __restrict__ WcF) {
    __shared__ __align__(16) float sP[64 * 64], sF[64 * 64];
    const float* P = params + (size_t)blockIdx.x * 64 * 64;
    int t = threadIdx.x;
    for (int i = t * 4; i < 4096; i += 1024) {
        *(float4*)&sP[i] = *(const float4*)&P[i];
        *(float4*)&sF[i] = *(const float4*)&fc_w[i];
    }
    __syncthreads();
    float* O = WcF + (size_t)blockIdx.x * 64 * 64;
    for (int i = t; i < 4096; i += 256) {
        int r = i >> 6, c = i & 63;
        float acc = 0.f;
#pragma unroll
        for (int k = 0; k < 64; ++k) acc += sP[r * 64 + k] * sF[k * 64 + c];
        O[i] = acc;
    }
}

// ---------------------------------------------------------------------------
// WfcW2 = fc_w @ W2 (64x50); wlr[i] = (fc_w[i]·attn_l, fc_w[i]·attn_r)
// ---------------------------------------------------------------------------
__global__ __launch_bounds__(256) void prep2_kernel(const float* __restrict__ fc_w,
                                                    const float* __restrict__ W2,
                                                    const float* __restrict__ attn_l,
                                                    const float* __restrict__ attn_r,
                                                    float* __restrict__ WfcW2,
                                                    float2* __restrict__ wlr) {
    __shared__ __align__(16) float sF[4096];
    __shared__ float sW[3200], sal[64], sar[64];
    int t = threadIdx.x;
    for (int i = t * 4; i < 4096; i += 1024)
        *(float4*)&sF[i] = *(const float4*)&fc_w[i];
    for (int i = t; i < 3200; i += 256) sW[i] = W2[i];
    if (t < 64) { sal[t] = attn_l[t]; sar[t] = attn_r[t]; }
    __syncthreads();
    if (t < 64) {
        float l = 0.f, r = 0.f;
#pragma unroll
        for (int k = 0; k < 64; ++k) {
            l += sF[t * 64 + k] * sal[k];
            r += sF[t * 64 + k] * sar[k];
        }
        wlr[t] = make_float2(l, r);
    }
    for (int i = t; i < 3200; i += 256) {
        int r = i / 50, c = i - r * 50;
        float acc = 0.f;
#pragma unroll
        for (int k = 0; k < 64; ++k) acc += sF[r * 64 + k] * sW[k * 50 + c];
        WfcW2[i] = acc;
    }
}

// ---------------------------------------------------------------------------
// Bucketed CSR build (unchanged)
// ---------------------------------------------------------------------------
__global__ __launch_bounds__(256) void bcount_kernel(const int* __restrict__ dst,
                                                     int* __restrict__ bcnt, int m, int NB) {
    __shared__ int h[1024];
    for (int i = threadIdx.x; i < NB; i += 256) h[i] = 0;
    __syncthreads();
    int base = blockIdx.x * SC_EDGES;
    int endi = base + SC_EDGES; if (endi > m) endi = m;
    for (int i = base + threadIdx.x; i < endi; i += 256)
        atomicAdd(&h[dst[i] >> NPB_SHIFT], 1);
    __syncthreads();
    for (int i = threadIdx.x; i < NB; i += 256)
        if (h[i]) atomicAdd(&bcnt[i], h[i]);
}

__global__ __launch_bounds__(1024) void bscan_kernel(const int* __restrict__ bcnt,
                                                     int* __restrict__ bbase,
                                                     int* __restrict__ bcur, int NB) {
    __shared__ int s[1024];
    int t = threadIdx.x;
    int v = (t < NB) ? bcnt[t] : 0;
    s[t] = v;
    __syncthreads();
    for (int off = 1; off < 1024; off <<= 1) {
        int u = (t >= off) ? s[t - off] : 0;
        __syncthreads();
        s[t] += u;
        __syncthreads();
    }
    if (t < NB) { bbase[t] = s[t] - v; bcur[t] = s[t] - v; }
    if (t == 1023) bbase[NB] = s[1023];
}

__global__ __launch_bounds__(256) void bscatter_kernel(const int* __restrict__ src,
                                                       const int* __restrict__ dst,
                                                       const int* __restrict__ rel,
                                                       int* __restrict__ bcur,
                                                       unsigned* __restrict__ ebuf,
                                                       int m, int NB) {
    __shared__ int cnt[1024];
    for (int i = threadIdx.x; i < NB; i += 256) cnt[i] = 0;
    __syncthreads();
    int base = blockIdx.x * SC_EDGES;
    int endi = base + SC_EDGES; if (endi > m) endi = m;
    for (int i = base + threadIdx.x; i < endi; i += 256)
        atomicAdd(&cnt[dst[i] >> NPB_SHIFT], 1);
    __syncthreads();
    for (int b = threadIdx.x; b < NB; b += 256) {
        int c = cnt[b];
        if (c) cnt[b] = atomicAdd(&bcur[b], c);
    }
    __syncthreads();
    for (int i = base + threadIdx.x; i < endi; i += 256) {
        int d = dst[i];
        int bk = d >> NPB_SHIFT;
        unsigned pk = (unsigned)src[i] | ((unsigned)rel[i] << 17) |
                      ((unsigned)(d & (NPB - 1)) << 19);
        int pos = atomicAdd(&cnt[bk], 1);
        ebuf[pos] = pk;
    }
}

__global__ __launch_bounds__(256) void bfinal_kernel(const unsigned* __restrict__ ebuf,
                                                     const int* __restrict__ bbase,
                                                     int* __restrict__ rowp,
                                                     unsigned* __restrict__ csr,
                                                     int n, int m, int NB) {
    __shared__ int cnt[NPB], cur[NPB], sc[NPB];
    int b = blockIdx.x;
    int t = threadIdx.x;
    int e0 = bbase[b], e1 = bbase[b + 1];
    if (t < NPB) cnt[t] = 0;
    __syncthreads();
    for (int j = e0 + t; j < e1; j += 256)
        atomicAdd(&cnt[(ebuf[j] >> 19) & (NPB - 1)], 1);
    __syncthreads();
    int v0 = (t < NPB) ? cnt[t] : 0;
    if (t < NPB) sc[t] = v0;
    __syncthreads();
    for (int off = 1; off < NPB; off <<= 1) {
        int u = (t >= off && t < NPB) ? sc[t - off] : 0;
        __syncthreads();
        if (t < NPB) sc[t] += u;
        __syncthreads();
    }
    if (t < NPB) {
        int ex = e0 + sc[t] - v0;
        cur[t] = ex;
        int v = b * NPB + t;
        if (v < n) rowp[v] = ex;
    }
    if (b == 0 && t == 0) rowp[n] = m;
    __syncthreads();
    for (int j = e0 + t; j < e1; j += 256) {
        unsigned pk = ebuf[j];
        int dl = (pk >> 19) & (NPB - 1);
        int pos = atomicAdd(&cur[dl], 1);
        csr[pos] = (pk & 0x1FFFF) | (((pk >> 17) & 3) << 20);
    }
}

// ---------------------------------------------------------------------------
// F0 dual GEMM: OAB[r][d] = hpack((h@WcF0)[r][d], (h@WcF1)[r][d]);
// epilogue -> el1/er1 (float2, from f32 accumulators).
// ---------------------------------------------------------------------------
__global__ __launch_bounds__(256) void gemm_f0(const float* __restrict__ A,
                                               const float* __restrict__ WcF,
                                               unsigned* __restrict__ OAB, int n,
                                               const float* __restrict__ attn_l,
                                               const float* __restrict__ attn_r,
                                               float2* __restrict__ el2,
                                               float2* __restrict__ er2) {
    __shared__ __align__(16) float sW[2][64 * 64];
    __shared__ __align__(16) float sA[64 * 68];
    __shared__ float sAl[64], sAr[64];
    int t = threadIdx.x;
    int row0 = blockIdx.x * 64;
    for (int i = t * 4; i < 8192; i += 1024)
        *(float4*)&sW[0][i] = *(const float4*)&WcF[i];
    if (t < 64) { sAl[t] = attn_l[t]; sAr[t] = attn_r[t]; }
    int rows = n - row0; if (rows > 64) rows = 64;
    for (int i = t * 4; i < 4096; i += 1024) {
        int r = i >> 6, c = i & 63;
        float4 v = {0.f, 0.f, 0.f, 0.f};
        if (r < rows) v = *(const float4*)&A[(size_t)(row0 + r) * 64 + c];
        *(float4*)&sA[r * 68 + c] = v;
    }
    __syncthreads();
    int tr = (t >> 4) * 4, tc = (t & 15) * 4;
    float accA[4][4] = {}, accB[4][4] = {};
#pragma unroll 4
    for (int k = 0; k < 64; k += 4) {
        float4 av[4];
#pragma unroll
        for (int i = 0; i < 4; ++i) av[i] = *(const float4*)&sA[(tr + i) * 68 + k];
#pragma unroll
        for (int kk = 0; kk < 4; ++kk) {
            float4 bA = *(const float4*)&sW[0][(k + kk) * 64 + tc];
            float4 bB = *(const float4*)&sW[1][(k + kk) * 64 + tc];
#pragma unroll
            for (int i = 0; i < 4; ++i) {
                float a = (&av[i].x)[kk];
                accA[i][0] += a * bA.x; accA[i][1] += a * bA.y;
                accA[i][2] += a * bA.z; accA[i][3] += a * bA.w;
                accB[i][0] += a * bB.x; accB[i][1] += a * bB.y;
                accB[i][2] += a * bB.z; accB[i][3] += a * bB.w;
            }
        }
    }
#pragma unroll
    for (int i = 0; i < 4; ++i) {
        int r = row0 + tr + i;
        if (r < n) {
            uint4 v = {hpack(accA[i][0], accB[i][0]), hpack(accA[i][1], accB[i][1]),
                       hpack(accA[i][2], accB[i][2]), hpack(accA[i][3], accB[i][3])};
            *(uint4*)&OAB[(size_t)r * 64 + tc] = v;
        }
    }
    float plA[4], prA[4], plB[4], prB[4];
#pragma unroll
    for (int i = 0; i < 4; ++i) {
        float la = 0.f, ra = 0.f, lb = 0.f, rb = 0.f;
#pragma unroll
        for (int j = 0; j < 4; ++j) {
            la += accA[i][j] * sAl[tc + j]; ra += accA[i][j] * sAr[tc + j];
            lb += accB[i][j] * sAl[tc + j]; rb += accB[i][j] * sAr[tc + j];
        }
        plA[i] = la; prA[i] = ra; plB[i] = lb; prB[i] = rb;
    }
#pragma unroll
    for (int off = 1; off < 16; off <<= 1) {
#pragma unroll
        for (int i = 0; i < 4; ++i) {
            plA[i] += __shfl_xor(plA[i], off); prA[i] += __shfl_xor(prA[i], off);
            plB[i] += __shfl_xor(plB[i], off); prB[i] += __shfl_xor(prB[i], off);
        }
    }
    if ((t & 15) == 0) {
#pragma unroll
        for (int i = 0; i < 4; ++i) {
            int r = row0 + tr + i;
            if (r < n) {
                el2[r] = make_float2(plA[i], plB[i]);
                er2[r] = make_float2(prA[i], prB[i]);
            }
        }
    }
}

// ---------------------------------------------------------------------------
// Sparse pass a: o = D^-1 A_w ft; writes attention e (f16x2) to ab.
// Serial gather unroll 8: 8 independent dword loads in flight per lane.
// ---------------------------------------------------------------------------
__global__ __launch_bounds__(256) void agg1_ab(
        const int* __restrict__ rowp, const unsigned* __restrict__ csr,
        const float* __restrict__ filt, int fo0, int fo1,
        const float2* __restrict__ el, const float2* __restrict__ er,
        const unsigned* __restrict__ ftAB, unsigned* __restrict__ oAB,
        unsigned* __restrict__ ab, float2* __restrict__ sb, int n) {
    __shared__ uint2 sPW[4][MAXD];
    int w = (blockIdx.x * blockDim.x + threadIdx.x) >> 6;
    int lane = threadIdx.x & 63;
    int wv = threadIdx.x >> 6;
    if (w >= n) return;
    int base = rowp[w], end = rowp[w + 1];
    float fA0 = filt[fo0], fA1 = filt[fo0 + 1], fA2 = filt[fo0 + 2];
    float fB0 = filt[fo1], fB1 = filt[fo1 + 1], fB2 = filt[fo1 + 2];
    float2 erv = er[w];
    const char* ftb = (const char*)ftAB;
    unsigned laneoff = (unsigned)lane << 2;

    // lane-parallel: stage (pk, wpk), degw, attention e -> ab, denom
    float degA = 0.f, degB = 0.f, ssA = 0.f, ssB = 0.f;
    for (int j = base + lane; j < end; j += 64) {
        unsigned pk = csr[j];
        int d = j - base;
        int s = pk & 0x1FFFF;
        int r = pk >> 20;
        float wA = (r == 0) ? fA0 : ((r == 1) ? fA1 : fA2);
        float wB = (r == 0) ? fB0 : ((r == 1) ? fB1 : fB2);
        if (d < MAXD) sPW[wv][d] = make_uint2(pk, hpack(wA, wB));
        degA += wA; degB += wB;
        float2 e2 = el[s];
        float xA = e2.x + erv.x;
        float eA = __expf(xA > 0.f ? xA : NEG_SLOPE * xA);
        float xB = e2.y + erv.y;
        float eB = __expf(xB > 0.f ? xB : NEG_SLOPE * xB);
        ab[j] = hpack(eA, eB);
        ssA += eA; ssB += eB;
    }
    for (int off = 32; off; off >>= 1) {
        degA += __shfl_xor(degA, off); degB += __shfl_xor(degB, off);
        ssA += __shfl_xor(ssA, off);   ssB += __shfl_xor(ssB, off);
    }
    float dA = degA > 0.f ? degA : 1.f;
    float dB = degB > 0.f ? degB : 1.f;

    // serial gather, lane = dim, unroll 8 (8 independent loads in flight)
    int deg = end - base;
    int dmax = deg < MAXD ? deg : MAXD;
    float accA = 0.f, accB = 0.f;
    int jj = 0;
    for (; jj + 8 <= dmax; jj += 8) {
        uint2 p0 = sPW[wv][jj],     p1 = sPW[wv][jj + 1];
        uint2 p2 = sPW[wv][jj + 2], p3 = sPW[wv][jj + 3];
        uint2 p4 = sPW[wv][jj + 4], p5 = sPW[wv][jj + 5];
        uint2 p6 = sPW[wv][jj + 6], p7 = sPW[wv][jj + 7];
        unsigned v0 = *(const unsigned*)(ftb + (((p0.x & 0x1FFFF) << 8) + laneoff));
        unsigned v1 = *(const unsigned*)(ftb + (((p1.x & 0x1FFFF) << 8) + laneoff));
        unsigned v2 = *(const unsigned*)(ftb + (((p2.x & 0x1FFFF) << 8) + laneoff));
        unsigned v3 = *(const unsigned*)(ftb + (((p3.x & 0x1FFFF) << 8) + laneoff));
        unsigned v4 = *(const unsigned*)(ftb + (((p4.x & 0x1FFFF) << 8) + laneoff));
        unsigned v5 = *(const unsigned*)(ftb + (((p5.x & 0x1FFFF) << 8) + laneoff));
        unsigned v6 = *(const unsigned*)(ftb + (((p6.x & 0x1FFFF) << 8) + laneoff));
        unsigned v7 = *(const unsigned*)(ftb + (((p7.x & 0x1FFFF) << 8) + laneoff));
        fmix_lo(accA, v0, p0.y); fmix_hi(accB, v0, p0.y);
        fmix_lo(accA, v1, p1.y); fmix_hi(accB, v1, p1.y);
        fmix_lo(accA, v2, p2.y); fmix_hi(accB, v2, p2.y);
        fmix_lo(accA, v3, p3.y); fmix_hi(accB, v3, p3.y);
        fmix_lo(accA, v4, p4.y); fmix_hi(accB, v4, p4.y);
        fmix_lo(accA, v5, p5.y); fmix_hi(accB, v5, p5.y);
        fmix_lo(accA, v6, p6.y); fmix_hi(accB, v6, p6.y);
        fmix_lo(accA, v7, p7.y); fmix_hi(accB, v7, p7.y);
    }
    for (; jj < dmax; ++jj) {
        uint2 p = sPW[wv][jj];
        unsigned v = *(const unsigned*)(ftb + (((p.x & 0x1FFFF) << 8) + laneoff));
        fmix_lo(accA, v, p.y); fmix_hi(accB, v, p.y);
    }
    for (int j = base + MAXD; j < end; ++j) {   // deg > MAXD fallback (~never)
        unsigned pk = csr[j];
        int s = pk & 0x1FFFF;
        int r = pk >> 20;
        float2 v = hunpack(*(const unsigned*)(ftb + ((unsigned)(s << 8) + laneoff)));
        accA += ((r == 0) ? fA0 : ((r == 1) ? fA1 : fA2)) * v.x;
        accB += ((r == 0) ? fB0 : ((r == 1) ? fB1 : fB2)) * v.y;
    }
    oAB[(size_t)w * 64 + lane] = hpack(accA / dA, accB / dB);
    if (lane == 0)
        sb[w] = make_float2(ssA > 0.f ? 1.f / ssA : 0.f,
                            ssB > 0.f ? 1.f / ssB : 0.f);
}

// ---------------------------------------------------------------------------
// Sparse pass b: o = S ft1. Attention e from ab (coalesced f16x2).
// Serial gather unroll 8. If EPI: next-layer el/er from f32 output row.
// ---------------------------------------------------------------------------
template <bool EPI>
__global__ __launch_bounds__(256) void agg2_ab(
        const int* __restrict__ rowp, const unsigned* __restrict__ csr,
        const unsigned* __restrict__ ab, const float2* __restrict__ sb,
        const unsigned* __restrict__ ftAB, unsigned* __restrict__ oAB,
        const float2* __restrict__ wlr,
        float2* __restrict__ elout, float2* __restrict__ erout, int n) {
    __shared__ uint2 sPW[4][MAXD];
    __shared__ float2 sWlr[64];
    int t = threadIdx.x;
    if (EPI) {
        if (t < 64) sWlr[t] = wlr[t];
        __syncthreads();
    }
    int w = (blockIdx.x * blockDim.x + t) >> 6;
    int lane = t & 63;
    int wv = t >> 6;
    if (w >= n) return;
    int base = rowp[w], end = rowp[w + 1];
    float2 inv = sb[w];
    const char* ftb = (const char*)ftAB;
    unsigned laneoff = (unsigned)lane << 2;

    // lane-parallel staging: (pk, e-pair) — both coalesced
    for (int j = base + lane; j < end; j += 64) {
        int d = j - base;
        if (d < MAXD) sPW[wv][d] = make_uint2(csr[j], ab[j]);
    }

    int deg = end - base;
    int dmax = deg < MAXD ? deg : MAXD;
    float accA = 0.f, accB = 0.f;
    int jj = 0;
    for (; jj + 8 <= dmax; jj += 8) {
        uint2 p0 = sPW[wv][jj],     p1 = sPW[wv][jj + 1];
        uint2 p2 = sPW[wv][jj + 2], p3 = sPW[wv][jj + 3];
        uint2 p4 = sPW[wv][jj + 4], p5 = sPW[wv][jj + 5];
        uint2 p6 = sPW[wv][jj + 6], p7 = sPW[wv][jj + 7];
        unsigned v0 = *(const unsigned*)(ftb + (((p0.x & 0x1FFFF) << 8) + laneoff));
        unsigned v1 = *(const unsigned*)(ftb + (((p1.x & 0x1FFFF) << 8) + laneoff));
        unsigned v2 = *(const unsigned*)(ftb + (((p2.x & 0x1FFFF) << 8) + laneoff));
        unsigned v3 = *(const unsigned*)(ftb + (((p3.x & 0x1FFFF) << 8) + laneoff));
        unsigned v4 = *(const unsigned*)(ftb + (((p4.x & 0x1FFFF) << 8) + laneoff));
        unsigned v5 = *(const unsigned*)(ftb + (((p5.x & 0x1FFFF) << 8) + laneoff));
        unsigned v6 = *(const unsigned*)(ftb + (((p6.x & 0x1FFFF) << 8) + laneoff));
        unsigned v7 = *(const unsigned*)(ftb + (((p7.x & 0x1FFFF) << 8) + laneoff));
        fmix_lo(accA, v0, p0.y); fmix_hi(accB, v0, p0.y);
        fmix_lo(accA, v1, p1.y); fmix_hi(accB, v1, p1.y);
        fmix_lo(accA, v2, p2.y); fmix_hi(accB, v2, p2.y);
        fmix_lo(accA, v3, p3.y); fmix_hi(accB, v3, p3.y);
        fmix_lo(accA, v4, p4.y); fmix_hi(accB, v4, p4.y);
        fmix_lo(accA, v5, p5.y); fmix_hi(accB, v5, p5.y);
        fmix_lo(accA, v6, p6.y); fmix_hi(accB, v6, p6.y);
        fmix_lo(accA, v7, p7.y); fmix_hi(accB, v7, p7.y);
    }
    for (; jj < dmax; ++jj) {
        uint2 p = sPW[wv][jj];
        unsigned v = *(const unsigned*)(ftb + (((p.x & 0x1FFFF) << 8) + laneoff));
        fmix_lo(accA, v, p.y); fmix_hi(accB, v, p.y);
    }
    for (int j = base + MAXD; j < end; ++j) {   // fallback (~never)
        unsigned pk = csr[j];
        int s = pk & 0x1FFFF;
        float2 ev = hunpack(ab[j]);
        float2 v = hunpack(*(const unsigned*)(ftb + ((unsigned)(s << 8) + laneoff)));
        accA += ev.x * v.x;
        accB += ev.y * v.y;
    }
    float oA = accA * inv.x, oB = accB * inv.y;
    oAB[(size_t)w * 64 + lane] = hpack(oA, oB);
    if (EPI) {
        float2 wv2 = sWlr[lane];
        float elA = oA * wv2.x, elB = oB * wv2.x;
        float erA = oA * wv2.y, erB = oB * wv2.y;
        for (int off = 32; off; off >>= 1) {
            elA += __shfl_xor(elA, off); elB += __shfl_xor(elB, off);
            erA += __shfl_xor(erA, off); erB += __shfl_xor(erB, off);
        }
        if (lane == 0) {
            elout[w] = make_float2(elA, elB);
            erout[w] = make_float2(erA, erB);
        }
    }
}

// ---------------------------------------------------------------------------
// Fused final: out = b2 + (lw0*A + lw1*B) @ WfcW2   (packed f16x2 input)
// ---------------------------------------------------------------------------
__global__ __launch_bounds__(256) void gemm_out_ab(const unsigned* __restrict__ AAB,
                                                   const float* __restrict__ W,
                                                   const float* __restrict__ b2,
                                                   const float* __restrict__ lin_w,
                                                   float* __restrict__ out, int n) {
    __shared__ __align__(16) float sW[64 * 50];
    __shared__ __align__(16) float sA[64 * 68];
    int t = threadIdx.x;
    int row0 = blockIdx.x * 64;
    float lw0 = lin_w[0], lw1 = lin_w[1];
    for (int i = t; i < 64 * 50; i += 256) sW[i] = W[i];
    int rows = n - row0; if (rows > 64) rows = 64;
    for (int i = t * 4; i < 4096; i += 1024) {
        int r = i >> 6, c = i & 63;
        uint4 v = {0u, 0u, 0u, 0u};
        if (r < rows) v = *(const uint4*)&AAB[(size_t)(row0 + r) * 64 + c];
        float2 f0 = hunpack(v.x), f1 = hunpack(v.y);
        float2 f2 = hunpack(v.z), f3 = hunpack(v.w);
        sA[r * 68 + c]     = lw0 * f0.x + lw1 * f0.y;
        sA[r * 68 + c + 1] = lw0 * f1.x + lw1 * f1.y;
        sA[r * 68 + c + 2] = lw0 * f2.x + lw1 * f2.y;
        sA[r * 68 + c + 3] = lw0 * f3.x + lw1 * f3.y;
    }
    __syncthreads();
    for (int i = t; i < 64 * 50; i += 256) {
        int r = i / 50, col = i - r * 50;
        if (row0 + r >= n) continue;
        float acc = 0.f;
#pragma unroll
        for (int k = 0; k < 64; ++k) acc += sA[r * 68 + k] * sW[k * 50 + col];
        out[(size_t)(row0 + r) * 50 + col] = b2[col] + acc;
    }
}

// ---------------------------------------------------------------------------
extern "C" void kernel_launch(void* const* d_in, const int* in_sizes, int n_in,
                              void* d_out, int out_size, void* d_ws, size_t ws_size,
                              hipStream_t stream) {
    const float* h      = (const float*)d_in[0];
    const float* params = (const float*)d_in[1];
    const float* gt_w   = (const float*)d_in[2];
    const float* fc_w   = (const float*)d_in[3];
    const float* attn_l = (const float*)d_in[4];
    const float* attn_r = (const float*)d_in[5];
    const float* lin_w  = (const float*)d_in[6];
    const float* W2     = (const float*)d_in[7];
    const float* b2     = (const float*)d_in[8];
    const int*   src    = (const int*)d_in[9];
    const int*   dst    = (const int*)d_in[10];
    const int*   rel    = (const int*)d_in[11];

    const int n = in_sizes[0] / 64;      // 100000 nodes
    const int m = in_sizes[9];           // 1.8M edges
    const int C = 2, L = 2;
    float* out = (float*)d_out;

    char* base = (char*)d_ws;
    size_t off = 0;
    auto alloc = [&](size_t bytes) -> char* {
        char* p = base + off;
        off = (off + bytes + 255) & ~(size_t)255;
        return p;
    };
    const int NB = (n + NPB - 1) >> NPB_SHIFT;
    const int nchunks = (m + SC_EDGES - 1) / SC_EDGES;
    float*    filt  = (float*)alloc(L * C * 3 * sizeof(float));
    float*    WcF   = (float*)alloc((size_t)C * 64 * 64 * 4);
    float*    WfcW2 = (float*)alloc((size_t)64 * 50 * 4);
    float2*   wlr   = (float2*)alloc((size_t)64 * 8);
    int*      bcnt  = (int*)alloc((size_t)NB * 4);
    int*      bbase = (int*)alloc((size_t)(NB + 1) * 4);
    int*      bcur  = (int*)alloc((size_t)NB * 4);
    int*      rowp  = (int*)alloc((size_t)(n + 1) * 4);
    unsigned* ebuf  = (unsigned*)alloc((size_t)m * 4);
    unsigned* csr   = (unsigned*)alloc((size_t)m * 4);
    unsigned* abuf  = (unsigned*)alloc((size_t)m * 4);   // packed f16x2 attention e
    float2*   el1   = (float2*)alloc((size_t)n * 8);
    float2*   er1   = (float2*)alloc((size_t)n * 8);
    float2*   elL2  = (float2*)alloc((size_t)n * 8);
    float2*   erL2  = (float2*)alloc((size_t)n * 8);
    float2*   sbAB  = (float2*)alloc((size_t)n * 8);
    unsigned* FAB   = (unsigned*)alloc((size_t)n * 64 * 4);   // packed f16x2
    unsigned* GAB   = (unsigned*)alloc((size_t)n * 64 * 4);
    unsigned* HAB   = (unsigned*)alloc((size_t)n * 64 * 4);

    // ---- tiny precomputes + CSR build ----
    hipMemsetAsync(bcnt, 0, (size_t)NB * 4, stream);
    mkfilt<<<1, 64, 0, stream>>>(gt_w, filt, L * C);
    combw_kernel<<<C, 256, 0, stream>>>(params, fc_w, WcF);
    prep2_kernel<<<1, 256, 0, stream>>>(fc_w, W2, attn_l, attn_r, WfcW2, wlr);
    bcount_kernel<<<nchunks, 256, 0, stream>>>(dst, bcnt, m, NB);
    bscan_kernel<<<1, 1024, 0, stream>>>(bcnt, bbase, bcur, NB);
    bscatter_kernel<<<nchunks, 256, 0, stream>>>(src, dst, rel, bcur, ebuf, m, NB);
    bfinal_kernel<<<NB, 256, 0, stream>>>(ebuf, bbase, rowp, csr, n, m, NB);

    const int gB = (n + 63) / 64;
    const int waveBlocks = (n + 3) / 4;

    // F0 = h @ (params_c @ fc_w), fused el1/er1
    gemm_f0<<<gB, 256, 0, stream>>>(h, WcF, FAB, n, attn_l, attn_r, el1, er1);
    // layer 1
    agg1_ab<<<waveBlocks, 256, 0, stream>>>(rowp, csr, filt, 0, 3,
                                            el1, er1, FAB, GAB, abuf, sbAB, n);
    agg2_ab<true><<<waveBlocks, 256, 0, stream>>>(rowp, csr, abuf, sbAB,
                                                  GAB, HAB, wlr, elL2, erL2, n);
    // layer 2 (fc_w deferred into the output GEMM)
    agg1_ab<<<waveBlocks, 256, 0, stream>>>(rowp, csr, filt, 6, 9,
                                            elL2, erL2, HAB, GAB, abuf, sbAB, n);
    agg2_ab<false><<<waveBlocks, 256, 0, stream>>>(rowp, csr, abuf, sbAB,
                                                   GAB, HAB, nullptr, nullptr, nullptr, n);
    // out = b2 + (lw0*HA + lw1*HB) @ (fc_w @ W2)
    gemm_out_ab<<<gB, 256, 0, stream>>>(HAB, WfcW2, b2, lin_w, out, n);
}